// Round 1
// baseline (667.984 us; speedup 1.0000x reference)
//
#include <hip/hip_runtime.h>
#include <cstddef>

// ---------------------------------------------------------------------------
// Reins layer on MI355X.  Pipeline:
//  1. fwd_fft_c        : 1024-pt FFT along C for x=feats[1:]  -> Fre,Fim
//  2. fwd_fft_b_amp    : 8-pt FFT along B, fused amp/phase    -> amp,phase
//  3. gemm_bt (GEMM1)  : logits = P @ tokens^T  (z=0 phase, z=1 amp)
//  4. compute_vT       : B2[c][k] = (tokens[1+k] @ w_t2f^T + b)[c], K-pad 128
//  5. in_softmax       : (instance-norm for z=1) + softmax, writes shifted aw
//  6. gemm_bt (GEMM2)  : df = aw @ B2^T  (K=128)
//  7. gemm_bt (GEMM3)  : d = (df + P) @ w_df^T + b_df
//  8. make_z_fftb      : z = amp*e^{i phase}/sqrt(2C), 8-pt ifft along b (ortho)
//  9. inv_fft_c_final  : Hermitian-extend 513->1024, ifft (ortho), out=x+delta*scale
// 10. copy_cls         : out[0] = feats[0]
// ---------------------------------------------------------------------------

using bf16x8 = __attribute__((ext_vector_type(8))) short;   // 8 bf16 in 4 VGPRs
using f32x4  = __attribute__((ext_vector_type(4))) float;

__device__ inline short f2bf(float f) {
  union { float f; unsigned u; } v; v.f = f;
  unsigned r = v.u + 0x7FFFu + ((v.u >> 16) & 1u);  // round-to-nearest-even
  return (short)(r >> 16);
}

// ---------------- 1. forward 1024-pt FFT along C (real input) ---------------
__global__ __launch_bounds__(256) void fwd_fft_c(const float* __restrict__ feats,
                                                 float* __restrict__ Fre,
                                                 float* __restrict__ Fim) {
  __shared__ __align__(16) float re[1024];
  __shared__ __align__(16) float im[1024];
  __shared__ float twr[512], twi[512];
  const int t = threadIdx.x;
  const int row = blockIdx.x;                       // 0..8191 = n*8+b
  const float* src = feats + 8192 + (size_t)row * 1024;
  for (int k = t; k < 512; k += 256) {
    float s, c;
    __sincosf(-6.283185307179586f * (float)k * (1.0f / 1024.0f), &s, &c);
    twr[k] = c; twi[k] = s;                         // e^{-2pi i k/1024}
  }
  for (int i = t; i < 1024; i += 256) {
    int j = __brev((unsigned)i) >> 22;              // 10-bit reversal
    re[j] = src[i];
    im[j] = 0.0f;
  }
  __syncthreads();
  for (int s = 1; s <= 10; ++s) {
    const int half = 1 << (s - 1);
    const int tshift = 10 - s;
    for (int b = t; b < 512; b += 256) {
      int j = b & (half - 1);
      int g = b >> (s - 1);
      int i0 = (g << s) + j;
      int i1 = i0 + half;
      float wr = twr[j << tshift], wi = twi[j << tshift];
      float xr = re[i1], xi = im[i1];
      float tr = wr * xr - wi * xi;
      float ti = wr * xi + wi * xr;
      float ur = re[i0], ui = im[i0];
      re[i0] = ur + tr; im[i0] = ui + ti;
      re[i1] = ur - tr; im[i1] = ui - ti;
    }
    __syncthreads();
  }
  float* dr = Fre + (size_t)row * 1024;
  float* di = Fim + (size_t)row * 1024;
  for (int i = t; i < 1024; i += 256) { dr[i] = re[i]; di[i] = im[i]; }
}

// ------- 2. 8-pt FFT along B + amp/phase (denormal-replaced), fused ---------
__global__ __launch_bounds__(256) void fwd_fft_b_amp(const float* __restrict__ Fre,
                                                     const float* __restrict__ Fim,
                                                     float* __restrict__ amp,
                                                     float* __restrict__ phase) {
  const int idx = blockIdx.x * 256 + threadIdx.x;   // 0..1024*1024-1 : (n,c)
  const int n = idx >> 10, c = idx & 1023;
  const size_t base = (size_t)n * 8192 + c;
  float xr[8], xi[8];
#pragma unroll
  for (int b = 0; b < 8; ++b) { xr[b] = Fre[base + b * 1024]; xi[b] = Fim[base + b * 1024]; }
  const float cv[8] = {1.f, 0.70710678f, 0.f, -0.70710678f, -1.f, -0.70710678f, 0.f, 0.70710678f};
  const float sv[8] = {0.f, 0.70710678f, 1.f, 0.70710678f, 0.f, -0.70710678f, -1.f, -0.70710678f};
#pragma unroll
  for (int kb = 0; kb < 8; ++kb) {
    float sr = 0.f, si = 0.f;
#pragma unroll
    for (int b = 0; b < 8; ++b) {
      const int p = (kb * b) & 7;                   // e^{-i pi p/4}
      sr += xr[b] * cv[p] + xi[b] * sv[p];
      si += xi[b] * cv[p] - xr[b] * sv[p];
    }
    float r2 = sr * sr + si * si;
    if (r2 < 1e-5f) r2 = 1e-5f;                     // _replace_denormals(re^2+im^2)
    float a = sqrtf(r2);
    float rr = (sr < 1e-5f && sr > -1e-5f) ? 1e-5f : sr;
    float ph = atan2f(si, rr);
    amp[base + kb * 1024] = a;
    phase[base + kb * 1024] = ph;
  }
}

// --------- generic MFMA bf16 GEMM:  C = A(MxK) @ B(NactxK)^T (+bias) --------
// tile 64x64, K-step 32, 256 threads = 4 waves, wave w does rows w*16..w*16+15
__global__ __launch_bounds__(256) void gemm_bt(
    const float* A0, const float* A1,
    const float* Add0, const float* Add1,
    const float* B0, const float* B1,
    const float* bias0, const float* bias1,
    float* C0, float* C1,
    const int* layerp, int K, int Nact, int ldc) {
  const int z = blockIdx.z;
  const float* A    = z ? A1 : A0;
  const float* Add  = z ? Add1 : Add0;
  const float* B    = z ? B1 : B0;
  const float* bias = z ? bias1 : bias0;
  float* C          = z ? C1 : C0;
  if (layerp) B += (size_t)layerp[0] * 102400;      // layer * 100 * 1024

  __shared__ __align__(16) short As[64][32];
  __shared__ __align__(16) short Bs[64][32];
  const int tid = threadIdx.x;
  const int wave = tid >> 6, lane = tid & 63;
  const int m16 = lane & 15, quad = lane >> 4;
  f32x4 acc[4];
#pragma unroll
  for (int i = 0; i < 4; ++i) acc[i] = (f32x4){0.f, 0.f, 0.f, 0.f};

  const int r = tid >> 2;                           // staging row 0..63
  const int cg = (tid & 3) * 8;                     // staging col 0,8,16,24
  const size_t arow = (size_t)(blockIdx.x * 64 + r) * (size_t)K;
  const int nrow = blockIdx.y * 64 + r;
  const float* aptr = A + arow + cg;
  const float* adptr = Add ? Add + arow + cg : nullptr;
  const float* bptr = (nrow < Nact) ? (B + (size_t)nrow * (size_t)K + cg) : nullptr;

  for (int k0 = 0; k0 < K; k0 += 32) {
    float4 a0 = *(const float4*)(aptr + k0);
    float4 a1 = *(const float4*)(aptr + k0 + 4);
    if (adptr) {
      float4 d0 = *(const float4*)(adptr + k0);
      float4 d1 = *(const float4*)(adptr + k0 + 4);
      a0.x += d0.x; a0.y += d0.y; a0.z += d0.z; a0.w += d0.w;
      a1.x += d1.x; a1.y += d1.y; a1.z += d1.z; a1.w += d1.w;
    }
    short* ad = &As[r][cg];
    ad[0] = f2bf(a0.x); ad[1] = f2bf(a0.y); ad[2] = f2bf(a0.z); ad[3] = f2bf(a0.w);
    ad[4] = f2bf(a1.x); ad[5] = f2bf(a1.y); ad[6] = f2bf(a1.z); ad[7] = f2bf(a1.w);
    float4 b0v = {0.f, 0.f, 0.f, 0.f}, b1v = {0.f, 0.f, 0.f, 0.f};
    if (bptr) { b0v = *(const float4*)(bptr + k0); b1v = *(const float4*)(bptr + k0 + 4); }
    short* bd = &Bs[r][cg];
    bd[0] = f2bf(b0v.x); bd[1] = f2bf(b0v.y); bd[2] = f2bf(b0v.z); bd[3] = f2bf(b0v.w);
    bd[4] = f2bf(b1v.x); bd[5] = f2bf(b1v.y); bd[6] = f2bf(b1v.z); bd[7] = f2bf(b1v.w);
    __syncthreads();
    bf16x8 af = *(const bf16x8*)&As[wave * 16 + m16][quad * 8];
#pragma unroll
    for (int cb = 0; cb < 4; ++cb) {
      bf16x8 bf = *(const bf16x8*)&Bs[cb * 16 + m16][quad * 8];
      acc[cb] = __builtin_amdgcn_mfma_f32_16x16x32_bf16(af, bf, acc[cb], 0, 0, 0);
    }
    __syncthreads();
  }
#pragma unroll
  for (int cb = 0; cb < 4; ++cb) {
    const int gcol = blockIdx.y * 64 + cb * 16 + m16;
    const float bv = bias ? bias[gcol] : 0.f;
    const size_t growb = (size_t)(blockIdx.x * 64 + wave * 16 + quad * 4);
#pragma unroll
    for (int rr = 0; rr < 4; ++rr)
      C[(growb + rr) * (size_t)ldc + gcol] = acc[cb][rr] + bv;
  }
}

// ---- 4. B2[z][c][k] = v[k][c] = tokens[1+k]·w_t2f[c] + b_t2f[c], pad K=128 --
__global__ __launch_bounds__(128) void compute_vT(
    const float* lt1, const float* lt2, const float* w1, const float* w2,
    const float* bb1, const float* bb2, const int* layerp, float* B2) {
  const int z = blockIdx.y;
  const int c = blockIdx.x;
  const float* tokens = (z ? lt2 : lt1) + (size_t)layerp[0] * 102400;
  const float* W = (z ? w2 : w1) + (size_t)c * 1024;
  const float* bias = z ? bb2 : bb1;
  __shared__ float wrow[1024];
  const int t = threadIdx.x;
  for (int i = t; i < 1024; i += 128) wrow[i] = W[i];
  __syncthreads();
  float acc = 0.f;
  if (t < 99) {
    const float* tok = tokens + (size_t)(t + 1) * 1024;
    for (int j = 0; j < 1024; j += 4) {
      float4 tv = *(const float4*)(tok + j);
      acc += wrow[j] * tv.x + wrow[j + 1] * tv.y + wrow[j + 2] * tv.z + wrow[j + 3] * tv.w;
    }
    acc += bias[c];
  }
  B2[((size_t)z * 1024 + c) * 128 + t] = (t < 99) ? acc : 0.f;  // zero pad: no NaN in MFMA
}

// -------- 5. (instance-norm for z=1) + softmax(x/32); in-place, shifted -----
__global__ __launch_bounds__(128) void in_softmax(float* logits) {
  const int z = blockIdx.y;
  float* L = logits + ((size_t)z * 8192 + blockIdx.x) * 128;
  const int t = threadIdx.x;
  const bool act = t < 100;
  float x = act ? L[t] : 0.f;
  __shared__ float red[128];
  if (z == 1) {
    red[t] = act ? x : 0.f; __syncthreads();
    for (int o = 64; o > 0; o >>= 1) { if (t < o) red[t] += red[t + o]; __syncthreads(); }
    float mu = red[0] * 0.01f; __syncthreads();
    float d = act ? (x - mu) : 0.f;
    red[t] = d * d; __syncthreads();
    for (int o = 64; o > 0; o >>= 1) { if (t < o) red[t] += red[t + o]; __syncthreads(); }
    float var = red[0] * 0.01f; __syncthreads();
    x = (x - mu) * rsqrtf(var + 1e-5f);
  }
  x *= 0.03125f;                                    // * C^{-1/2}
  red[t] = act ? x : -3.4e38f; __syncthreads();
  for (int o = 64; o > 0; o >>= 1) { if (t < o) red[t] = fmaxf(red[t], red[t + o]); __syncthreads(); }
  float mx = red[0]; __syncthreads();
  float e = act ? __expf(x - mx) : 0.f;
  red[t] = e; __syncthreads();
  for (int o = 64; o > 0; o >>= 1) { if (t < o) red[t] += red[t + o]; __syncthreads(); }
  float inv = 1.f / red[0];
  __syncthreads();
  if (t >= 1 && t < 100) L[t - 1] = e * inv;        // aw[k] = attn[k+1]
  if (t >= 99) L[t] = 0.f;                          // zero pad cols 99..127
}

// ------ 8. z = amp e^{i phase}/sqrt(2C), keep k<=512, ortho ifft along b ----
__global__ __launch_bounds__(576) void make_z_fftb(const float* __restrict__ dph,
                                                   const float* __restrict__ dam,
                                                   float* __restrict__ Zre,
                                                   float* __restrict__ Zim) {
  const int n = blockIdx.x;
  const int k = threadIdx.x;
  if (k >= 513) return;
  const float* pp = dph + (size_t)n * 8192 + k;
  const float* ap = dam + (size_t)n * 8192 + k;
  float zr[8], zi[8];
  const float invs = 0.022097086912079608f;         // 1/sqrt(2048)
#pragma unroll
  for (int b = 0; b < 8; ++b) {
    float p = pp[b * 1024], a = ap[b * 1024] * invs;
    float s, c; __sincosf(p, &s, &c);
    zr[b] = c * a; zi[b] = s * a;
  }
  const float cv[8] = {1.f, 0.70710678f, 0.f, -0.70710678f, -1.f, -0.70710678f, 0.f, 0.70710678f};
  const float sv[8] = {0.f, 0.70710678f, 1.f, 0.70710678f, 0.f, -0.70710678f, -1.f, -0.70710678f};
  float* zro = Zre + (size_t)n * 4160 + k;
  float* zio = Zim + (size_t)n * 4160 + k;
  const float inv8 = 0.35355339059327373f;          // 1/sqrt(8) (ortho)
#pragma unroll
  for (int bp = 0; bp < 8; ++bp) {
    float sr = 0.f, si = 0.f;
#pragma unroll
    for (int b = 0; b < 8; ++b) {
      const int p = (bp * b) & 7;                   // e^{+i pi p/4}
      sr += zr[b] * cv[p] - zi[b] * sv[p];
      si += zi[b] * cv[p] + zr[b] * sv[p];
    }
    zro[bp * 520] = sr * inv8;
    zio[bp * 520] = si * inv8;
  }
}

// --- 9. Hermitian extension + 1024-pt ortho ifft + out = x + delta*scale ----
__global__ __launch_bounds__(256) void inv_fft_c_final(const float* __restrict__ Zre,
                                                       const float* __restrict__ Zim,
                                                       const float* __restrict__ feats,
                                                       const float* __restrict__ scalep,
                                                       float* __restrict__ out) {
  __shared__ __align__(16) float re[1024];
  __shared__ __align__(16) float im[1024];
  __shared__ float twr[512], twi[512];
  const int t = threadIdx.x;
  const int row = blockIdx.x;                       // n*8 + bp
  const int n = row >> 3, bp = row & 7;
  const float* zr = Zre + (size_t)n * 4160 + (size_t)bp * 520;
  const float* zi = Zim + (size_t)n * 4160 + (size_t)bp * 520;
  for (int k = t; k < 512; k += 256) {
    float s, c;
    __sincosf(6.283185307179586f * (float)k * (1.0f / 1024.0f), &s, &c);
    twr[k] = c; twi[k] = s;                         // e^{+2pi i k/1024}
  }
  for (int i = t; i < 1024; i += 256) {
    int j = __brev((unsigned)i) >> 22;
    float vr, vi;
    if (i <= 512) { vr = zr[i]; vi = zi[i]; }
    else          { vr = zr[1024 - i]; vi = -zi[1024 - i]; }  // Hermitian ext
    re[j] = vr; im[j] = vi;
  }
  __syncthreads();
  for (int s = 1; s <= 10; ++s) {
    const int half = 1 << (s - 1);
    const int tshift = 10 - s;
    for (int b = t; b < 512; b += 256) {
      int j = b & (half - 1);
      int g = b >> (s - 1);
      int i0 = (g << s) + j;
      int i1 = i0 + half;
      float wr = twr[j << tshift], wi = twi[j << tshift];
      float xr = re[i1], xi = im[i1];
      float tr = wr * xr - wi * xi;
      float ti = wr * xi + wi * xr;
      float ur = re[i0], ui = im[i0];
      re[i0] = ur + tr; im[i0] = ui + ti;
      re[i1] = ur - tr; im[i1] = ui - ti;
    }
    __syncthreads();
  }
  const size_t ob = 8192 + (size_t)row * 1024;
  const float s = scalep[0] * 0.03125f;             // scale * 1/sqrt(1024)
  for (int c = t; c < 1024; c += 256)
    out[ob + c] = feats[ob + c] + re[c] * s;
}

__global__ __launch_bounds__(256) void copy_cls(const float* __restrict__ feats,
                                                float* __restrict__ out) {
  const int i = blockIdx.x * 256 + threadIdx.x;
  if (i < 8192) out[i] = feats[i];
}

// ---------------------------------------------------------------------------
extern "C" void kernel_launch(void* const* d_in, const int* in_sizes, int n_in,
                              void* d_out, int out_size, void* d_ws, size_t ws_size,
                              hipStream_t stream) {
  const float* feats  = (const float*)d_in[0];
  const float* lt1    = (const float*)d_in[1];
  const float* lt2    = (const float*)d_in[2];
  const float* w_t2f  = (const float*)d_in[3];
  const float* b_t2f  = (const float*)d_in[4];
  const float* w_df   = (const float*)d_in[5];
  const float* b_df   = (const float*)d_in[6];
  const float* w_t2f2 = (const float*)d_in[7];
  const float* b_t2f2 = (const float*)d_in[8];
  const float* w_df2  = (const float*)d_in[9];
  const float* b_df2  = (const float*)d_in[10];
  const float* scalep = (const float*)d_in[11];
  const int*   layerp = (const int*)d_in[12];
  float* out = (float*)d_out;
  float* ws  = (float*)d_ws;

  const size_t SZ = 8192ull * 1024ull;              // 8,388,608 floats
  float* W0 = ws;                  // Fre -> df_phase -> Zre (4,259,840 < SZ)
  float* W1 = W0 + SZ;             // Fim -> df_amp   -> Zim
  float* W2 = W1 + SZ;             // amp
  float* W3 = W2 + SZ;             // phase
  float* W4 = W3 + SZ;             // logits/aw in-place, 2 x 8192 x 128
  float* W5 = W4 + 2ull * 8192 * 128;   // B2, 2 x 1024 x 128
  float* W6 = W5 + 2ull * 1024 * 128;   // d_phase
  float* W7 = W6 + SZ;             // d_amp
  (void)in_sizes; (void)n_in; (void)out_size; (void)ws_size;

  // 1-2: forward FFT2 + amp/phase
  fwd_fft_c<<<dim3(8192), dim3(256), 0, stream>>>(feats, W0, W1);
  fwd_fft_b_amp<<<dim3(4096), dim3(256), 0, stream>>>(W0, W1, W2, W3);
  // 3: logits = P @ tokens^T   (M=8192, N=128(100), K=1024)
  gemm_bt<<<dim3(128, 2, 2), dim3(256), 0, stream>>>(
      W3, W2, (const float*)nullptr, (const float*)nullptr,
      lt1, lt2, (const float*)nullptr, (const float*)nullptr,
      W4, W4 + 8192 * 128, layerp, 1024, 100, 128);
  // 4: v^T (K-padded)
  compute_vT<<<dim3(1024, 2), dim3(128), 0, stream>>>(
      lt1, lt2, w_t2f, w_t2f2, b_t2f, b_t2f2, layerp, W5);
  // 5: instance-norm(amp path) + softmax, shifted in-place
  in_softmax<<<dim3(8192, 2), dim3(128), 0, stream>>>(W4);
  // 6: df = aw @ B2^T   (M=8192, N=1024, K=128)
  gemm_bt<<<dim3(128, 16, 2), dim3(256), 0, stream>>>(
      W4, W4 + 8192 * 128, (const float*)nullptr, (const float*)nullptr,
      W5, W5 + 1024 * 128, (const float*)nullptr, (const float*)nullptr,
      W0, W1, (const int*)nullptr, 128, 1024, 1024);
  // 7: d = (df + P) @ w_df^T + b_df   (M=8192, N=1024, K=1024)
  gemm_bt<<<dim3(128, 16, 2), dim3(256), 0, stream>>>(
      W0, W1, W3, W2, w_df, w_df2, b_df, b_df2,
      W6, W7, (const int*)nullptr, 1024, 1024, 1024);
  // 8: z + ortho 8-pt ifft along b
  make_z_fftb<<<dim3(1024), dim3(576), 0, stream>>>(W6, W7, W0, W1);
  // 9: ortho 1024-pt irfft along c + residual
  inv_fft_c_final<<<dim3(8192), dim3(256), 0, stream>>>(W0, W1, feats, scalep, out);
  // 10: cls token passthrough
  copy_cls<<<dim3(32), dim3(256), 0, stream>>>(feats, out);
}

// Round 2
// 570.299 us; speedup vs baseline: 1.1713x; 1.1713x over previous
//
#include <hip/hip_runtime.h>
#include <cstddef>

// ---------------------------------------------------------------------------
// Reins layer on MI355X — round 2.
// GEMMs rewritten to the m97 ladder structure: bf16 operands end-to-end,
// 128x128 tile, 4 waves x (4x4) 16x16x32 MFMA, global_load_lds width=16
// staging with XOR chunk swizzle. All fp32->bf16 conversion fused into
// producer kernels (fft_b_amp, softmax, vT, GEMM2 epilogue, weight convert).
// ---------------------------------------------------------------------------

using bf16x8 = __attribute__((ext_vector_type(8))) short;   // 8 bf16 in 4 VGPRs
using f32x4  = __attribute__((ext_vector_type(4))) float;

__device__ inline short f2bf(float f) {
  union { float f; unsigned u; } v; v.f = f;
  unsigned r = v.u + 0x7FFFu + ((v.u >> 16) & 1u);  // round-to-nearest-even
  return (short)(r >> 16);
}
__device__ inline float bf2f(short s) {
  union { unsigned u; float f; } v; v.u = ((unsigned)(unsigned short)s) << 16;
  return v.f;
}
__device__ inline void async16(const void* g, void* l) {
  __builtin_amdgcn_global_load_lds(
      (const __attribute__((address_space(1))) void*)g,
      (__attribute__((address_space(3))) void*)l, 16, 0, 0);
}

// ---------------- 1. forward 1024-pt FFT along C (real input) ---------------
__global__ __launch_bounds__(256) void fwd_fft_c(const float* __restrict__ feats,
                                                 float* __restrict__ Fre,
                                                 float* __restrict__ Fim) {
  __shared__ __align__(16) float re[1024];
  __shared__ __align__(16) float im[1024];
  __shared__ float twr[512], twi[512];
  const int t = threadIdx.x;
  const int row = blockIdx.x;                       // 0..8191 = n*8+b
  const float* src = feats + 8192 + (size_t)row * 1024;
  for (int k = t; k < 512; k += 256) {
    float s, c;
    __sincosf(-6.283185307179586f * (float)k * (1.0f / 1024.0f), &s, &c);
    twr[k] = c; twi[k] = s;                         // e^{-2pi i k/1024}
  }
  for (int i = t; i < 1024; i += 256) {
    int j = __brev((unsigned)i) >> 22;              // 10-bit reversal
    re[j] = src[i];
    im[j] = 0.0f;
  }
  __syncthreads();
  for (int s = 1; s <= 10; ++s) {
    const int half = 1 << (s - 1);
    const int tshift = 10 - s;
    for (int b = t; b < 512; b += 256) {
      int j = b & (half - 1);
      int g = b >> (s - 1);
      int i0 = (g << s) + j;
      int i1 = i0 + half;
      float wr = twr[j << tshift], wi = twi[j << tshift];
      float xr = re[i1], xi = im[i1];
      float tr = wr * xr - wi * xi;
      float ti = wr * xi + wi * xr;
      float ur = re[i0], ui = im[i0];
      re[i0] = ur + tr; im[i0] = ui + ti;
      re[i1] = ur - tr; im[i1] = ui - ti;
    }
    __syncthreads();
  }
  float* dr = Fre + (size_t)row * 1024;
  float* di = Fim + (size_t)row * 1024;
  for (int i = t; i < 1024; i += 256) { dr[i] = re[i]; di[i] = im[i]; }
}

// ------- 2. 8-pt FFT along B + amp/phase, output bf16 directly --------------
__global__ __launch_bounds__(256) void fwd_fft_b_amp(const float* __restrict__ Fre,
                                                     const float* __restrict__ Fim,
                                                     short* __restrict__ ampb,
                                                     short* __restrict__ phaseb) {
  const int idx = blockIdx.x * 256 + threadIdx.x;   // 0..1024*1024-1 : (n,c)
  const int n = idx >> 10, c = idx & 1023;
  const size_t base = (size_t)n * 8192 + c;
  float xr[8], xi[8];
#pragma unroll
  for (int b = 0; b < 8; ++b) { xr[b] = Fre[base + b * 1024]; xi[b] = Fim[base + b * 1024]; }
  const float cv[8] = {1.f, 0.70710678f, 0.f, -0.70710678f, -1.f, -0.70710678f, 0.f, 0.70710678f};
  const float sv[8] = {0.f, 0.70710678f, 1.f, 0.70710678f, 0.f, -0.70710678f, -1.f, -0.70710678f};
#pragma unroll
  for (int kb = 0; kb < 8; ++kb) {
    float sr = 0.f, si = 0.f;
#pragma unroll
    for (int b = 0; b < 8; ++b) {
      const int p = (kb * b) & 7;                   // e^{-i pi p/4}
      sr += xr[b] * cv[p] + xi[b] * sv[p];
      si += xi[b] * cv[p] - xr[b] * sv[p];
    }
    float r2 = sr * sr + si * si;
    if (r2 < 1e-5f) r2 = 1e-5f;                     // _replace_denormals(re^2+im^2)
    float a = sqrtf(r2);
    float rr = (sr < 1e-5f && sr > -1e-5f) ? 1e-5f : sr;
    float ph = atan2f(si, rr);
    ampb[base + kb * 1024] = f2bf(a);
    phaseb[base + kb * 1024] = f2bf(ph);
  }
}

// ------------- weight / token bf16 conversion (one-time, tiny) --------------
__global__ __launch_bounds__(256) void conv_w(const float* __restrict__ w1,
                                              const float* __restrict__ w2,
                                              short* __restrict__ dst) {
  const int z = blockIdx.y;
  const float* W = (z ? w2 : w1) + (size_t)blockIdx.x * 1024;
  short* D = dst + ((size_t)z * 1024 + blockIdx.x) * 1024;
  const int t = threadIdx.x * 4;
  float4 v = *(const float4*)(W + t);
  D[t] = f2bf(v.x); D[t + 1] = f2bf(v.y); D[t + 2] = f2bf(v.z); D[t + 3] = f2bf(v.w);
}

__global__ __launch_bounds__(256) void conv_tok(const float* __restrict__ lt1,
                                                const float* __restrict__ lt2,
                                                const int* __restrict__ layerp,
                                                short* __restrict__ dst) {
  const int z = blockIdx.y;
  const int row = blockIdx.x;                       // 0..127 (100 real, rest 0)
  short* D = dst + ((size_t)z * 128 + row) * 1024;
  const int t = threadIdx.x * 4;
  if (row < 100) {
    const float* S = (z ? lt2 : lt1) + (size_t)layerp[0] * 102400 + (size_t)row * 1024;
    float4 v = *(const float4*)(S + t);
    D[t] = f2bf(v.x); D[t + 1] = f2bf(v.y); D[t + 2] = f2bf(v.z); D[t + 3] = f2bf(v.w);
  } else {
    D[t] = 0; D[t + 1] = 0; D[t + 2] = 0; D[t + 3] = 0;
  }
}

// ------------- m97-style bf16 GEMM:  C = A(MxK) @ B(NxK)^T ------------------
// 128x128 tile, BK=32, 256 thr = 4 waves (2x2), global_load_lds staging with
// XOR chunk swizzle (chunk ^= (row>>1)&3) -> 2-way LDS conflicts (free).
__global__ __launch_bounds__(256) void gemm128(
    const short* A0, const short* A1,       // M x K bf16
    const short* B0, const short* B1,       // N x K bf16
    const short* Add0, const short* Add1,   // optional bf16 addend at C index
    const float* bias0, const float* bias1, // optional per-col fp32 bias
    void* C0v, void* C1v,
    int K, int ldc, int outBf16) {
  const int z = blockIdx.z;
  const short* A   = z ? A1 : A0;
  const short* B   = z ? B1 : B0;
  const short* Add = z ? Add1 : Add0;
  const float* bias = z ? bias1 : bias0;
  void* Cv = z ? C1v : C0v;

  __shared__ __align__(16) short As[128 * 32];
  __shared__ __align__(16) short Bs[128 * 32];

  const int tid = threadIdx.x;
  const int wave = tid >> 6, lane = tid & 63;
  const int m16 = lane & 15, quad = lane >> 4;
  const int wm = (wave & 1) * 64, wn = (wave >> 1) * 64;

  f32x4 acc[4][4];
#pragma unroll
  for (int i = 0; i < 4; ++i)
#pragma unroll
    for (int j = 0; j < 4; ++j) acc[i][j] = (f32x4){0.f, 0.f, 0.f, 0.f};

  // staging: 256 lanes x 16B x 2 halves per operand; source chunk XOR-swizzled
  const int r0 = tid >> 2;                              // 0..63
  const int csw = (((tid & 3) ^ ((r0 >> 1) & 3)) * 8);  // elems
  const short* aSrc0 = A + (size_t)(blockIdx.x * 128 + r0) * K + csw;
  const short* aSrc1 = aSrc0 + (size_t)64 * K;
  const short* bSrc0 = B + (size_t)(blockIdx.y * 128 + r0) * K + csw;
  const short* bSrc1 = bSrc0 + (size_t)64 * K;
  short* aDst0 = As + tid * 8;
  short* aDst1 = As + 2048 + tid * 8;
  short* bDst0 = Bs + tid * 8;
  short* bDst1 = Bs + 2048 + tid * 8;

  // fragment read: LDS chunk position quad^((row>>1)&3); row = 16*x + m16
  const int fcol = ((quad ^ ((m16 >> 1) & 3)) * 8) + m16 * 32;

  for (int k0 = 0; k0 < K; k0 += 32) {
    async16(aSrc0 + k0, aDst0);
    async16(aSrc1 + k0, aDst1);
    async16(bSrc0 + k0, bDst0);
    async16(bSrc1 + k0, bDst1);
    __syncthreads();
    bf16x8 af[4], bg[4];
#pragma unroll
    for (int ib = 0; ib < 4; ++ib)
      af[ib] = *(const bf16x8*)(As + (wm + ib * 16) * 32 + fcol);
#pragma unroll
    for (int jb = 0; jb < 4; ++jb)
      bg[jb] = *(const bf16x8*)(Bs + (wn + jb * 16) * 32 + fcol);
#pragma unroll
    for (int ib = 0; ib < 4; ++ib)
#pragma unroll
      for (int jb = 0; jb < 4; ++jb)
        acc[ib][jb] = __builtin_amdgcn_mfma_f32_16x16x32_bf16(af[ib], bg[jb], acc[ib][jb], 0, 0, 0);
    __syncthreads();
  }

#pragma unroll
  for (int ib = 0; ib < 4; ++ib) {
    const int rowb = blockIdx.x * 128 + wm + ib * 16 + quad * 4;
#pragma unroll
    for (int jb = 0; jb < 4; ++jb) {
      const int col = blockIdx.y * 128 + wn + jb * 16 + m16;
      const float bv = bias ? bias[col] : 0.f;
#pragma unroll
      for (int r = 0; r < 4; ++r) {
        const size_t idx = (size_t)(rowb + r) * (size_t)ldc + col;
        float v = acc[ib][jb][r] + bv;
        if (Add) v += bf2f(Add[idx]);
        if (outBf16) ((short*)Cv)[idx] = f2bf(v);
        else         ((float*)Cv)[idx] = v;
      }
    }
  }
}

// ---- v^T: B2[z][c][k] = tokens[1+k]·w_t2f[c] + b_t2f[c], bf16, K-pad 128 ---
__global__ __launch_bounds__(128) void compute_vT(
    const float* lt1, const float* lt2, const float* w1, const float* w2,
    const float* bb1, const float* bb2, const int* layerp, short* B2) {
  const int z = blockIdx.y;
  const int c = blockIdx.x;
  const float* tokens = (z ? lt2 : lt1) + (size_t)layerp[0] * 102400;
  const float* W = (z ? w2 : w1) + (size_t)c * 1024;
  const float* bias = z ? bb2 : bb1;
  __shared__ float wrow[1024];
  const int t = threadIdx.x;
  for (int i = t; i < 1024; i += 128) wrow[i] = W[i];
  __syncthreads();
  float acc = 0.f;
  if (t < 99) {
    const float* tok = tokens + (size_t)(t + 1) * 1024;
    for (int j = 0; j < 1024; j += 4) {
      float4 tv = *(const float4*)(tok + j);
      acc += wrow[j] * tv.x + wrow[j + 1] * tv.y + wrow[j + 2] * tv.z + wrow[j + 3] * tv.w;
    }
    acc += bias[c];
  }
  B2[((size_t)z * 1024 + c) * 128 + t] = (t < 99) ? f2bf(acc) : (short)0;
}

// ---- (instance-norm for z=1) + softmax(x/32); fp32 in -> shifted bf16 out --
__global__ __launch_bounds__(128) void in_softmax(const float* __restrict__ logits,
                                                  short* __restrict__ awb) {
  const int z = blockIdx.y;
  const float* L = logits + ((size_t)z * 8192 + blockIdx.x) * 128;
  short* A = awb + ((size_t)z * 8192 + blockIdx.x) * 128;
  const int t = threadIdx.x;
  const bool act = t < 100;
  float x = act ? L[t] : 0.f;
  __shared__ float red[128];
  if (z == 1) {
    red[t] = act ? x : 0.f; __syncthreads();
    for (int o = 64; o > 0; o >>= 1) { if (t < o) red[t] += red[t + o]; __syncthreads(); }
    float mu = red[0] * 0.01f; __syncthreads();
    float d = act ? (x - mu) : 0.f;
    red[t] = d * d; __syncthreads();
    for (int o = 64; o > 0; o >>= 1) { if (t < o) red[t] += red[t + o]; __syncthreads(); }
    float var = red[0] * 0.01f; __syncthreads();
    x = (x - mu) * rsqrtf(var + 1e-5f);
  }
  x *= 0.03125f;                                    // * C^{-1/2}
  red[t] = act ? x : -3.4e38f; __syncthreads();
  for (int o = 64; o > 0; o >>= 1) { if (t < o) red[t] = fmaxf(red[t], red[t + o]); __syncthreads(); }
  float mx = red[0]; __syncthreads();
  float e = act ? __expf(x - mx) : 0.f;
  red[t] = e; __syncthreads();
  for (int o = 64; o > 0; o >>= 1) { if (t < o) red[t] += red[t + o]; __syncthreads(); }
  float inv = 1.f / red[0];
  __syncthreads();
  if (t >= 1 && t < 100) A[t - 1] = f2bf(e * inv);  // aw[k] = attn[k+1]
  if (t >= 99) A[t] = 0;                            // zero pad 99..127
}

// ------ z = amp e^{i phase}/sqrt(2C), keep k<=512, ortho ifft along b -------
__global__ __launch_bounds__(576) void make_z_fftb(const float* __restrict__ dph,
                                                   const float* __restrict__ dam,
                                                   float* __restrict__ Zre,
                                                   float* __restrict__ Zim) {
  const int n = blockIdx.x;
  const int k = threadIdx.x;
  if (k >= 513) return;
  const float* pp = dph + (size_t)n * 8192 + k;
  const float* ap = dam + (size_t)n * 8192 + k;
  float zr[8], zi[8];
  const float invs = 0.022097086912079608f;         // 1/sqrt(2048)
#pragma unroll
  for (int b = 0; b < 8; ++b) {
    float p = pp[b * 1024], a = ap[b * 1024] * invs;
    float s, c; __sincosf(p, &s, &c);
    zr[b] = c * a; zi[b] = s * a;
  }
  const float cv[8] = {1.f, 0.70710678f, 0.f, -0.70710678f, -1.f, -0.70710678f, 0.f, 0.70710678f};
  const float sv[8] = {0.f, 0.70710678f, 1.f, 0.70710678f, 0.f, -0.70710678f, -1.f, -0.70710678f};
  float* zro = Zre + (size_t)n * 4160 + k;
  float* zio = Zim + (size_t)n * 4160 + k;
  const float inv8 = 0.35355339059327373f;          // 1/sqrt(8) (ortho)
#pragma unroll
  for (int bp = 0; bp < 8; ++bp) {
    float sr = 0.f, si = 0.f;
#pragma unroll
    for (int b = 0; b < 8; ++b) {
      const int p = (bp * b) & 7;                   // e^{+i pi p/4}
      sr += zr[b] * cv[p] - zi[b] * sv[p];
      si += zi[b] * cv[p] + zr[b] * sv[p];
    }
    zro[bp * 520] = sr * inv8;
    zio[bp * 520] = si * inv8;
  }
}

// --- Hermitian extension + 1024-pt ortho ifft + out = x + delta*scale -------
__global__ __launch_bounds__(256) void inv_fft_c_final(const float* __restrict__ Zre,
                                                       const float* __restrict__ Zim,
                                                       const float* __restrict__ feats,
                                                       const float* __restrict__ scalep,
                                                       float* __restrict__ out) {
  __shared__ __align__(16) float re[1024];
  __shared__ __align__(16) float im[1024];
  __shared__ float twr[512], twi[512];
  const int t = threadIdx.x;
  const int row = blockIdx.x;                       // n*8 + bp
  const int n = row >> 3, bp = row & 7;
  const float* zr = Zre + (size_t)n * 4160 + (size_t)bp * 520;
  const float* zi = Zim + (size_t)n * 4160 + (size_t)bp * 520;
  for (int k = t; k < 512; k += 256) {
    float s, c;
    __sincosf(6.283185307179586f * (float)k * (1.0f / 1024.0f), &s, &c);
    twr[k] = c; twi[k] = s;                         // e^{+2pi i k/1024}
  }
  for (int i = t; i < 1024; i += 256) {
    int j = __brev((unsigned)i) >> 22;
    float vr, vi;
    if (i <= 512) { vr = zr[i]; vi = zi[i]; }
    else          { vr = zr[1024 - i]; vi = -zi[1024 - i]; }  // Hermitian ext
    re[j] = vr; im[j] = vi;
  }
  __syncthreads();
  for (int s = 1; s <= 10; ++s) {
    const int half = 1 << (s - 1);
    const int tshift = 10 - s;
    for (int b = t; b < 512; b += 256) {
      int j = b & (half - 1);
      int g = b >> (s - 1);
      int i0 = (g << s) + j;
      int i1 = i0 + half;
      float wr = twr[j << tshift], wi = twi[j << tshift];
      float xr = re[i1], xi = im[i1];
      float tr = wr * xr - wi * xi;
      float ti = wr * xi + wi * xr;
      float ur = re[i0], ui = im[i0];
      re[i0] = ur + tr; im[i0] = ui + ti;
      re[i1] = ur - tr; im[i1] = ui - ti;
    }
    __syncthreads();
  }
  const size_t ob = 8192 + (size_t)row * 1024;
  const float s = scalep[0] * 0.03125f;             // scale * 1/sqrt(1024)
  for (int c = t; c < 1024; c += 256)
    out[ob + c] = feats[ob + c] + re[c] * s;
}

__global__ __launch_bounds__(256) void copy_cls(const float* __restrict__ feats,
                                                float* __restrict__ out) {
  const int i = blockIdx.x * 256 + threadIdx.x;
  if (i < 8192) out[i] = feats[i];
}

// ---------------------------------------------------------------------------
extern "C" void kernel_launch(void* const* d_in, const int* in_sizes, int n_in,
                              void* d_out, int out_size, void* d_ws, size_t ws_size,
                              hipStream_t stream) {
  const float* feats  = (const float*)d_in[0];
  const float* lt1    = (const float*)d_in[1];
  const float* lt2    = (const float*)d_in[2];
  const float* w_t2f  = (const float*)d_in[3];
  const float* b_t2f  = (const float*)d_in[4];
  const float* w_df   = (const float*)d_in[5];
  const float* b_df   = (const float*)d_in[6];
  const float* w_t2f2 = (const float*)d_in[7];
  const float* b_t2f2 = (const float*)d_in[8];
  const float* w_df2  = (const float*)d_in[9];
  const float* b_df2  = (const float*)d_in[10];
  const float* scalep = (const float*)d_in[11];
  const int*   layerp = (const int*)d_in[12];
  float* out = (float*)d_out;
  float* ws  = (float*)d_ws;
  (void)in_sizes; (void)n_in; (void)out_size; (void)ws_size;

  const size_t SZ = 8192ull * 1024ull;              // 8,388,608 floats
  float* W0  = ws;                  // Fre -> XP bf16 (2 x 8192x1024 shorts) -> Zre
  float* W1  = W0 + SZ;             // Fim -> d_phase fp32
  float* W2  = W1 + SZ;             // d_amp fp32
  float* PAB = W2 + SZ;             // phase_bf + amp_bf (shorts) -> Zim
  short* Pa  = (short*)PAB;                    // phase bf16, 8192x1024
  short* Pb  = Pa + SZ;                        // amp   bf16, 8192x1024
  float* L   = PAB + SZ;            // logits fp32, 2 x 8192x128
  short* awb = (short*)(L + 2ull * 8192 * 128);     // aw bf16, 2 x 8192x128
  short* Wtok = awb + 2ull * 8192 * 128;            // tokens bf16, 2 x 128x1024
  short* Wwdf = Wtok + 2ull * 128 * 1024;           // w_df bf16,  2 x 1024x1024
  short* B2   = Wwdf + 2ull * 1024 * 1024;          // v^T bf16,   2 x 1024x128
  short* XP0 = (short*)W0;                          // (df+P) bf16
  short* XP1 = XP0 + SZ;
  float* Zre = W0;                                  // reuse after GEMM3
  float* Zim = PAB;

  // 1-2: forward FFT2 + amp/phase (bf16 out)
  fwd_fft_c<<<dim3(8192), dim3(256), 0, stream>>>(feats, W0, W1);
  fwd_fft_b_amp<<<dim3(4096), dim3(256), 0, stream>>>(W0, W1, Pb, Pa);
  // operand conversion (tiny)
  conv_w<<<dim3(1024, 2), dim3(256), 0, stream>>>(w_df, w_df2, Wwdf);
  conv_tok<<<dim3(128, 2), dim3(256), 0, stream>>>(lt1, lt2, layerp, Wtok);
  // GEMM1: logits = P @ tokens^T  (M=8192, N=128, K=1024), fp32 out
  gemm128<<<dim3(64, 1, 2), dim3(256), 0, stream>>>(
      Pa, Pb, Wtok, Wtok + 128 * 1024,
      (const short*)nullptr, (const short*)nullptr,
      (const float*)nullptr, (const float*)nullptr,
      L, L + 8192 * 128, 1024, 128, 0);
  // v^T (K-padded bf16)
  compute_vT<<<dim3(1024, 2), dim3(128), 0, stream>>>(
      lt1, lt2, w_t2f, w_t2f2, b_t2f, b_t2f2, layerp, B2);
  // instance-norm(amp) + softmax -> shifted bf16 aw
  in_softmax<<<dim3(8192, 2), dim3(128), 0, stream>>>(L, awb);
  // GEMM2: XP = aw @ B2^T + P  (M=8192, N=1024, K=128), bf16 out
  gemm128<<<dim3(64, 8, 2), dim3(256), 0, stream>>>(
      awb, awb + 8192 * 128, B2, B2 + 1024 * 128,
      Pa, Pb, (const float*)nullptr, (const float*)nullptr,
      XP0, XP1, 128, 1024, 1);
  // GEMM3: d = XP @ w_df^T + b_df  (M=8192, N=1024, K=1024), fp32 out
  gemm128<<<dim3(64, 8, 2), dim3(256), 0, stream>>>(
      XP0, XP1, Wwdf, Wwdf + 1024 * 1024,
      (const short*)nullptr, (const short*)nullptr,
      b_df, b_df2, W1, W2, 1024, 1024, 0);
  // z + ortho 8-pt ifft along b
  make_z_fftb<<<dim3(1024), dim3(576), 0, stream>>>(W1, W2, Zre, Zim);
  // ortho 1024-pt irfft along c + residual
  inv_fft_c_final<<<dim3(8192), dim3(256), 0, stream>>>(Zre, Zim, feats, scalep, out);
  // cls token passthrough
  copy_cls<<<dim3(32), dim3(256), 0, stream>>>(feats, out);
}

// Round 3
// 505.138 us; speedup vs baseline: 1.3224x; 1.1290x over previous
//
#include <hip/hip_runtime.h>
#include <cstddef>

// ---------------------------------------------------------------------------
// Reins layer on MI355X — round 3.
// R2 ladder (bf16 end-to-end, 128x128 MFMA tiles, global_load_lds) kept.
// R3: compute_vT (104 us latency-bound loop) replaced by a gemm128 call with
// per-row bias; weight/token converts merged into single dispatches.
// ---------------------------------------------------------------------------

using bf16x8 = __attribute__((ext_vector_type(8))) short;   // 8 bf16 in 4 VGPRs
using f32x4  = __attribute__((ext_vector_type(4))) float;

__device__ inline short f2bf(float f) {
  union { float f; unsigned u; } v; v.f = f;
  unsigned r = v.u + 0x7FFFu + ((v.u >> 16) & 1u);  // round-to-nearest-even
  return (short)(r >> 16);
}
__device__ inline float bf2f(short s) {
  union { unsigned u; float f; } v; v.u = ((unsigned)(unsigned short)s) << 16;
  return v.f;
}
__device__ inline void async16(const void* g, void* l) {
  __builtin_amdgcn_global_load_lds(
      (const __attribute__((address_space(1))) void*)g,
      (__attribute__((address_space(3))) void*)l, 16, 0, 0);
}

// ---------------- 1. forward 1024-pt FFT along C (real input) ---------------
__global__ __launch_bounds__(256) void fwd_fft_c(const float* __restrict__ feats,
                                                 float* __restrict__ Fre,
                                                 float* __restrict__ Fim) {
  __shared__ __align__(16) float re[1024];
  __shared__ __align__(16) float im[1024];
  __shared__ float twr[512], twi[512];
  const int t = threadIdx.x;
  const int row = blockIdx.x;                       // 0..8191 = n*8+b
  const float* src = feats + 8192 + (size_t)row * 1024;
  for (int k = t; k < 512; k += 256) {
    float s, c;
    __sincosf(-6.283185307179586f * (float)k * (1.0f / 1024.0f), &s, &c);
    twr[k] = c; twi[k] = s;                         // e^{-2pi i k/1024}
  }
  for (int i = t; i < 1024; i += 256) {
    int j = __brev((unsigned)i) >> 22;              // 10-bit reversal
    re[j] = src[i];
    im[j] = 0.0f;
  }
  __syncthreads();
  for (int s = 1; s <= 10; ++s) {
    const int half = 1 << (s - 1);
    const int tshift = 10 - s;
    for (int b = t; b < 512; b += 256) {
      int j = b & (half - 1);
      int g = b >> (s - 1);
      int i0 = (g << s) + j;
      int i1 = i0 + half;
      float wr = twr[j << tshift], wi = twi[j << tshift];
      float xr = re[i1], xi = im[i1];
      float tr = wr * xr - wi * xi;
      float ti = wr * xi + wi * xr;
      float ur = re[i0], ui = im[i0];
      re[i0] = ur + tr; im[i0] = ui + ti;
      re[i1] = ur - tr; im[i1] = ui - ti;
    }
    __syncthreads();
  }
  float* dr = Fre + (size_t)row * 1024;
  float* di = Fim + (size_t)row * 1024;
  for (int i = t; i < 1024; i += 256) { dr[i] = re[i]; di[i] = im[i]; }
}

// ------- 2. 8-pt FFT along B + amp/phase, output bf16 directly --------------
__global__ __launch_bounds__(256) void fwd_fft_b_amp(const float* __restrict__ Fre,
                                                     const float* __restrict__ Fim,
                                                     short* __restrict__ ampb,
                                                     short* __restrict__ phaseb) {
  const int idx = blockIdx.x * 256 + threadIdx.x;   // 0..1024*1024-1 : (n,c)
  const int n = idx >> 10, c = idx & 1023;
  const size_t base = (size_t)n * 8192 + c;
  float xr[8], xi[8];
#pragma unroll
  for (int b = 0; b < 8; ++b) { xr[b] = Fre[base + b * 1024]; xi[b] = Fim[base + b * 1024]; }
  const float cv[8] = {1.f, 0.70710678f, 0.f, -0.70710678f, -1.f, -0.70710678f, 0.f, 0.70710678f};
  const float sv[8] = {0.f, 0.70710678f, 1.f, 0.70710678f, 0.f, -0.70710678f, -1.f, -0.70710678f};
#pragma unroll
  for (int kb = 0; kb < 8; ++kb) {
    float sr = 0.f, si = 0.f;
#pragma unroll
    for (int b = 0; b < 8; ++b) {
      const int p = (kb * b) & 7;                   // e^{-i pi p/4}
      sr += xr[b] * cv[p] + xi[b] * sv[p];
      si += xi[b] * cv[p] - xr[b] * sv[p];
    }
    float r2 = sr * sr + si * si;
    if (r2 < 1e-5f) r2 = 1e-5f;                     // _replace_denormals(re^2+im^2)
    float a = sqrtf(r2);
    float rr = (sr < 1e-5f && sr > -1e-5f) ? 1e-5f : sr;
    float ph = atan2f(si, rr);
    ampb[base + kb * 1024] = f2bf(a);
    phaseb[base + kb * 1024] = f2bf(ph);
  }
}

// ---- weight bf16 convert: 4 matrices [w_t2f, w_t2f2, w_df, w_df2] ----------
__global__ __launch_bounds__(256) void conv_w(const float* __restrict__ w1,
                                              const float* __restrict__ w2,
                                              const float* __restrict__ w3,
                                              const float* __restrict__ w4,
                                              short* __restrict__ dst) {
  const int z = blockIdx.y;                         // 0..3
  const float* W = (z == 0 ? w1 : z == 1 ? w2 : z == 2 ? w3 : w4)
                   + (size_t)blockIdx.x * 1024;
  short* D = dst + ((size_t)z * 1024 + blockIdx.x) * 1024;
  const int t = threadIdx.x * 4;
  float4 v = *(const float4*)(W + t);
  D[t] = f2bf(v.x); D[t + 1] = f2bf(v.y); D[t + 2] = f2bf(v.z); D[t + 3] = f2bf(v.w);
}

// ---- token bf16 convert: [z0 s0, z1 s0, z0 s1, z1 s1], rows zero-padded ----
__global__ __launch_bounds__(256) void conv_tok(const float* __restrict__ lt1,
                                                const float* __restrict__ lt2,
                                                const int* __restrict__ layerp,
                                                short* __restrict__ dst) {
  const int zz = blockIdx.y;                        // z = zz&1, shift = zz>>1
  const int z = zz & 1, shift = zz >> 1;
  const int row = blockIdx.x;                       // 0..127
  short* D = dst + ((size_t)zz * 128 + row) * 1024;
  const int t = threadIdx.x * 4;
  if (row + shift < 100) {
    const float* S = (z ? lt2 : lt1) + (size_t)layerp[0] * 102400
                     + (size_t)(row + shift) * 1024;
    float4 v = *(const float4*)(S + t);
    D[t] = f2bf(v.x); D[t + 1] = f2bf(v.y); D[t + 2] = f2bf(v.z); D[t + 3] = f2bf(v.w);
  } else {
    D[t] = 0; D[t + 1] = 0; D[t + 2] = 0; D[t + 3] = 0;
  }
}

// ------------- m97-style bf16 GEMM:  C = A(MxK) @ B(NxK)^T ------------------
// 128x128 tile, BK=32, 256 thr = 4 waves (2x2), global_load_lds staging with
// XOR chunk swizzle.  biasMode: 0=none, 1=per-col, 2=per-row.
__global__ __launch_bounds__(256) void gemm128(
    const short* A0, const short* A1,       // M x K bf16
    const short* B0, const short* B1,       // N x K bf16
    const short* Add0, const short* Add1,   // optional bf16 addend at C index
    const float* bias0, const float* bias1, // optional fp32 bias
    void* C0v, void* C1v,
    int K, int ldc, int outBf16, int biasMode) {
  const int z = blockIdx.z;
  const short* A   = z ? A1 : A0;
  const short* B   = z ? B1 : B0;
  const short* Add = z ? Add1 : Add0;
  const float* bias = z ? bias1 : bias0;
  void* Cv = z ? C1v : C0v;

  __shared__ __align__(16) short As[128 * 32];
  __shared__ __align__(16) short Bs[128 * 32];

  const int tid = threadIdx.x;
  const int wave = tid >> 6, lane = tid & 63;
  const int m16 = lane & 15, quad = lane >> 4;
  const int wm = (wave & 1) * 64, wn = (wave >> 1) * 64;

  f32x4 acc[4][4];
#pragma unroll
  for (int i = 0; i < 4; ++i)
#pragma unroll
    for (int j = 0; j < 4; ++j) acc[i][j] = (f32x4){0.f, 0.f, 0.f, 0.f};

  const int r0 = tid >> 2;                              // 0..63
  const int csw = (((tid & 3) ^ ((r0 >> 1) & 3)) * 8);  // elems
  const short* aSrc0 = A + (size_t)(blockIdx.x * 128 + r0) * K + csw;
  const short* aSrc1 = aSrc0 + (size_t)64 * K;
  const short* bSrc0 = B + (size_t)(blockIdx.y * 128 + r0) * K + csw;
  const short* bSrc1 = bSrc0 + (size_t)64 * K;
  short* aDst0 = As + tid * 8;
  short* aDst1 = As + 2048 + tid * 8;
  short* bDst0 = Bs + tid * 8;
  short* bDst1 = Bs + 2048 + tid * 8;

  const int fcol = ((quad ^ ((m16 >> 1) & 3)) * 8) + m16 * 32;

  for (int k0 = 0; k0 < K; k0 += 32) {
    async16(aSrc0 + k0, aDst0);
    async16(aSrc1 + k0, aDst1);
    async16(bSrc0 + k0, bDst0);
    async16(bSrc1 + k0, bDst1);
    __syncthreads();
    bf16x8 af[4], bg[4];
#pragma unroll
    for (int ib = 0; ib < 4; ++ib)
      af[ib] = *(const bf16x8*)(As + (wm + ib * 16) * 32 + fcol);
#pragma unroll
    for (int jb = 0; jb < 4; ++jb)
      bg[jb] = *(const bf16x8*)(Bs + (wn + jb * 16) * 32 + fcol);
#pragma unroll
    for (int ib = 0; ib < 4; ++ib)
#pragma unroll
      for (int jb = 0; jb < 4; ++jb)
        acc[ib][jb] = __builtin_amdgcn_mfma_f32_16x16x32_bf16(af[ib], bg[jb], acc[ib][jb], 0, 0, 0);
    __syncthreads();
  }

#pragma unroll
  for (int ib = 0; ib < 4; ++ib) {
    const int rowb = blockIdx.x * 128 + wm + ib * 16 + quad * 4;
#pragma unroll
    for (int jb = 0; jb < 4; ++jb) {
      const int col = blockIdx.y * 128 + wn + jb * 16 + m16;
      const float bcv = (biasMode == 1) ? bias[col] : 0.f;
#pragma unroll
      for (int r = 0; r < 4; ++r) {
        const size_t idx = (size_t)(rowb + r) * (size_t)ldc + col;
        float v = acc[ib][jb][r] + bcv;
        if (biasMode == 2) v += bias[rowb + r];
        if (Add) v += bf2f(Add[idx]);
        if (outBf16) ((short*)Cv)[idx] = f2bf(v);
        else         ((float*)Cv)[idx] = v;
      }
    }
  }
}

// ---- (instance-norm for z=1) + softmax(x/32); fp32 in -> shifted bf16 out --
__global__ __launch_bounds__(128) void in_softmax(const float* __restrict__ logits,
                                                  short* __restrict__ awb) {
  const int z = blockIdx.y;
  const float* L = logits + ((size_t)z * 8192 + blockIdx.x) * 128;
  short* A = awb + ((size_t)z * 8192 + blockIdx.x) * 128;
  const int t = threadIdx.x;
  const bool act = t < 100;
  float x = act ? L[t] : 0.f;
  __shared__ float red[128];
  if (z == 1) {
    red[t] = act ? x : 0.f; __syncthreads();
    for (int o = 64; o > 0; o >>= 1) { if (t < o) red[t] += red[t + o]; __syncthreads(); }
    float mu = red[0] * 0.01f; __syncthreads();
    float d = act ? (x - mu) : 0.f;
    red[t] = d * d; __syncthreads();
    for (int o = 64; o > 0; o >>= 1) { if (t < o) red[t] += red[t + o]; __syncthreads(); }
    float var = red[0] * 0.01f; __syncthreads();
    x = (x - mu) * rsqrtf(var + 1e-5f);
  }
  x *= 0.03125f;                                    // * C^{-1/2}
  red[t] = act ? x : -3.4e38f; __syncthreads();
  for (int o = 64; o > 0; o >>= 1) { if (t < o) red[t] = fmaxf(red[t], red[t + o]); __syncthreads(); }
  float mx = red[0]; __syncthreads();
  float e = act ? __expf(x - mx) : 0.f;
  red[t] = e; __syncthreads();
  for (int o = 64; o > 0; o >>= 1) { if (t < o) red[t] += red[t + o]; __syncthreads(); }
  float inv = 1.f / red[0];
  __syncthreads();
  if (t >= 1 && t < 100) A[t - 1] = f2bf(e * inv);  // aw[k] = attn[k+1]
  if (t >= 99) A[t] = 0;                            // zero pad 99..127
}

// ------ z = amp e^{i phase}/sqrt(2C), keep k<=512, ortho ifft along b -------
__global__ __launch_bounds__(576) void make_z_fftb(const float* __restrict__ dph,
                                                   const float* __restrict__ dam,
                                                   float* __restrict__ Zre,
                                                   float* __restrict__ Zim) {
  const int n = blockIdx.x;
  const int k = threadIdx.x;
  if (k >= 513) return;
  const float* pp = dph + (size_t)n * 8192 + k;
  const float* ap = dam + (size_t)n * 8192 + k;
  float zr[8], zi[8];
  const float invs = 0.022097086912079608f;         // 1/sqrt(2048)
#pragma unroll
  for (int b = 0; b < 8; ++b) {
    float p = pp[b * 1024], a = ap[b * 1024] * invs;
    float s, c; __sincosf(p, &s, &c);
    zr[b] = c * a; zi[b] = s * a;
  }
  const float cv[8] = {1.f, 0.70710678f, 0.f, -0.70710678f, -1.f, -0.70710678f, 0.f, 0.70710678f};
  const float sv[8] = {0.f, 0.70710678f, 1.f, 0.70710678f, 0.f, -0.70710678f, -1.f, -0.70710678f};
  float* zro = Zre + (size_t)n * 4160 + k;
  float* zio = Zim + (size_t)n * 4160 + k;
  const float inv8 = 0.35355339059327373f;          // 1/sqrt(8) (ortho)
#pragma unroll
  for (int bp = 0; bp < 8; ++bp) {
    float sr = 0.f, si = 0.f;
#pragma unroll
    for (int b = 0; b < 8; ++b) {
      const int p = (bp * b) & 7;                   // e^{+i pi p/4}
      sr += zr[b] * cv[p] - zi[b] * sv[p];
      si += zi[b] * cv[p] + zr[b] * sv[p];
    }
    zro[bp * 520] = sr * inv8;
    zio[bp * 520] = si * inv8;
  }
}

// --- Hermitian extension + 1024-pt ortho ifft + out = x + delta*scale -------
__global__ __launch_bounds__(256) void inv_fft_c_final(const float* __restrict__ Zre,
                                                       const float* __restrict__ Zim,
                                                       const float* __restrict__ feats,
                                                       const float* __restrict__ scalep,
                                                       float* __restrict__ out) {
  __shared__ __align__(16) float re[1024];
  __shared__ __align__(16) float im[1024];
  __shared__ float twr[512], twi[512];
  const int t = threadIdx.x;
  const int row = blockIdx.x;                       // n*8 + bp
  const int n = row >> 3, bp = row & 7;
  const float* zr = Zre + (size_t)n * 4160 + (size_t)bp * 520;
  const float* zi = Zim + (size_t)n * 4160 + (size_t)bp * 520;
  for (int k = t; k < 512; k += 256) {
    float s, c;
    __sincosf(6.283185307179586f * (float)k * (1.0f / 1024.0f), &s, &c);
    twr[k] = c; twi[k] = s;                         // e^{+2pi i k/1024}
  }
  for (int i = t; i < 1024; i += 256) {
    int j = __brev((unsigned)i) >> 22;
    float vr, vi;
    if (i <= 512) { vr = zr[i]; vi = zi[i]; }
    else          { vr = zr[1024 - i]; vi = -zi[1024 - i]; }  // Hermitian ext
    re[j] = vr; im[j] = vi;
  }
  __syncthreads();
  for (int s = 1; s <= 10; ++s) {
    const int half = 1 << (s - 1);
    const int tshift = 10 - s;
    for (int b = t; b < 512; b += 256) {
      int j = b & (half - 1);
      int g = b >> (s - 1);
      int i0 = (g << s) + j;
      int i1 = i0 + half;
      float wr = twr[j << tshift], wi = twi[j << tshift];
      float xr = re[i1], xi = im[i1];
      float tr = wr * xr - wi * xi;
      float ti = wr * xi + wi * xr;
      float ur = re[i0], ui = im[i0];
      re[i0] = ur + tr; im[i0] = ui + ti;
      re[i1] = ur - tr; im[i1] = ui - ti;
    }
    __syncthreads();
  }
  const size_t ob = 8192 + (size_t)row * 1024;
  const float s = scalep[0] * 0.03125f;             // scale * 1/sqrt(1024)
  for (int c = t; c < 1024; c += 256)
    out[ob + c] = feats[ob + c] + re[c] * s;
}

__global__ __launch_bounds__(256) void copy_cls(const float* __restrict__ feats,
                                                float* __restrict__ out) {
  const int i = blockIdx.x * 256 + threadIdx.x;
  if (i < 8192) out[i] = feats[i];
}

// ---------------------------------------------------------------------------
extern "C" void kernel_launch(void* const* d_in, const int* in_sizes, int n_in,
                              void* d_out, int out_size, void* d_ws, size_t ws_size,
                              hipStream_t stream) {
  const float* feats  = (const float*)d_in[0];
  const float* lt1    = (const float*)d_in[1];
  const float* lt2    = (const float*)d_in[2];
  const float* w_t2f  = (const float*)d_in[3];
  const float* b_t2f  = (const float*)d_in[4];
  const float* w_df   = (const float*)d_in[5];
  const float* b_df   = (const float*)d_in[6];
  const float* w_t2f2 = (const float*)d_in[7];
  const float* b_t2f2 = (const float*)d_in[8];
  const float* w_df2  = (const float*)d_in[9];
  const float* b_df2  = (const float*)d_in[10];
  const float* scalep = (const float*)d_in[11];
  const int*   layerp = (const int*)d_in[12];
  float* out = (float*)d_out;
  float* ws  = (float*)d_ws;
  (void)in_sizes; (void)n_in; (void)out_size; (void)ws_size;

  const size_t SZ = 8192ull * 1024ull;              // 8,388,608 elements
  float* W0  = ws;                        // 32MB: Fre -> XP bf16 pair -> Zre
  float* W1  = W0 + SZ;                   // 32MB: Fim -> d_phase fp32
  float* W2  = W1 + SZ;                   // 32MB: d_amp fp32
  float* PAB = W2 + SZ;                   // 32MB: Pa,Pb bf16 -> Zim
  short* Pa  = (short*)PAB;                         // phase bf16, 8192x1024
  short* Pb  = Pa + SZ;                             // amp   bf16, 8192x1024
  float* L   = PAB + SZ;                  // logits fp32, 2 x 8192x128
  short* awb = (short*)(L + 2ull * 8192 * 128);     // aw bf16, 2 x 8192x128
  short* Tok = awb + 2ull * 8192 * 128;             // tokens bf16, 4 x 128x1024
  short* Wall = Tok + 4ull * 128 * 1024;            // weights bf16, 4 x 1024x1024
  short* B2   = Wall + 4ull * 1024 * 1024;          // v^T bf16, 2 x 1024x128
  short* XP0 = (short*)W0;                          // (df+P) bf16
  short* XP1 = XP0 + SZ;
  float* Zre = W0;                                  // reuse after GEMM3
  float* Zim = PAB;

  // 1-2: forward FFT2 + amp/phase (bf16 out)
  fwd_fft_c<<<dim3(8192), dim3(256), 0, stream>>>(feats, W0, W1);
  fwd_fft_b_amp<<<dim3(4096), dim3(256), 0, stream>>>(W0, W1, Pb, Pa);
  // operand conversion (tiny): weights [w_t2f, w_t2f2, w_df, w_df2], tokens
  conv_w<<<dim3(1024, 4), dim3(256), 0, stream>>>(w_t2f, w_t2f2, w_df, w_df2, Wall);
  conv_tok<<<dim3(128, 4), dim3(256), 0, stream>>>(lt1, lt2, layerp, Tok);
  // GEMM1: logits = P @ tokens^T  (M=8192, N=128, K=1024), fp32 out
  gemm128<<<dim3(64, 1, 2), dim3(256), 0, stream>>>(
      Pa, Pb, Tok, Tok + 128 * 1024,
      (const short*)nullptr, (const short*)nullptr,
      (const float*)nullptr, (const float*)nullptr,
      L, L + 8192 * 128, 1024, 128, 0, 0);
  // GEMM-vT: B2 = W_t2f @ Vtok^T + b_t2f (row bias)  (M=1024, N=128, K=1024)
  gemm128<<<dim3(8, 1, 2), dim3(256), 0, stream>>>(
      Wall, Wall + 1024 * 1024,
      Tok + 2 * 128 * 1024, Tok + 3 * 128 * 1024,
      (const short*)nullptr, (const short*)nullptr,
      b_t2f, b_t2f2,
      B2, B2 + 1024 * 128, 1024, 128, 1, 2);
  // instance-norm(amp) + softmax -> shifted bf16 aw
  in_softmax<<<dim3(8192, 2), dim3(128), 0, stream>>>(L, awb);
  // GEMM2: XP = aw @ B2^T + P  (M=8192, N=1024, K=128), bf16 out
  gemm128<<<dim3(64, 8, 2), dim3(256), 0, stream>>>(
      awb, awb + 8192 * 128, B2, B2 + 1024 * 128,
      Pa, Pb, (const float*)nullptr, (const float*)nullptr,
      XP0, XP1, 128, 1024, 1, 0);
  // GEMM3: d = XP @ w_df^T + b_df  (M=8192, N=1024, K=1024), fp32 out
  gemm128<<<dim3(64, 8, 2), dim3(256), 0, stream>>>(
      XP0, XP1, Wall + 2 * 1024 * 1024, Wall + 3 * 1024 * 1024,
      (const short*)nullptr, (const short*)nullptr,
      b_df, b_df2, W1, W2, 1024, 1024, 0, 1);
  // z + ortho 8-pt ifft along b
  make_z_fftb<<<dim3(1024), dim3(576), 0, stream>>>(W1, W2, Zre, Zim);
  // ortho 1024-pt irfft along c + residual
  inv_fft_c_final<<<dim3(8192), dim3(256), 0, stream>>>(Zre, Zim, feats, scalep, out);
  // cls token passthrough
  copy_cls<<<dim3(32), dim3(256), 0, stream>>>(feats, out);
}

// Round 4
// 373.353 us; speedup vs baseline: 1.7891x; 1.3530x over previous
//
#include <hip/hip_runtime.h>
#include <cstddef>

// ---------------------------------------------------------------------------
// Reins layer on MI355X — round 4.
// R3 kept (bf16 MFMA GEMMs, vT-as-GEMM). R4: 1024-pt FFT kernels rewritten:
// radix-4 DIF in-place (5 stages, float2 LDS, +pad(i>>5) anti-conflict),
// two real rows packed per complex FFT (4096 blocks instead of 8192),
// digit-reversal folded into the epilogue gather (pos = 4*rev4(t)+m).
// ---------------------------------------------------------------------------

using bf16x8 = __attribute__((ext_vector_type(8))) short;   // 8 bf16 in 4 VGPRs
using f32x4  = __attribute__((ext_vector_type(4))) float;

__device__ inline short f2bf(float f) {
  union { float f; unsigned u; } v; v.f = f;
  unsigned r = v.u + 0x7FFFu + ((v.u >> 16) & 1u);  // round-to-nearest-even
  return (short)(r >> 16);
}
__device__ inline float bf2f(short s) {
  union { unsigned u; float f; } v; v.u = ((unsigned)(unsigned short)s) << 16;
  return v.f;
}
__device__ inline void async16(const void* g, void* l) {
  __builtin_amdgcn_global_load_lds(
      (const __attribute__((address_space(1))) void*)g,
      (__attribute__((address_space(3))) void*)l, 16, 0, 0);
}

__device__ inline int PADi(int i) { return i + (i >> 5); }   // LDS anti-conflict
__device__ inline int rev4_8(int t) {                         // reverse 4 base-4 digits
  return ((t & 3) << 6) | (((t >> 2) & 3) << 4) | (((t >> 4) & 3) << 2) | ((t >> 6) & 3);
}

// 1024-pt in-place radix-4 DIF over padded float2 LDS. SIGN=-1 fwd, +1 inv.
// Result: z[pos] = X[digitrev4_5(pos)]; X[256*m+t] lives at pos = 4*rev4_8(t)+m.
template <int SIGN>
__device__ inline void fft1024_stages(float2* z, int t) {
#pragma unroll
  for (int s = 0; s < 5; ++s) {
    const int Q = 256 >> (2 * s);
    const int j = t & (Q - 1);
    const int i0 = ((t & ~(Q - 1)) << 2) + j;
    float2 x0 = z[PADi(i0)];
    float2 x1 = z[PADi(i0 + Q)];
    float2 x2 = z[PADi(i0 + 2 * Q)];
    float2 x3 = z[PADi(i0 + 3 * Q)];
    float t0x = x0.x + x2.x, t0y = x0.y + x2.y;
    float t1x = x0.x - x2.x, t1y = x0.y - x2.y;
    float t2x = x1.x + x3.x, t2y = x1.y + x3.y;
    float t3x = x1.x - x3.x, t3y = x1.y - x3.y;
    float u0x = t0x + t2x, u0y = t0y + t2y;
    float u2x = t0x - t2x, u2y = t0y - t2y;
    float u1x, u1y, u3x, u3y;
    if (SIGN < 0) { u1x = t1x + t3y; u1y = t1y - t3x; u3x = t1x - t3y; u3y = t1y + t3x; }
    else          { u1x = t1x - t3y; u1y = t1y + t3x; u3x = t1x + t3y; u3y = t1y - t3x; }
    const float ang = (float)SIGN * 6.283185307179586f * (float)j / (float)(4 * Q);
    float s1, c1; __sincosf(ang, &s1, &c1);
    const float c2 = c1 * c1 - s1 * s1, s2 = 2.f * c1 * s1;
    const float c3 = c2 * c1 - s2 * s1, s3 = c2 * s1 + s2 * c1;
    z[PADi(i0)]         = make_float2(u0x, u0y);
    z[PADi(i0 + Q)]     = make_float2(u1x * c1 - u1y * s1, u1x * s1 + u1y * c1);
    z[PADi(i0 + 2 * Q)] = make_float2(u2x * c2 - u2y * s2, u2x * s2 + u2y * c2);
    z[PADi(i0 + 3 * Q)] = make_float2(u3x * c3 - u3y * s3, u3x * s3 + u3y * c3);
    __syncthreads();
  }
}

// ---- 1. fwd FFT along C, two real rows packed per complex FFT --------------
__global__ __launch_bounds__(256) void fwd_fft_c2(const float* __restrict__ feats,
                                                  float* __restrict__ Fre,
                                                  float* __restrict__ Fim) {
  __shared__ float2 z[1056];
  const int t = threadIdx.x;
  const int blk = blockIdx.x;                       // rows 2*blk, 2*blk+1
  const float* x0 = feats + 8192 + (size_t)blk * 2048;
  const float* x1 = x0 + 1024;
#pragma unroll
  for (int m = 0; m < 4; ++m) {
    const int c = t + 256 * m;
    z[PADi(c)] = make_float2(x0[c], x1[c]);
  }
  __syncthreads();
  fft1024_stages<-1>(z, t);
  // unpack: F0 = (Z[k]+conj(Z[N-k]))/2, F1 = (Z[k]-conj(Z[N-k]))/(2i)
  const int rt = rev4_8(t);
  float* fr0 = Fre + (size_t)blk * 2048;
  float* fi0 = Fim + (size_t)blk * 2048;
#pragma unroll
  for (int m = 0; m < 4; ++m) {
    const int k = 256 * m + t;
    const int kk = (1024 - k) & 1023;
    const int pos  = 4 * rt + m;
    const int pos2 = 4 * rev4_8(kk & 255) + (kk >> 8);
    float2 Z = z[PADi(pos)];
    float2 W = z[PADi(pos2)];
    fr0[k]        = 0.5f * (Z.x + W.x);
    fi0[k]        = 0.5f * (Z.y - W.y);
    fr0[1024 + k] = 0.5f * (Z.y + W.y);
    fi0[1024 + k] = 0.5f * (W.x - Z.x);
  }
}

// ------- 2. 8-pt FFT along B + amp/phase, output bf16 directly --------------
__global__ __launch_bounds__(256) void fwd_fft_b_amp(const float* __restrict__ Fre,
                                                     const float* __restrict__ Fim,
                                                     short* __restrict__ ampb,
                                                     short* __restrict__ phaseb) {
  const int idx = blockIdx.x * 256 + threadIdx.x;   // 0..1024*1024-1 : (n,c)
  const int n = idx >> 10, c = idx & 1023;
  const size_t base = (size_t)n * 8192 + c;
  float xr[8], xi[8];
#pragma unroll
  for (int b = 0; b < 8; ++b) { xr[b] = Fre[base + b * 1024]; xi[b] = Fim[base + b * 1024]; }
  const float cv[8] = {1.f, 0.70710678f, 0.f, -0.70710678f, -1.f, -0.70710678f, 0.f, 0.70710678f};
  const float sv[8] = {0.f, 0.70710678f, 1.f, 0.70710678f, 0.f, -0.70710678f, -1.f, -0.70710678f};
#pragma unroll
  for (int kb = 0; kb < 8; ++kb) {
    float sr = 0.f, si = 0.f;
#pragma unroll
    for (int b = 0; b < 8; ++b) {
      const int p = (kb * b) & 7;                   // e^{-i pi p/4}
      sr += xr[b] * cv[p] + xi[b] * sv[p];
      si += xi[b] * cv[p] - xr[b] * sv[p];
    }
    float r2 = sr * sr + si * si;
    if (r2 < 1e-5f) r2 = 1e-5f;                     // _replace_denormals(re^2+im^2)
    float a = sqrtf(r2);
    float rr = (sr < 1e-5f && sr > -1e-5f) ? 1e-5f : sr;
    float ph = atan2f(si, rr);
    ampb[base + kb * 1024] = f2bf(a);
    phaseb[base + kb * 1024] = f2bf(ph);
  }
}

// ---- weight bf16 convert: 4 matrices [w_t2f, w_t2f2, w_df, w_df2] ----------
__global__ __launch_bounds__(256) void conv_w(const float* __restrict__ w1,
                                              const float* __restrict__ w2,
                                              const float* __restrict__ w3,
                                              const float* __restrict__ w4,
                                              short* __restrict__ dst) {
  const int z = blockIdx.y;                         // 0..3
  const float* W = (z == 0 ? w1 : z == 1 ? w2 : z == 2 ? w3 : w4)
                   + (size_t)blockIdx.x * 1024;
  short* D = dst + ((size_t)z * 1024 + blockIdx.x) * 1024;
  const int t = threadIdx.x * 4;
  float4 v = *(const float4*)(W + t);
  D[t] = f2bf(v.x); D[t + 1] = f2bf(v.y); D[t + 2] = f2bf(v.z); D[t + 3] = f2bf(v.w);
}

// ---- token bf16 convert: [z0 s0, z1 s0, z0 s1, z1 s1], rows zero-padded ----
__global__ __launch_bounds__(256) void conv_tok(const float* __restrict__ lt1,
                                                const float* __restrict__ lt2,
                                                const int* __restrict__ layerp,
                                                short* __restrict__ dst) {
  const int zz = blockIdx.y;                        // z = zz&1, shift = zz>>1
  const int z = zz & 1, shift = zz >> 1;
  const int row = blockIdx.x;                       // 0..127
  short* D = dst + ((size_t)zz * 128 + row) * 1024;
  const int t = threadIdx.x * 4;
  if (row + shift < 100) {
    const float* S = (z ? lt2 : lt1) + (size_t)layerp[0] * 102400
                     + (size_t)(row + shift) * 1024;
    float4 v = *(const float4*)(S + t);
    D[t] = f2bf(v.x); D[t + 1] = f2bf(v.y); D[t + 2] = f2bf(v.z); D[t + 3] = f2bf(v.w);
  } else {
    D[t] = 0; D[t + 1] = 0; D[t + 2] = 0; D[t + 3] = 0;
  }
}

// ------------- m97-style bf16 GEMM:  C = A(MxK) @ B(NxK)^T ------------------
// 128x128 tile, BK=32, 256 thr = 4 waves (2x2), global_load_lds staging with
// XOR chunk swizzle.  biasMode: 0=none, 1=per-col, 2=per-row.
__global__ __launch_bounds__(256) void gemm128(
    const short* A0, const short* A1,       // M x K bf16
    const short* B0, const short* B1,       // N x K bf16
    const short* Add0, const short* Add1,   // optional bf16 addend at C index
    const float* bias0, const float* bias1, // optional fp32 bias
    void* C0v, void* C1v,
    int K, int ldc, int outBf16, int biasMode) {
  const int z = blockIdx.z;
  const short* A   = z ? A1 : A0;
  const short* B   = z ? B1 : B0;
  const short* Add = z ? Add1 : Add0;
  const float* bias = z ? bias1 : bias0;
  void* Cv = z ? C1v : C0v;

  __shared__ __align__(16) short As[128 * 32];
  __shared__ __align__(16) short Bs[128 * 32];

  const int tid = threadIdx.x;
  const int wave = tid >> 6, lane = tid & 63;
  const int m16 = lane & 15, quad = lane >> 4;
  const int wm = (wave & 1) * 64, wn = (wave >> 1) * 64;

  f32x4 acc[4][4];
#pragma unroll
  for (int i = 0; i < 4; ++i)
#pragma unroll
    for (int j = 0; j < 4; ++j) acc[i][j] = (f32x4){0.f, 0.f, 0.f, 0.f};

  const int r0 = tid >> 2;                              // 0..63
  const int csw = (((tid & 3) ^ ((r0 >> 1) & 3)) * 8);  // elems
  const short* aSrc0 = A + (size_t)(blockIdx.x * 128 + r0) * K + csw;
  const short* aSrc1 = aSrc0 + (size_t)64 * K;
  const short* bSrc0 = B + (size_t)(blockIdx.y * 128 + r0) * K + csw;
  const short* bSrc1 = bSrc0 + (size_t)64 * K;
  short* aDst0 = As + tid * 8;
  short* aDst1 = As + 2048 + tid * 8;
  short* bDst0 = Bs + tid * 8;
  short* bDst1 = Bs + 2048 + tid * 8;

  const int fcol = ((quad ^ ((m16 >> 1) & 3)) * 8) + m16 * 32;

  for (int k0 = 0; k0 < K; k0 += 32) {
    async16(aSrc0 + k0, aDst0);
    async16(aSrc1 + k0, aDst1);
    async16(bSrc0 + k0, bDst0);
    async16(bSrc1 + k0, bDst1);
    __syncthreads();
    bf16x8 af[4], bg[4];
#pragma unroll
    for (int ib = 0; ib < 4; ++ib)
      af[ib] = *(const bf16x8*)(As + (wm + ib * 16) * 32 + fcol);
#pragma unroll
    for (int jb = 0; jb < 4; ++jb)
      bg[jb] = *(const bf16x8*)(Bs + (wn + jb * 16) * 32 + fcol);
#pragma unroll
    for (int ib = 0; ib < 4; ++ib)
#pragma unroll
      for (int jb = 0; jb < 4; ++jb)
        acc[ib][jb] = __builtin_amdgcn_mfma_f32_16x16x32_bf16(af[ib], bg[jb], acc[ib][jb], 0, 0, 0);
    __syncthreads();
  }

#pragma unroll
  for (int ib = 0; ib < 4; ++ib) {
    const int rowb = blockIdx.x * 128 + wm + ib * 16 + quad * 4;
#pragma unroll
    for (int jb = 0; jb < 4; ++jb) {
      const int col = blockIdx.y * 128 + wn + jb * 16 + m16;
      const float bcv = (biasMode == 1) ? bias[col] : 0.f;
#pragma unroll
      for (int r = 0; r < 4; ++r) {
        const size_t idx = (size_t)(rowb + r) * (size_t)ldc + col;
        float v = acc[ib][jb][r] + bcv;
        if (biasMode == 2) v += bias[rowb + r];
        if (Add) v += bf2f(Add[idx]);
        if (outBf16) ((short*)Cv)[idx] = f2bf(v);
        else         ((float*)Cv)[idx] = v;
      }
    }
  }
}

// ---- (instance-norm for z=1) + softmax(x/32); fp32 in -> shifted bf16 out --
__global__ __launch_bounds__(128) void in_softmax(const float* __restrict__ logits,
                                                  short* __restrict__ awb) {
  const int z = blockIdx.y;
  const float* L = logits + ((size_t)z * 8192 + blockIdx.x) * 128;
  short* A = awb + ((size_t)z * 8192 + blockIdx.x) * 128;
  const int t = threadIdx.x;
  const bool act = t < 100;
  float x = act ? L[t] : 0.f;
  __shared__ float red[128];
  if (z == 1) {
    red[t] = act ? x : 0.f; __syncthreads();
    for (int o = 64; o > 0; o >>= 1) { if (t < o) red[t] += red[t + o]; __syncthreads(); }
    float mu = red[0] * 0.01f; __syncthreads();
    float d = act ? (x - mu) : 0.f;
    red[t] = d * d; __syncthreads();
    for (int o = 64; o > 0; o >>= 1) { if (t < o) red[t] += red[t + o]; __syncthreads(); }
    float var = red[0] * 0.01f; __syncthreads();
    x = (x - mu) * rsqrtf(var + 1e-5f);
  }
  x *= 0.03125f;                                    // * C^{-1/2}
  red[t] = act ? x : -3.4e38f; __syncthreads();
  for (int o = 64; o > 0; o >>= 1) { if (t < o) red[t] = fmaxf(red[t], red[t + o]); __syncthreads(); }
  float mx = red[0]; __syncthreads();
  float e = act ? __expf(x - mx) : 0.f;
  red[t] = e; __syncthreads();
  for (int o = 64; o > 0; o >>= 1) { if (t < o) red[t] += red[t + o]; __syncthreads(); }
  float inv = 1.f / red[0];
  __syncthreads();
  if (t >= 1 && t < 100) A[t - 1] = f2bf(e * inv);  // aw[k] = attn[k+1]
  if (t >= 99) A[t] = 0;                            // zero pad 99..127
}

// ------ z = amp e^{i phase}/sqrt(2C), keep k<=512, ortho ifft along b -------
__global__ __launch_bounds__(576) void make_z_fftb(const float* __restrict__ dph,
                                                   const float* __restrict__ dam,
                                                   float* __restrict__ Zre,
                                                   float* __restrict__ Zim) {
  const int n = blockIdx.x;
  const int k = threadIdx.x;
  if (k >= 513) return;
  const float* pp = dph + (size_t)n * 8192 + k;
  const float* ap = dam + (size_t)n * 8192 + k;
  float zr[8], zi[8];
  const float invs = 0.022097086912079608f;         // 1/sqrt(2048)
#pragma unroll
  for (int b = 0; b < 8; ++b) {
    float p = pp[b * 1024], a = ap[b * 1024] * invs;
    float s, c; __sincosf(p, &s, &c);
    zr[b] = c * a; zi[b] = s * a;
  }
  const float cv[8] = {1.f, 0.70710678f, 0.f, -0.70710678f, -1.f, -0.70710678f, 0.f, 0.70710678f};
  const float sv[8] = {0.f, 0.70710678f, 1.f, 0.70710678f, 0.f, -0.70710678f, -1.f, -0.70710678f};
  float* zro = Zre + (size_t)n * 4160 + k;
  float* zio = Zim + (size_t)n * 4160 + k;
  const float inv8 = 0.35355339059327373f;          // 1/sqrt(8) (ortho)
#pragma unroll
  for (int bp = 0; bp < 8; ++bp) {
    float sr = 0.f, si = 0.f;
#pragma unroll
    for (int b = 0; b < 8; ++b) {
      const int p = (bp * b) & 7;                   // e^{+i pi p/4}
      sr += zr[b] * cv[p] - zi[b] * sv[p];
      si += zi[b] * cv[p] + zr[b] * sv[p];
    }
    zro[bp * 520] = sr * inv8;
    zio[bp * 520] = si * inv8;
  }
}

// ---- inverse FFT along C: two Hermitian spectra packed, + residual add -----
__global__ __launch_bounds__(256) void inv_fft_c2(const float* __restrict__ Zre,
                                                  const float* __restrict__ Zim,
                                                  const float* __restrict__ feats,
                                                  const float* __restrict__ scalep,
                                                  float* __restrict__ out) {
  __shared__ float2 z[1056];
  const int t = threadIdx.x;
  const int blk = blockIdx.x;                       // n = blk>>2, q = blk&3
  const int n = blk >> 2, q = blk & 3;
  const float* zr0 = Zre + (size_t)n * 4160 + (size_t)(2 * q) * 520;
  const float* zi0 = Zim + (size_t)n * 4160 + (size_t)(2 * q) * 520;
  const float* zr1 = zr0 + 520;
  const float* zi1 = zi0 + 520;
#pragma unroll
  for (int m = 0; m < 4; ++m) {
    const int jj = t + 256 * m;
    float ar, ai, br, bi;
    if (jj <= 512) { ar = zr0[jj]; ai = zi0[jj]; br = zr1[jj]; bi = zi1[jj]; }
    else {
      const int js = 1024 - jj;
      ar = zr0[js]; ai = -zi0[js]; br = zr1[js]; bi = -zi1[js];
    }
    z[PADi(jj)] = make_float2(ar - bi, ai + br);    // Za + i*Zb
  }
  __syncthreads();
  fft1024_stages<1>(z, t);
  const int rt = rev4_8(t);
  const float s = scalep[0] * 0.03125f;             // scale * 1/sqrt(1024)
  const size_t ob0 = 8192 + (size_t)blk * 2048;
  const size_t ob1 = ob0 + 1024;
#pragma unroll
  for (int m = 0; m < 4; ++m) {
    const int nn = 256 * m + t;
    float2 y = z[PADi(4 * rt + m)];
    out[ob0 + nn] = feats[ob0 + nn] + y.x * s;
    out[ob1 + nn] = feats[ob1 + nn] + y.y * s;
  }
}

__global__ __launch_bounds__(256) void copy_cls(const float* __restrict__ feats,
                                                float* __restrict__ out) {
  const int i = blockIdx.x * 256 + threadIdx.x;
  if (i < 8192) out[i] = feats[i];
}

// ---------------------------------------------------------------------------
extern "C" void kernel_launch(void* const* d_in, const int* in_sizes, int n_in,
                              void* d_out, int out_size, void* d_ws, size_t ws_size,
                              hipStream_t stream) {
  const float* feats  = (const float*)d_in[0];
  const float* lt1    = (const float*)d_in[1];
  const float* lt2    = (const float*)d_in[2];
  const float* w_t2f  = (const float*)d_in[3];
  const float* b_t2f  = (const float*)d_in[4];
  const float* w_df   = (const float*)d_in[5];
  const float* b_df   = (const float*)d_in[6];
  const float* w_t2f2 = (const float*)d_in[7];
  const float* b_t2f2 = (const float*)d_in[8];
  const float* w_df2  = (const float*)d_in[9];
  const float* b_df2  = (const float*)d_in[10];
  const float* scalep = (const float*)d_in[11];
  const int*   layerp = (const int*)d_in[12];
  float* out = (float*)d_out;
  float* ws  = (float*)d_ws;
  (void)in_sizes; (void)n_in; (void)out_size; (void)ws_size;

  const size_t SZ = 8192ull * 1024ull;              // 8,388,608 elements
  float* W0  = ws;                        // 32MB: Fre -> XP bf16 pair -> Zre
  float* W1  = W0 + SZ;                   // 32MB: Fim -> d_phase fp32
  float* W2  = W1 + SZ;                   // 32MB: d_amp fp32
  float* PAB = W2 + SZ;                   // 32MB: Pa,Pb bf16 -> Zim
  short* Pa  = (short*)PAB;                         // phase bf16, 8192x1024
  short* Pb  = Pa + SZ;                             // amp   bf16, 8192x1024
  float* L   = PAB + SZ;                  // logits fp32, 2 x 8192x128
  short* awb = (short*)(L + 2ull * 8192 * 128);     // aw bf16, 2 x 8192x128
  short* Tok = awb + 2ull * 8192 * 128;             // tokens bf16, 4 x 128x1024
  short* Wall = Tok + 4ull * 128 * 1024;            // weights bf16, 4 x 1024x1024
  short* B2   = Wall + 4ull * 1024 * 1024;          // v^T bf16, 2 x 1024x128
  short* XP0 = (short*)W0;                          // (df+P) bf16
  short* XP1 = XP0 + SZ;
  float* Zre = W0;                                  // reuse after GEMM3
  float* Zim = PAB;

  // 1-2: forward FFT2 + amp/phase (bf16 out)
  fwd_fft_c2<<<dim3(4096), dim3(256), 0, stream>>>(feats, W0, W1);
  fwd_fft_b_amp<<<dim3(4096), dim3(256), 0, stream>>>(W0, W1, Pb, Pa);
  // operand conversion (tiny): weights [w_t2f, w_t2f2, w_df, w_df2], tokens
  conv_w<<<dim3(1024, 4), dim3(256), 0, stream>>>(w_t2f, w_t2f2, w_df, w_df2, Wall);
  conv_tok<<<dim3(128, 4), dim3(256), 0, stream>>>(lt1, lt2, layerp, Tok);
  // GEMM1: logits = P @ tokens^T  (M=8192, N=128, K=1024), fp32 out
  gemm128<<<dim3(64, 1, 2), dim3(256), 0, stream>>>(
      Pa, Pb, Tok, Tok + 128 * 1024,
      (const short*)nullptr, (const short*)nullptr,
      (const float*)nullptr, (const float*)nullptr,
      L, L + 8192 * 128, 1024, 128, 0, 0);
  // GEMM-vT: B2 = W_t2f @ Vtok^T + b_t2f (row bias)  (M=1024, N=128, K=1024)
  gemm128<<<dim3(8, 1, 2), dim3(256), 0, stream>>>(
      Wall, Wall + 1024 * 1024,
      Tok + 2 * 128 * 1024, Tok + 3 * 128 * 1024,
      (const short*)nullptr, (const short*)nullptr,
      b_t2f, b_t2f2,
      B2, B2 + 1024 * 128, 1024, 128, 1, 2);
  // instance-norm(amp) + softmax -> shifted bf16 aw
  in_softmax<<<dim3(8192, 2), dim3(128), 0, stream>>>(L, awb);
  // GEMM2: XP = aw @ B2^T + P  (M=8192, N=1024, K=128), bf16 out
  gemm128<<<dim3(64, 8, 2), dim3(256), 0, stream>>>(
      awb, awb + 8192 * 128, B2, B2 + 1024 * 128,
      Pa, Pb, (const float*)nullptr, (const float*)nullptr,
      XP0, XP1, 128, 1024, 1, 0);
  // GEMM3: d = XP @ w_df^T + b_df  (M=8192, N=1024, K=1024), fp32 out
  gemm128<<<dim3(64, 8, 2), dim3(256), 0, stream>>>(
      XP0, XP1, Wall + 2 * 1024 * 1024, Wall + 3 * 1024 * 1024,
      (const short*)nullptr, (const short*)nullptr,
      b_df, b_df2, W1, W2, 1024, 1024, 0, 1);
  // z + ortho 8-pt ifft along b
  make_z_fftb<<<dim3(1024), dim3(576), 0, stream>>>(W1, W2, Zre, Zim);
  // inverse FFT along C (two Hermitian spectra per block) + residual
  inv_fft_c2<<<dim3(4096), dim3(256), 0, stream>>>(Zre, Zim, feats, scalep, out);
  // cls token passthrough
  copy_cls<<<dim3(32), dim3(256), 0, stream>>>(feats, out);
}

// Round 5
// 348.324 us; speedup vs baseline: 1.9177x; 1.0719x over previous
//
#include <hip/hip_runtime.h>
#include <cstddef>

// ---------------------------------------------------------------------------
// Reins layer on MI355X — round 5.
// R4 kept (radix-4 packed FFT, bf16 MFMA GEMMs). R5:
//  * fwd_fft2_amp : FFT-C (4 packed complex FFTs/block) + 8-pt FFT-B in regs
//                   + amp/phase -> bf16, one kernel, no Fre/Fim intermediate.
//  * inv_fft2_res : polar->z + 8-pt ifft (regs) + Hermitian-packed 1024-pt
//                   ifft + residual add, one kernel, no Zre/Zim intermediate.
//  * GEMM3 emits bf16 d_phase/d_amp (halves its writes).
//  * gemm64 (64x128 tile) for GEMM1 / vT -> 256 blocks, full GPU.
// ---------------------------------------------------------------------------

using bf16x8 = __attribute__((ext_vector_type(8))) short;   // 8 bf16 in 4 VGPRs
using f32x4  = __attribute__((ext_vector_type(4))) float;

__device__ inline short f2bf(float f) {
  union { float f; unsigned u; } v; v.f = f;
  unsigned r = v.u + 0x7FFFu + ((v.u >> 16) & 1u);  // round-to-nearest-even
  return (short)(r >> 16);
}
__device__ inline float bf2f(short s) {
  union { unsigned u; float f; } v; v.u = ((unsigned)(unsigned short)s) << 16;
  return v.f;
}
__device__ inline void async16(const void* g, void* l) {
  __builtin_amdgcn_global_load_lds(
      (const __attribute__((address_space(1))) void*)g,
      (__attribute__((address_space(3))) void*)l, 16, 0, 0);
}

__device__ inline int PADi(int i) { return i + (i >> 5); }   // LDS anti-conflict
__device__ inline int rev4_8(int t) {                         // reverse 4 base-4 digits
  return ((t & 3) << 6) | (((t >> 2) & 3) << 4) | (((t >> 4) & 3) << 2) | ((t >> 6) & 3);
}

// 1024-pt in-place radix-4 DIF, 4 interleaved FFTs sharing barriers.
// SIGN=-1 fwd, +1 inv.  X[256*m+t] ends at pos = 4*rev4_8(t)+m.
template <int SIGN>
__device__ inline void fft1024x4(float2 (*zb)[1056], int t) {
#pragma unroll
  for (int s = 0; s < 5; ++s) {
    const int Q = 256 >> (2 * s);
    const int j = t & (Q - 1);
    const int i0 = ((t & ~(Q - 1)) << 2) + j;
    const float ang = (float)SIGN * 6.283185307179586f * (float)j / (float)(4 * Q);
    float s1, c1; __sincosf(ang, &s1, &c1);
    const float c2 = c1 * c1 - s1 * s1, s2 = 2.f * c1 * s1;
    const float c3 = c2 * c1 - s2 * s1, s3 = c2 * s1 + s2 * c1;
#pragma unroll
    for (int p = 0; p < 4; ++p) {
      float2* z = zb[p];
      float2 x0 = z[PADi(i0)];
      float2 x1 = z[PADi(i0 + Q)];
      float2 x2 = z[PADi(i0 + 2 * Q)];
      float2 x3 = z[PADi(i0 + 3 * Q)];
      float t0x = x0.x + x2.x, t0y = x0.y + x2.y;
      float t1x = x0.x - x2.x, t1y = x0.y - x2.y;
      float t2x = x1.x + x3.x, t2y = x1.y + x3.y;
      float t3x = x1.x - x3.x, t3y = x1.y - x3.y;
      float u0x = t0x + t2x, u0y = t0y + t2y;
      float u2x = t0x - t2x, u2y = t0y - t2y;
      float u1x, u1y, u3x, u3y;
      if (SIGN < 0) { u1x = t1x + t3y; u1y = t1y - t3x; u3x = t1x - t3y; u3y = t1y + t3x; }
      else          { u1x = t1x - t3y; u1y = t1y + t3x; u3x = t1x + t3y; u3y = t1y - t3x; }
      z[PADi(i0)]         = make_float2(u0x, u0y);
      z[PADi(i0 + Q)]     = make_float2(u1x * c1 - u1y * s1, u1x * s1 + u1y * c1);
      z[PADi(i0 + 2 * Q)] = make_float2(u2x * c2 - u2y * s2, u2x * s2 + u2y * c2);
      z[PADi(i0 + 3 * Q)] = make_float2(u3x * c3 - u3y * s3, u3x * s3 + u3y * c3);
    }
    __syncthreads();
  }
}

// ---- 1. fused fwd fft2 + amp/phase: one block per n --------------------------
__global__ __launch_bounds__(256) void fwd_fft2_amp(const float* __restrict__ feats,
                                                    short* __restrict__ ampb,
                                                    short* __restrict__ phaseb) {
  __shared__ float2 zb[4][1056];                    // 33.8 KB
  const int t = threadIdx.x;
  const int n = blockIdx.x;
  const float* base = feats + 8192 + (size_t)n * 8192;
#pragma unroll
  for (int p = 0; p < 4; ++p) {
    const float* x0 = base + (size_t)(2 * p) * 1024;
    const float* x1 = x0 + 1024;
#pragma unroll
    for (int m = 0; m < 4; ++m) {
      const int c = t + 256 * m;
      zb[p][PADi(c)] = make_float2(x0[c], x1[c]);
    }
  }
  __syncthreads();
  fft1024x4<-1>(zb, t);
  const int rt = rev4_8(t);
  const float cv[8] = {1.f, 0.70710678f, 0.f, -0.70710678f, -1.f, -0.70710678f, 0.f, 0.70710678f};
  const float sv[8] = {0.f, 0.70710678f, 1.f, 0.70710678f, 0.f, -0.70710678f, -1.f, -0.70710678f};
  short* ab = ampb + (size_t)n * 8192;
  short* pb = phaseb + (size_t)n * 8192;
#pragma unroll
  for (int m = 0; m < 4; ++m) {
    const int k = 256 * m + t;
    const int kk = (1024 - k) & 1023;
    const int pos  = 4 * rt + m;
    const int pos2 = 4 * rev4_8(kk & 255) + (kk >> 8);
    float xr[8], xi[8];
#pragma unroll
    for (int p = 0; p < 4; ++p) {
      float2 Z = zb[p][PADi(pos)];
      float2 W = zb[p][PADi(pos2)];
      xr[2 * p]     = 0.5f * (Z.x + W.x);
      xi[2 * p]     = 0.5f * (Z.y - W.y);
      xr[2 * p + 1] = 0.5f * (Z.y + W.y);
      xi[2 * p + 1] = 0.5f * (W.x - Z.x);
    }
#pragma unroll
    for (int kb = 0; kb < 8; ++kb) {
      float sr = 0.f, si = 0.f;
#pragma unroll
      for (int b = 0; b < 8; ++b) {
        const int p = (kb * b) & 7;                 // e^{-i pi p/4}
        sr += xr[b] * cv[p] + xi[b] * sv[p];
        si += xi[b] * cv[p] - xr[b] * sv[p];
      }
      float r2 = sr * sr + si * si;
      if (r2 < 1e-5f) r2 = 1e-5f;                   // _replace_denormals(re^2+im^2)
      float a = sqrtf(r2);
      float rr = (sr < 1e-5f && sr > -1e-5f) ? 1e-5f : sr;
      float ph = atan2f(si, rr);
      ab[kb * 1024 + k] = f2bf(a);
      pb[kb * 1024 + k] = f2bf(ph);
    }
  }
}

// ---- weight bf16 convert: 4 matrices [w_t2f, w_t2f2, w_df, w_df2] ----------
__global__ __launch_bounds__(256) void conv_w(const float* __restrict__ w1,
                                              const float* __restrict__ w2,
                                              const float* __restrict__ w3,
                                              const float* __restrict__ w4,
                                              short* __restrict__ dst) {
  const int z = blockIdx.y;                         // 0..3
  const float* W = (z == 0 ? w1 : z == 1 ? w2 : z == 2 ? w3 : w4)
                   + (size_t)blockIdx.x * 1024;
  short* D = dst + ((size_t)z * 1024 + blockIdx.x) * 1024;
  const int t = threadIdx.x * 4;
  float4 v = *(const float4*)(W + t);
  D[t] = f2bf(v.x); D[t + 1] = f2bf(v.y); D[t + 2] = f2bf(v.z); D[t + 3] = f2bf(v.w);
}

// ---- token bf16 convert: [z0 s0, z1 s0, z0 s1, z1 s1], rows zero-padded ----
__global__ __launch_bounds__(256) void conv_tok(const float* __restrict__ lt1,
                                                const float* __restrict__ lt2,
                                                const int* __restrict__ layerp,
                                                short* __restrict__ dst) {
  const int zz = blockIdx.y;                        // z = zz&1, shift = zz>>1
  const int z = zz & 1, shift = zz >> 1;
  const int row = blockIdx.x;                       // 0..127
  short* D = dst + ((size_t)zz * 128 + row) * 1024;
  const int t = threadIdx.x * 4;
  if (row + shift < 100) {
    const float* S = (z ? lt2 : lt1) + (size_t)layerp[0] * 102400
                     + (size_t)(row + shift) * 1024;
    float4 v = *(const float4*)(S + t);
    D[t] = f2bf(v.x); D[t + 1] = f2bf(v.y); D[t + 2] = f2bf(v.z); D[t + 3] = f2bf(v.w);
  } else {
    D[t] = 0; D[t + 1] = 0; D[t + 2] = 0; D[t + 3] = 0;
  }
}

// ------------- m97-style bf16 GEMM:  C = A(MxK) @ B(NxK)^T ------------------
// 128x128 tile.  biasMode: 0=none, 1=per-col, 2=per-row.
__global__ __launch_bounds__(256) void gemm128(
    const short* A0, const short* A1,       // M x K bf16
    const short* B0, const short* B1,       // N x K bf16
    const short* Add0, const short* Add1,   // optional bf16 addend at C index
    const float* bias0, const float* bias1, // optional fp32 bias
    void* C0v, void* C1v,
    int K, int ldc, int outBf16, int biasMode) {
  const int z = blockIdx.z;
  const short* A   = z ? A1 : A0;
  const short* B   = z ? B1 : B0;
  const short* Add = z ? Add1 : Add0;
  const float* bias = z ? bias1 : bias0;
  void* Cv = z ? C1v : C0v;

  __shared__ __align__(16) short As[128 * 32];
  __shared__ __align__(16) short Bs[128 * 32];

  const int tid = threadIdx.x;
  const int wave = tid >> 6, lane = tid & 63;
  const int m16 = lane & 15, quad = lane >> 4;
  const int wm = (wave & 1) * 64, wn = (wave >> 1) * 64;

  f32x4 acc[4][4];
#pragma unroll
  for (int i = 0; i < 4; ++i)
#pragma unroll
    for (int j = 0; j < 4; ++j) acc[i][j] = (f32x4){0.f, 0.f, 0.f, 0.f};

  const int r0 = tid >> 2;                              // 0..63
  const int csw = (((tid & 3) ^ ((r0 >> 1) & 3)) * 8);  // elems
  const short* aSrc0 = A + (size_t)(blockIdx.x * 128 + r0) * K + csw;
  const short* aSrc1 = aSrc0 + (size_t)64 * K;
  const short* bSrc0 = B + (size_t)(blockIdx.y * 128 + r0) * K + csw;
  const short* bSrc1 = bSrc0 + (size_t)64 * K;
  short* aDst0 = As + tid * 8;
  short* aDst1 = As + 2048 + tid * 8;
  short* bDst0 = Bs + tid * 8;
  short* bDst1 = Bs + 2048 + tid * 8;

  const int fcol = ((quad ^ ((m16 >> 1) & 3)) * 8) + m16 * 32;

  for (int k0 = 0; k0 < K; k0 += 32) {
    async16(aSrc0 + k0, aDst0);
    async16(aSrc1 + k0, aDst1);
    async16(bSrc0 + k0, bDst0);
    async16(bSrc1 + k0, bDst1);
    __syncthreads();
    bf16x8 af[4], bg[4];
#pragma unroll
    for (int ib = 0; ib < 4; ++ib)
      af[ib] = *(const bf16x8*)(As + (wm + ib * 16) * 32 + fcol);
#pragma unroll
    for (int jb = 0; jb < 4; ++jb)
      bg[jb] = *(const bf16x8*)(Bs + (wn + jb * 16) * 32 + fcol);
#pragma unroll
    for (int ib = 0; ib < 4; ++ib)
#pragma unroll
      for (int jb = 0; jb < 4; ++jb)
        acc[ib][jb] = __builtin_amdgcn_mfma_f32_16x16x32_bf16(af[ib], bg[jb], acc[ib][jb], 0, 0, 0);
    __syncthreads();
  }

#pragma unroll
  for (int ib = 0; ib < 4; ++ib) {
    const int rowb = blockIdx.x * 128 + wm + ib * 16 + quad * 4;
#pragma unroll
    for (int jb = 0; jb < 4; ++jb) {
      const int col = blockIdx.y * 128 + wn + jb * 16 + m16;
      const float bcv = (biasMode == 1) ? bias[col] : 0.f;
#pragma unroll
      for (int r = 0; r < 4; ++r) {
        const size_t idx = (size_t)(rowb + r) * (size_t)ldc + col;
        float v = acc[ib][jb][r] + bcv;
        if (biasMode == 2) v += bias[rowb + r];
        if (Add) v += bf2f(Add[idx]);
        if (outBf16) ((short*)Cv)[idx] = f2bf(v);
        else         ((float*)Cv)[idx] = v;
      }
    }
  }
}

// ------------- 64x128-tile variant (for small-N GEMMs, 2x block count) ------
__global__ __launch_bounds__(256) void gemm64(
    const short* A0, const short* A1,       // M x K bf16
    const short* B0, const short* B1,       // 128 x K bf16
    const float* bias0, const float* bias1, // optional fp32 bias
    void* C0v, void* C1v,
    int K, int ldc, int outBf16, int biasMode) {
  const int z = blockIdx.z;
  const short* A   = z ? A1 : A0;
  const short* B   = z ? B1 : B0;
  const float* bias = z ? bias1 : bias0;
  void* Cv = z ? C1v : C0v;

  __shared__ __align__(16) short As[64 * 32];
  __shared__ __align__(16) short Bs[128 * 32];

  const int tid = threadIdx.x;
  const int wave = tid >> 6, lane = tid & 63;
  const int m16 = lane & 15, quad = lane >> 4;
  const int wm = (wave & 1) * 32, wn = (wave >> 1) * 64;

  f32x4 acc[2][4];
#pragma unroll
  for (int i = 0; i < 2; ++i)
#pragma unroll
    for (int j = 0; j < 4; ++j) acc[i][j] = (f32x4){0.f, 0.f, 0.f, 0.f};

  const int r0 = tid >> 2;                              // 0..63
  const int csw = (((tid & 3) ^ ((r0 >> 1) & 3)) * 8);
  const short* aSrc  = A + (size_t)(blockIdx.x * 64 + r0) * K + csw;
  const short* bSrc0 = B + (size_t)r0 * K + csw;
  const short* bSrc1 = bSrc0 + (size_t)64 * K;
  short* aDst  = As + tid * 8;
  short* bDst0 = Bs + tid * 8;
  short* bDst1 = Bs + 2048 + tid * 8;

  const int fcol = ((quad ^ ((m16 >> 1) & 3)) * 8) + m16 * 32;

  for (int k0 = 0; k0 < K; k0 += 32) {
    async16(aSrc + k0, aDst);
    async16(bSrc0 + k0, bDst0);
    async16(bSrc1 + k0, bDst1);
    __syncthreads();
    bf16x8 af[2], bg[4];
#pragma unroll
    for (int ib = 0; ib < 2; ++ib)
      af[ib] = *(const bf16x8*)(As + (wm + ib * 16) * 32 + fcol);
#pragma unroll
    for (int jb = 0; jb < 4; ++jb)
      bg[jb] = *(const bf16x8*)(Bs + (wn + jb * 16) * 32 + fcol);
#pragma unroll
    for (int ib = 0; ib < 2; ++ib)
#pragma unroll
      for (int jb = 0; jb < 4; ++jb)
        acc[ib][jb] = __builtin_amdgcn_mfma_f32_16x16x32_bf16(af[ib], bg[jb], acc[ib][jb], 0, 0, 0);
    __syncthreads();
  }

#pragma unroll
  for (int ib = 0; ib < 2; ++ib) {
    const int rowb = blockIdx.x * 64 + wm + ib * 16 + quad * 4;
#pragma unroll
    for (int jb = 0; jb < 4; ++jb) {
      const int col = wn + jb * 16 + m16;
      const float bcv = (biasMode == 1) ? bias[col] : 0.f;
#pragma unroll
      for (int r = 0; r < 4; ++r) {
        const size_t idx = (size_t)(rowb + r) * (size_t)ldc + col;
        float v = acc[ib][jb][r] + bcv;
        if (biasMode == 2) v += bias[rowb + r];
        if (outBf16) ((short*)Cv)[idx] = f2bf(v);
        else         ((float*)Cv)[idx] = v;
      }
    }
  }
}

// ---- (instance-norm for z=1) + softmax(x/32); fp32 in -> shifted bf16 out --
__global__ __launch_bounds__(128) void in_softmax(const float* __restrict__ logits,
                                                  short* __restrict__ awb) {
  const int z = blockIdx.y;
  const float* L = logits + ((size_t)z * 8192 + blockIdx.x) * 128;
  short* A = awb + ((size_t)z * 8192 + blockIdx.x) * 128;
  const int t = threadIdx.x;
  const bool act = t < 100;
  float x = act ? L[t] : 0.f;
  __shared__ float red[128];
  if (z == 1) {
    red[t] = act ? x : 0.f; __syncthreads();
    for (int o = 64; o > 0; o >>= 1) { if (t < o) red[t] += red[t + o]; __syncthreads(); }
    float mu = red[0] * 0.01f; __syncthreads();
    float d = act ? (x - mu) : 0.f;
    red[t] = d * d; __syncthreads();
    for (int o = 64; o > 0; o >>= 1) { if (t < o) red[t] += red[t + o]; __syncthreads(); }
    float var = red[0] * 0.01f; __syncthreads();
    x = (x - mu) * rsqrtf(var + 1e-5f);
  }
  x *= 0.03125f;                                    // * C^{-1/2}
  red[t] = act ? x : -3.4e38f; __syncthreads();
  for (int o = 64; o > 0; o >>= 1) { if (t < o) red[t] = fmaxf(red[t], red[t + o]); __syncthreads(); }
  float mx = red[0]; __syncthreads();
  float e = act ? __expf(x - mx) : 0.f;
  red[t] = e; __syncthreads();
  for (int o = 64; o > 0; o >>= 1) { if (t < o) red[t] += red[t + o]; __syncthreads(); }
  float inv = 1.f / red[0];
  __syncthreads();
  if (t >= 1 && t < 100) A[t - 1] = f2bf(e * inv);  // aw[k] = attn[k+1]
  if (t >= 99) A[t] = 0;                            // zero pad 99..127
}

// ---- fused inverse: polar->z, 8-pt ifft (regs), Hermitian-packed 1024-pt ---
// ---- ifft, + residual.  One block per n. -----------------------------------
__global__ __launch_bounds__(256) void inv_fft2_res(const short* __restrict__ dPb,
                                                    const short* __restrict__ dAb,
                                                    const float* __restrict__ feats,
                                                    const float* __restrict__ scalep,
                                                    float* __restrict__ out) {
  __shared__ float2 zs[8][520];                     // Z[b'][k], k<=512 (33.3 KB)
  __shared__ float2 zb[4][1056];                    // packed ifft workspace (33.8 KB)
  const int t = threadIdx.x;
  const int n = blockIdx.x;
  const short* pp = dPb + (size_t)n * 8192;
  const short* ap = dAb + (size_t)n * 8192;
  const float cv[8] = {1.f, 0.70710678f, 0.f, -0.70710678f, -1.f, -0.70710678f, 0.f, 0.70710678f};
  const float sv[8] = {0.f, 0.70710678f, 1.f, 0.70710678f, 0.f, -0.70710678f, -1.f, -0.70710678f};
  const float invs = 0.022097086912079608f;         // 1/sqrt(2048)
  const float inv8 = 0.35355339059327373f;          // 1/sqrt(8) (ortho)
  for (int k = t; k < 513; k += 256) {
    float zr[8], zi[8];
#pragma unroll
    for (int b = 0; b < 8; ++b) {
      float p = bf2f(pp[b * 1024 + k]);
      float a = bf2f(ap[b * 1024 + k]) * invs;
      float s, c; __sincosf(p, &s, &c);
      zr[b] = c * a; zi[b] = s * a;
    }
#pragma unroll
    for (int bp = 0; bp < 8; ++bp) {
      float sr = 0.f, si = 0.f;
#pragma unroll
      for (int b = 0; b < 8; ++b) {
        const int p = (bp * b) & 7;                 // e^{+i pi p/4}
        sr += zr[b] * cv[p] - zi[b] * sv[p];
        si += zi[b] * cv[p] + zr[b] * sv[p];
      }
      zs[bp][k] = make_float2(sr * inv8, si * inv8);
    }
  }
  __syncthreads();
  // pack pairs (2p, 2p+1) with Hermitian extension: Y = Za + i*Zb
#pragma unroll
  for (int p = 0; p < 4; ++p) {
#pragma unroll
    for (int m = 0; m < 4; ++m) {
      const int j = 256 * m + t;
      float2 a, b;
      if (j <= 512) { a = zs[2 * p][j]; b = zs[2 * p + 1][j]; }
      else {
        const int js = 1024 - j;
        float2 aa = zs[2 * p][js], bb = zs[2 * p + 1][js];
        a = make_float2(aa.x, -aa.y); b = make_float2(bb.x, -bb.y);
      }
      zb[p][PADi(j)] = make_float2(a.x - b.y, a.y + b.x);
    }
  }
  __syncthreads();
  fft1024x4<1>(zb, t);
  const int rt = rev4_8(t);
  const float s = scalep[0] * 0.03125f;             // scale * 1/sqrt(1024)
#pragma unroll
  for (int p = 0; p < 4; ++p) {
    const size_t ob0 = 8192 + ((size_t)n * 8 + 2 * p) * 1024;
    const size_t ob1 = ob0 + 1024;
#pragma unroll
    for (int m = 0; m < 4; ++m) {
      const int nn = 256 * m + t;
      float2 y = zb[p][PADi(4 * rt + m)];
      out[ob0 + nn] = feats[ob0 + nn] + y.x * s;
      out[ob1 + nn] = feats[ob1 + nn] + y.y * s;
    }
  }
}

__global__ __launch_bounds__(256) void copy_cls(const float* __restrict__ feats,
                                                float* __restrict__ out) {
  const int i = blockIdx.x * 256 + threadIdx.x;
  if (i < 8192) out[i] = feats[i];
}

// ---------------------------------------------------------------------------
extern "C" void kernel_launch(void* const* d_in, const int* in_sizes, int n_in,
                              void* d_out, int out_size, void* d_ws, size_t ws_size,
                              hipStream_t stream) {
  const float* feats  = (const float*)d_in[0];
  const float* lt1    = (const float*)d_in[1];
  const float* lt2    = (const float*)d_in[2];
  const float* w_t2f  = (const float*)d_in[3];
  const float* b_t2f  = (const float*)d_in[4];
  const float* w_df   = (const float*)d_in[5];
  const float* b_df   = (const float*)d_in[6];
  const float* w_t2f2 = (const float*)d_in[7];
  const float* b_t2f2 = (const float*)d_in[8];
  const float* w_df2  = (const float*)d_in[9];
  const float* b_df2  = (const float*)d_in[10];
  const float* scalep = (const float*)d_in[11];
  const int*   layerp = (const int*)d_in[12];
  float* out = (float*)d_out;
  (void)in_sizes; (void)n_in; (void)out_size; (void)ws_size;

  const size_t SZ = 8192ull * 1024ull;              // 8,388,608 elements
  short* Pa   = (short*)d_ws;                       // phase bf16 (16 MB)
  short* Pb   = Pa + SZ;                            // amp   bf16 (16 MB)
  float* L    = (float*)(Pb + SZ);                  // logits fp32, 2x8192x128 (8 MB)
  short* awb  = (short*)(L + 2ull * 8192 * 128);    // aw bf16 (4 MB)
  short* Tok  = awb + 2ull * 8192 * 128;            // tokens bf16, 4x128x1024 (1 MB)
  short* Wall = Tok + 4ull * 128 * 1024;            // weights bf16, 4x1024x1024 (8 MB)
  short* B2   = Wall + 4ull * 1024 * 1024;          // v^T bf16, 2x1024x128 (0.5 MB)
  short* XP0  = B2 + 2ull * 1024 * 128;             // (df+P) bf16 (16 MB)
  short* XP1  = XP0 + SZ;                           // (16 MB)
  short* dP   = XP1 + SZ;                           // d_phase bf16 (16 MB)
  short* dA   = dP + SZ;                            // d_amp bf16 (16 MB)

  // 1: fused forward fft2 + amp/phase -> bf16
  fwd_fft2_amp<<<dim3(1024), dim3(256), 0, stream>>>(feats, Pb, Pa);
  // operand conversion (tiny)
  conv_w<<<dim3(1024, 4), dim3(256), 0, stream>>>(w_t2f, w_t2f2, w_df, w_df2, Wall);
  conv_tok<<<dim3(128, 4), dim3(256), 0, stream>>>(lt1, lt2, layerp, Tok);
  // GEMM1: logits = P @ tokens^T  (M=8192, N=128, K=1024), fp32 out, 256 blocks
  gemm64<<<dim3(128, 1, 2), dim3(256), 0, stream>>>(
      Pa, Pb, Tok, Tok + 128 * 1024,
      (const float*)nullptr, (const float*)nullptr,
      L, L + 8192 * 128, 1024, 128, 0, 0);
  // GEMM-vT: B2 = W_t2f @ Vtok^T + b_t2f (row bias)  (M=1024, N=128, K=1024)
  gemm64<<<dim3(16, 1, 2), dim3(256), 0, stream>>>(
      Wall, Wall + 1024 * 1024,
      Tok + 2 * 128 * 1024, Tok + 3 * 128 * 1024,
      b_t2f, b_t2f2,
      B2, B2 + 1024 * 128, 1024, 128, 1, 2);
  // instance-norm(amp) + softmax -> shifted bf16 aw
  in_softmax<<<dim3(8192, 2), dim3(128), 0, stream>>>(L, awb);
  // GEMM2: XP = aw @ B2^T + P  (M=8192, N=1024, K=128), bf16 out
  gemm128<<<dim3(64, 8, 2), dim3(256), 0, stream>>>(
      awb, awb + 8192 * 128, B2, B2 + 1024 * 128,
      Pa, Pb, (const float*)nullptr, (const float*)nullptr,
      XP0, XP1, 128, 1024, 1, 0);
  // GEMM3: d = XP @ w_df^T + b_df  (M=8192, N=1024, K=1024), bf16 out
  gemm128<<<dim3(64, 8, 2), dim3(256), 0, stream>>>(
      XP0, XP1, Wall + 2 * 1024 * 1024, Wall + 3 * 1024 * 1024,
      (const short*)nullptr, (const short*)nullptr,
      b_df, b_df2, dP, dA, 1024, 1024, 1, 1);
  // fused inverse: polar -> ifft_b -> ifft_c -> residual
  inv_fft2_res<<<dim3(1024), dim3(256), 0, stream>>>(dP, dA, feats, scalep, out);
  // cls token passthrough
  copy_cls<<<dim3(32), dim3(256), 0, stream>>>(feats, out);
}

// Round 6
// 322.934 us; speedup vs baseline: 2.0685x; 1.0786x over previous
//
#include <hip/hip_runtime.h>
#include <cstddef>

// ---------------------------------------------------------------------------
// Reins layer on MI355X — round 6.
// R5 kept. R6:
//  * gemm64_sm : GEMM1 with instance-norm+softmax fused in epilogue
//                (N=128 fits one tile -> block owns full rows). in_softmax
//                kernel and the 16 MB logits round-trip are gone.
//  * fast_atan2 polynomial in fwd_fft2_amp (err ~1.5e-4 rad, ok vs bf16).
//  * inv_fft2_res writes zb + Hermitian mirror directly (no zs array):
//                LDS 67->34 KB, 2->4 blocks/CU.
//  * GEMM3 left untouched (control: K-loop-bound at ~495 TF, not write-bound).
// ---------------------------------------------------------------------------

using bf16x8 = __attribute__((ext_vector_type(8))) short;   // 8 bf16 in 4 VGPRs
using f32x4  = __attribute__((ext_vector_type(4))) float;

__device__ inline short f2bf(float f) {
  union { float f; unsigned u; } v; v.f = f;
  unsigned r = v.u + 0x7FFFu + ((v.u >> 16) & 1u);  // round-to-nearest-even
  return (short)(r >> 16);
}
__device__ inline float bf2f(short s) {
  union { unsigned u; float f; } v; v.u = ((unsigned)(unsigned short)s) << 16;
  return v.f;
}
__device__ inline void async16(const void* g, void* l) {
  __builtin_amdgcn_global_load_lds(
      (const __attribute__((address_space(1))) void*)g,
      (__attribute__((address_space(3))) void*)l, 16, 0, 0);
}
__device__ inline float fast_atan2(float y, float x) {   // max err ~1.5e-4 rad
  float ax = fabsf(x), ay = fabsf(y);
  float mx = fmaxf(ax, ay), mn = fminf(ax, ay);
  float a = mn * __frcp_rn(mx);
  float s = a * a;
  float r = fmaf(fmaf(fmaf(-0.0464964749f, s, 0.15931422f), s, -0.327622764f),
                 s * a, a);
  if (ay > ax) r = 1.5707963267948966f - r;
  if (x < 0.f) r = 3.14159265358979f - r;
  return (y < 0.f) ? -r : r;
}

__device__ inline int PADi(int i) { return i + (i >> 5); }   // LDS anti-conflict
__device__ inline int rev4_8(int t) {                         // reverse 4 base-4 digits
  return ((t & 3) << 6) | (((t >> 2) & 3) << 4) | (((t >> 4) & 3) << 2) | ((t >> 6) & 3);
}

// 1024-pt in-place radix-4 DIF, 4 interleaved FFTs sharing barriers.
// SIGN=-1 fwd, +1 inv.  X[256*m+t] ends at pos = 4*rev4_8(t)+m.
template <int SIGN>
__device__ inline void fft1024x4(float2 (*zb)[1056], int t) {
#pragma unroll
  for (int s = 0; s < 5; ++s) {
    const int Q = 256 >> (2 * s);
    const int j = t & (Q - 1);
    const int i0 = ((t & ~(Q - 1)) << 2) + j;
    const float ang = (float)SIGN * 6.283185307179586f * (float)j / (float)(4 * Q);
    float s1, c1; __sincosf(ang, &s1, &c1);
    const float c2 = c1 * c1 - s1 * s1, s2 = 2.f * c1 * s1;
    const float c3 = c2 * c1 - s2 * s1, s3 = c2 * s1 + s2 * c1;
#pragma unroll
    for (int p = 0; p < 4; ++p) {
      float2* z = zb[p];
      float2 x0 = z[PADi(i0)];
      float2 x1 = z[PADi(i0 + Q)];
      float2 x2 = z[PADi(i0 + 2 * Q)];
      float2 x3 = z[PADi(i0 + 3 * Q)];
      float t0x = x0.x + x2.x, t0y = x0.y + x2.y;
      float t1x = x0.x - x2.x, t1y = x0.y - x2.y;
      float t2x = x1.x + x3.x, t2y = x1.y + x3.y;
      float t3x = x1.x - x3.x, t3y = x1.y - x3.y;
      float u0x = t0x + t2x, u0y = t0y + t2y;
      float u2x = t0x - t2x, u2y = t0y - t2y;
      float u1x, u1y, u3x, u3y;
      if (SIGN < 0) { u1x = t1x + t3y; u1y = t1y - t3x; u3x = t1x - t3y; u3y = t1y + t3x; }
      else          { u1x = t1x - t3y; u1y = t1y + t3x; u3x = t1x + t3y; u3y = t1y - t3x; }
      z[PADi(i0)]         = make_float2(u0x, u0y);
      z[PADi(i0 + Q)]     = make_float2(u1x * c1 - u1y * s1, u1x * s1 + u1y * c1);
      z[PADi(i0 + 2 * Q)] = make_float2(u2x * c2 - u2y * s2, u2x * s2 + u2y * c2);
      z[PADi(i0 + 3 * Q)] = make_float2(u3x * c3 - u3y * s3, u3x * s3 + u3y * c3);
    }
    __syncthreads();
  }
}

// ---- 1. fused fwd fft2 + amp/phase: one block per n ------------------------
__global__ __launch_bounds__(256) void fwd_fft2_amp(const float* __restrict__ feats,
                                                    short* __restrict__ ampb,
                                                    short* __restrict__ phaseb) {
  __shared__ float2 zb[4][1056];                    // 33.8 KB
  const int t = threadIdx.x;
  const int n = blockIdx.x;
  const float* base = feats + 8192 + (size_t)n * 8192;
#pragma unroll
  for (int p = 0; p < 4; ++p) {
    const float* x0 = base + (size_t)(2 * p) * 1024;
    const float* x1 = x0 + 1024;
#pragma unroll
    for (int m = 0; m < 4; ++m) {
      const int c = t + 256 * m;
      zb[p][PADi(c)] = make_float2(x0[c], x1[c]);
    }
  }
  __syncthreads();
  fft1024x4<-1>(zb, t);
  const int rt = rev4_8(t);
  const float cv[8] = {1.f, 0.70710678f, 0.f, -0.70710678f, -1.f, -0.70710678f, 0.f, 0.70710678f};
  const float sv[8] = {0.f, 0.70710678f, 1.f, 0.70710678f, 0.f, -0.70710678f, -1.f, -0.70710678f};
  short* ab = ampb + (size_t)n * 8192;
  short* pb = phaseb + (size_t)n * 8192;
#pragma unroll
  for (int m = 0; m < 4; ++m) {
    const int k = 256 * m + t;
    const int kk = (1024 - k) & 1023;
    const int pos  = 4 * rt + m;
    const int pos2 = 4 * rev4_8(kk & 255) + (kk >> 8);
    float xr[8], xi[8];
#pragma unroll
    for (int p = 0; p < 4; ++p) {
      float2 Z = zb[p][PADi(pos)];
      float2 W = zb[p][PADi(pos2)];
      xr[2 * p]     = 0.5f * (Z.x + W.x);
      xi[2 * p]     = 0.5f * (Z.y - W.y);
      xr[2 * p + 1] = 0.5f * (Z.y + W.y);
      xi[2 * p + 1] = 0.5f * (W.x - Z.x);
    }
#pragma unroll
    for (int kb = 0; kb < 8; ++kb) {
      float sr = 0.f, si = 0.f;
#pragma unroll
      for (int b = 0; b < 8; ++b) {
        const int p = (kb * b) & 7;                 // e^{-i pi p/4}
        sr += xr[b] * cv[p] + xi[b] * sv[p];
        si += xi[b] * cv[p] - xr[b] * sv[p];
      }
      float r2 = sr * sr + si * si;
      if (r2 < 1e-5f) r2 = 1e-5f;                   // _replace_denormals(re^2+im^2)
      float a = sqrtf(r2);
      float rr = (sr < 1e-5f && sr > -1e-5f) ? 1e-5f : sr;
      float ph = fast_atan2(si, rr);
      ab[kb * 1024 + k] = f2bf(a);
      pb[kb * 1024 + k] = f2bf(ph);
    }
  }
}

// ---- weight bf16 convert: 4 matrices [w_t2f, w_t2f2, w_df, w_df2] ----------
__global__ __launch_bounds__(256) void conv_w(const float* __restrict__ w1,
                                              const float* __restrict__ w2,
                                              const float* __restrict__ w3,
                                              const float* __restrict__ w4,
                                              short* __restrict__ dst) {
  const int z = blockIdx.y;                         // 0..3
  const float* W = (z == 0 ? w1 : z == 1 ? w2 : z == 2 ? w3 : w4)
                   + (size_t)blockIdx.x * 1024;
  short* D = dst + ((size_t)z * 1024 + blockIdx.x) * 1024;
  const int t = threadIdx.x * 4;
  float4 v = *(const float4*)(W + t);
  D[t] = f2bf(v.x); D[t + 1] = f2bf(v.y); D[t + 2] = f2bf(v.z); D[t + 3] = f2bf(v.w);
}

// ---- token bf16 convert: [z0 s0, z1 s0, z0 s1, z1 s1], rows zero-padded ----
__global__ __launch_bounds__(256) void conv_tok(const float* __restrict__ lt1,
                                                const float* __restrict__ lt2,
                                                const int* __restrict__ layerp,
                                                short* __restrict__ dst) {
  const int zz = blockIdx.y;                        // z = zz&1, shift = zz>>1
  const int z = zz & 1, shift = zz >> 1;
  const int row = blockIdx.x;                       // 0..127
  short* D = dst + ((size_t)zz * 128 + row) * 1024;
  const int t = threadIdx.x * 4;
  if (row + shift < 100) {
    const float* S = (z ? lt2 : lt1) + (size_t)layerp[0] * 102400
                     + (size_t)(row + shift) * 1024;
    float4 v = *(const float4*)(S + t);
    D[t] = f2bf(v.x); D[t + 1] = f2bf(v.y); D[t + 2] = f2bf(v.z); D[t + 3] = f2bf(v.w);
  } else {
    D[t] = 0; D[t + 1] = 0; D[t + 2] = 0; D[t + 3] = 0;
  }
}

// ------------- m97-style bf16 GEMM:  C = A(MxK) @ B(NxK)^T ------------------
// 128x128 tile.  biasMode: 0=none, 1=per-col, 2=per-row.
__global__ __launch_bounds__(256) void gemm128(
    const short* A0, const short* A1,       // M x K bf16
    const short* B0, const short* B1,       // N x K bf16
    const short* Add0, const short* Add1,   // optional bf16 addend at C index
    const float* bias0, const float* bias1, // optional fp32 bias
    void* C0v, void* C1v,
    int K, int ldc, int outBf16, int biasMode) {
  const int z = blockIdx.z;
  const short* A   = z ? A1 : A0;
  const short* B   = z ? B1 : B0;
  const short* Add = z ? Add1 : Add0;
  const float* bias = z ? bias1 : bias0;
  void* Cv = z ? C1v : C0v;

  __shared__ __align__(16) short As[128 * 32];
  __shared__ __align__(16) short Bs[128 * 32];

  const int tid = threadIdx.x;
  const int wave = tid >> 6, lane = tid & 63;
  const int m16 = lane & 15, quad = lane >> 4;
  const int wm = (wave & 1) * 64, wn = (wave >> 1) * 64;

  f32x4 acc[4][4];
#pragma unroll
  for (int i = 0; i < 4; ++i)
#pragma unroll
    for (int j = 0; j < 4; ++j) acc[i][j] = (f32x4){0.f, 0.f, 0.f, 0.f};

  const int r0 = tid >> 2;                              // 0..63
  const int csw = (((tid & 3) ^ ((r0 >> 1) & 3)) * 8);  // elems
  const short* aSrc0 = A + (size_t)(blockIdx.x * 128 + r0) * K + csw;
  const short* aSrc1 = aSrc0 + (size_t)64 * K;
  const short* bSrc0 = B + (size_t)(blockIdx.y * 128 + r0) * K + csw;
  const short* bSrc1 = bSrc0 + (size_t)64 * K;
  short* aDst0 = As + tid * 8;
  short* aDst1 = As + 2048 + tid * 8;
  short* bDst0 = Bs + tid * 8;
  short* bDst1 = Bs + 2048 + tid * 8;

  const int fcol = ((quad ^ ((m16 >> 1) & 3)) * 8) + m16 * 32;

  for (int k0 = 0; k0 < K; k0 += 32) {
    async16(aSrc0 + k0, aDst0);
    async16(aSrc1 + k0, aDst1);
    async16(bSrc0 + k0, bDst0);
    async16(bSrc1 + k0, bDst1);
    __syncthreads();
    bf16x8 af[4], bg[4];
#pragma unroll
    for (int ib = 0; ib < 4; ++ib)
      af[ib] = *(const bf16x8*)(As + (wm + ib * 16) * 32 + fcol);
#pragma unroll
    for (int jb = 0; jb < 4; ++jb)
      bg[jb] = *(const bf16x8*)(Bs + (wn + jb * 16) * 32 + fcol);
#pragma unroll
    for (int ib = 0; ib < 4; ++ib)
#pragma unroll
      for (int jb = 0; jb < 4; ++jb)
        acc[ib][jb] = __builtin_amdgcn_mfma_f32_16x16x32_bf16(af[ib], bg[jb], acc[ib][jb], 0, 0, 0);
    __syncthreads();
  }

#pragma unroll
  for (int ib = 0; ib < 4; ++ib) {
    const int rowb = blockIdx.x * 128 + wm + ib * 16 + quad * 4;
#pragma unroll
    for (int jb = 0; jb < 4; ++jb) {
      const int col = blockIdx.y * 128 + wn + jb * 16 + m16;
      const float bcv = (biasMode == 1) ? bias[col] : 0.f;
#pragma unroll
      for (int r = 0; r < 4; ++r) {
        const size_t idx = (size_t)(rowb + r) * (size_t)ldc + col;
        float v = acc[ib][jb][r] + bcv;
        if (biasMode == 2) v += bias[rowb + r];
        if (Add) v += bf2f(Add[idx]);
        if (outBf16) ((short*)Cv)[idx] = f2bf(v);
        else         ((float*)Cv)[idx] = v;
      }
    }
  }
}

// ------------- 64x128-tile variant (vT GEMM) --------------------------------
__global__ __launch_bounds__(256) void gemm64(
    const short* A0, const short* A1,       // M x K bf16
    const short* B0, const short* B1,       // 128 x K bf16
    const float* bias0, const float* bias1, // optional fp32 bias
    void* C0v, void* C1v,
    int K, int ldc, int outBf16, int biasMode) {
  const int z = blockIdx.z;
  const short* A   = z ? A1 : A0;
  const short* B   = z ? B1 : B0;
  const float* bias = z ? bias1 : bias0;
  void* Cv = z ? C1v : C0v;

  __shared__ __align__(16) short As[64 * 32];
  __shared__ __align__(16) short Bs[128 * 32];

  const int tid = threadIdx.x;
  const int wave = tid >> 6, lane = tid & 63;
  const int m16 = lane & 15, quad = lane >> 4;
  const int wm = (wave & 1) * 32, wn = (wave >> 1) * 64;

  f32x4 acc[2][4];
#pragma unroll
  for (int i = 0; i < 2; ++i)
#pragma unroll
    for (int j = 0; j < 4; ++j) acc[i][j] = (f32x4){0.f, 0.f, 0.f, 0.f};

  const int r0 = tid >> 2;                              // 0..63
  const int csw = (((tid & 3) ^ ((r0 >> 1) & 3)) * 8);
  const short* aSrc  = A + (size_t)(blockIdx.x * 64 + r0) * K + csw;
  const short* bSrc0 = B + (size_t)r0 * K + csw;
  const short* bSrc1 = bSrc0 + (size_t)64 * K;
  short* aDst  = As + tid * 8;
  short* bDst0 = Bs + tid * 8;
  short* bDst1 = Bs + 2048 + tid * 8;

  const int fcol = ((quad ^ ((m16 >> 1) & 3)) * 8) + m16 * 32;

  for (int k0 = 0; k0 < K; k0 += 32) {
    async16(aSrc + k0, aDst);
    async16(bSrc0 + k0, bDst0);
    async16(bSrc1 + k0, bDst1);
    __syncthreads();
    bf16x8 af[2], bg[4];
#pragma unroll
    for (int ib = 0; ib < 2; ++ib)
      af[ib] = *(const bf16x8*)(As + (wm + ib * 16) * 32 + fcol);
#pragma unroll
    for (int jb = 0; jb < 4; ++jb)
      bg[jb] = *(const bf16x8*)(Bs + (wn + jb * 16) * 32 + fcol);
#pragma unroll
    for (int ib = 0; ib < 2; ++ib)
#pragma unroll
      for (int jb = 0; jb < 4; ++jb)
        acc[ib][jb] = __builtin_amdgcn_mfma_f32_16x16x32_bf16(af[ib], bg[jb], acc[ib][jb], 0, 0, 0);
    __syncthreads();
  }

#pragma unroll
  for (int ib = 0; ib < 2; ++ib) {
    const int rowb = blockIdx.x * 64 + wm + ib * 16 + quad * 4;
#pragma unroll
    for (int jb = 0; jb < 4; ++jb) {
      const int col = wn + jb * 16 + m16;
      const float bcv = (biasMode == 1) ? bias[col] : 0.f;
#pragma unroll
      for (int r = 0; r < 4; ++r) {
        const size_t idx = (size_t)(rowb + r) * (size_t)ldc + col;
        float v = acc[ib][jb][r] + bcv;
        if (biasMode == 2) v += bias[rowb + r];
        if (outBf16) ((short*)Cv)[idx] = f2bf(v);
        else         ((float*)Cv)[idx] = v;
      }
    }
  }
}

// ---- GEMM1 + fused instance-norm(z=1) + softmax -> shifted bf16 aw ---------
// 64x128 tile, N=128 = full logits row per block.
__global__ __launch_bounds__(256) void gemm64_sm(
    const short* A0, const short* A1,       // 8192 x 1024 bf16 (phase, amp)
    const short* Tok,                       // 2 x 128 x 1024 bf16 tokens
    short* __restrict__ awb) {              // 2 x 8192 x 128 bf16 out
  const int z = blockIdx.z;
  const short* A = z ? A1 : A0;
  const short* B = Tok + (size_t)z * 128 * 1024;
  const int K = 1024;

  __shared__ __align__(16) short As[64 * 32];
  __shared__ __align__(16) short Bs[128 * 32];
  __shared__ float ltile[64][129];                  // 33 KB, pad129: conflict-free
  __shared__ float reds[64][4], redq[64][4];

  const int tid = threadIdx.x;
  const int wave = tid >> 6, lane = tid & 63;
  const int m16 = lane & 15, quad = lane >> 4;
  const int wm = (wave & 1) * 32, wn = (wave >> 1) * 64;

  f32x4 acc[2][4];
#pragma unroll
  for (int i = 0; i < 2; ++i)
#pragma unroll
    for (int j = 0; j < 4; ++j) acc[i][j] = (f32x4){0.f, 0.f, 0.f, 0.f};

  const int r0 = tid >> 2;
  const int csw = (((tid & 3) ^ ((r0 >> 1) & 3)) * 8);
  const short* aSrc  = A + (size_t)(blockIdx.x * 64 + r0) * K + csw;
  const short* bSrc0 = B + (size_t)r0 * K + csw;
  const short* bSrc1 = bSrc0 + (size_t)64 * K;
  short* aDst  = As + tid * 8;
  short* bDst0 = Bs + tid * 8;
  short* bDst1 = Bs + 2048 + tid * 8;
  const int fcol = ((quad ^ ((m16 >> 1) & 3)) * 8) + m16 * 32;

  for (int k0 = 0; k0 < K; k0 += 32) {
    async16(aSrc + k0, aDst);
    async16(bSrc0 + k0, bDst0);
    async16(bSrc1 + k0, bDst1);
    __syncthreads();
    bf16x8 af[2], bg[4];
#pragma unroll
    for (int ib = 0; ib < 2; ++ib)
      af[ib] = *(const bf16x8*)(As + (wm + ib * 16) * 32 + fcol);
#pragma unroll
    for (int jb = 0; jb < 4; ++jb)
      bg[jb] = *(const bf16x8*)(Bs + (wn + jb * 16) * 32 + fcol);
#pragma unroll
    for (int ib = 0; ib < 2; ++ib)
#pragma unroll
      for (int jb = 0; jb < 4; ++jb)
        acc[ib][jb] = __builtin_amdgcn_mfma_f32_16x16x32_bf16(af[ib], bg[jb], acc[ib][jb], 0, 0, 0);
    __syncthreads();
  }

  // stage logits tile to LDS (rows 0..63 x cols 0..127)
#pragma unroll
  for (int ib = 0; ib < 2; ++ib)
#pragma unroll
    for (int jb = 0; jb < 4; ++jb)
#pragma unroll
      for (int r = 0; r < 4; ++r)
        ltile[wm + ib * 16 + quad * 4 + r][wn + jb * 16 + m16] = acc[ib][jb][r];
  __syncthreads();

  // fused instance-norm + softmax: 4 threads per row
  const int row = tid >> 2, l4 = tid & 3;
  float s = 0.f, q = 0.f;
  for (int c = l4; c < 100; c += 4) { float x = ltile[row][c]; s += x; q += x * x; }
  reds[row][l4] = s; redq[row][l4] = q;
  __syncthreads();
  const float ssum = reds[row][0] + reds[row][1] + reds[row][2] + reds[row][3];
  const float qsum = redq[row][0] + redq[row][1] + redq[row][2] + redq[row][3];
  __syncthreads();
  const float mu = ssum * 0.01f;
  const float rinv = rsqrtf(fmaxf(qsum * 0.01f - mu * mu, 0.f) + 1e-5f);
  float mx = -3.4e38f;
  for (int c = l4; c < 100; c += 4) {
    float x = ltile[row][c];
    if (z == 1) x = (x - mu) * rinv;                // instance-norm (amp path)
    x *= 0.03125f;                                  // * C^{-1/2}
    ltile[row][c] = x;
    mx = fmaxf(mx, x);
  }
  reds[row][l4] = mx;
  __syncthreads();
  mx = fmaxf(fmaxf(reds[row][0], reds[row][1]), fmaxf(reds[row][2], reds[row][3]));
  __syncthreads();
  float es = 0.f;
  for (int c = l4; c < 100; c += 4) {
    float e = __expf(ltile[row][c] - mx);
    ltile[row][c] = e; es += e;
  }
  reds[row][l4] = es;
  __syncthreads();
  const float tot = reds[row][0] + reds[row][1] + reds[row][2] + reds[row][3];
  const float inv = 1.f / tot;
  short* Aout = awb + ((size_t)z * 8192 + (size_t)blockIdx.x * 64 + row) * 128;
  for (int c = l4; c < 100; c += 4)
    if (c >= 1) Aout[c - 1] = f2bf(ltile[row][c] * inv);  // aw[k]=attn[k+1]
  for (int k = 96 + l4; k < 128; k += 4)
    if (k >= 99) Aout[k] = 0;                             // zero pad 99..127
}

// ---- fused inverse: polar->z, 8-pt ifft (regs, + Hermitian mirror write), --
// ---- packed 1024-pt ifft, residual.  One block per n. ----------------------
__global__ __launch_bounds__(256) void inv_fft2_res(const short* __restrict__ dPb,
                                                    const short* __restrict__ dAb,
                                                    const float* __restrict__ feats,
                                                    const float* __restrict__ scalep,
                                                    float* __restrict__ out) {
  __shared__ float2 zb[4][1056];                    // 33.8 KB only
  const int t = threadIdx.x;
  const int n = blockIdx.x;
  const short* pp = dPb + (size_t)n * 8192;
  const short* ap = dAb + (size_t)n * 8192;
  const float cv[8] = {1.f, 0.70710678f, 0.f, -0.70710678f, -1.f, -0.70710678f, 0.f, 0.70710678f};
  const float sv[8] = {0.f, 0.70710678f, 1.f, 0.70710678f, 0.f, -0.70710678f, -1.f, -0.70710678f};
  const float invs = 0.022097086912079608f;         // 1/sqrt(2048)
  const float inv8 = 0.35355339059327373f;          // 1/sqrt(8) (ortho)
  for (int k = t; k < 513; k += 256) {
    float zr[8], zi[8];
#pragma unroll
    for (int b = 0; b < 8; ++b) {
      float p = bf2f(pp[b * 1024 + k]);
      float a = bf2f(ap[b * 1024 + k]) * invs;
      float s, c; __sincosf(p, &s, &c);
      zr[b] = c * a; zi[b] = s * a;
    }
#pragma unroll
    for (int p4 = 0; p4 < 4; ++p4) {
      float2 a2, b2;                                // Z[2p], Z[2p+1] after ifft_b
#pragma unroll
      for (int h = 0; h < 2; ++h) {
        const int bp = 2 * p4 + h;
        float sr = 0.f, si = 0.f;
#pragma unroll
        for (int b = 0; b < 8; ++b) {
          const int p = (bp * b) & 7;               // e^{+i pi p/4}
          sr += zr[b] * cv[p] - zi[b] * sv[p];
          si += zi[b] * cv[p] + zr[b] * sv[p];
        }
        if (h == 0) a2 = make_float2(sr * inv8, si * inv8);
        else        b2 = make_float2(sr * inv8, si * inv8);
      }
      // Y = Za + i*Zb at k; Hermitian mirror at 1024-k
      zb[p4][PADi(k)] = make_float2(a2.x - b2.y, a2.y + b2.x);
      if (k >= 1 && k <= 511)
        zb[p4][PADi(1024 - k)] = make_float2(a2.x + b2.y, b2.x - a2.y);
    }
  }
  __syncthreads();
  fft1024x4<1>(zb, t);
  const int rt = rev4_8(t);
  const float s = scalep[0] * 0.03125f;             // scale * 1/sqrt(1024)
#pragma unroll
  for (int p = 0; p < 4; ++p) {
    const size_t ob0 = 8192 + ((size_t)n * 8 + 2 * p) * 1024;
    const size_t ob1 = ob0 + 1024;
#pragma unroll
    for (int m = 0; m < 4; ++m) {
      const int nn = 256 * m + t;
      float2 y = zb[p][PADi(4 * rt + m)];
      out[ob0 + nn] = feats[ob0 + nn] + y.x * s;
      out[ob1 + nn] = feats[ob1 + nn] + y.y * s;
    }
  }
}

__global__ __launch_bounds__(256) void copy_cls(const float* __restrict__ feats,
                                                float* __restrict__ out) {
  const int i = blockIdx.x * 256 + threadIdx.x;
  if (i < 8192) out[i] = feats[i];
}

// ---------------------------------------------------------------------------
extern "C" void kernel_launch(void* const* d_in, const int* in_sizes, int n_in,
                              void* d_out, int out_size, void* d_ws, size_t ws_size,
                              hipStream_t stream) {
  const float* feats  = (const float*)d_in[0];
  const float* lt1    = (const float*)d_in[1];
  const float* lt2    = (const float*)d_in[2];
  const float* w_t2f  = (const float*)d_in[3];
  const float* b_t2f  = (const float*)d_in[4];
  const float* w_df   = (const float*)d_in[5];
  const float* b_df   = (const float*)d_in[6];
  const float* w_t2f2 = (const float*)d_in[7];
  const float* b_t2f2 = (const float*)d_in[8];
  const float* w_df2  = (const float*)d_in[9];
  const float* b_df2  = (const float*)d_in[10];
  const float* scalep = (const float*)d_in[11];
  const int*   layerp = (const int*)d_in[12];
  float* out = (float*)d_out;
  (void)in_sizes; (void)n_in; (void)out_size; (void)ws_size;

  const size_t SZ = 8192ull * 1024ull;              // 8,388,608 elements
  short* Pa   = (short*)d_ws;                       // phase bf16 (16 MB)
  short* Pb   = Pa + SZ;                            // amp   bf16 (16 MB)
  short* awb  = Pb + SZ;                            // aw bf16, 2x8192x128 (4 MB)
  short* Tok  = awb + 2ull * 8192 * 128;            // tokens bf16, 4x128x1024 (1 MB)
  short* Wall = Tok + 4ull * 128 * 1024;            // weights bf16, 4x1024x1024 (8 MB)
  short* B2   = Wall + 4ull * 1024 * 1024;          // v^T bf16, 2x1024x128 (0.5 MB)
  short* XP0  = B2 + 2ull * 1024 * 128;             // (df+P) bf16 (16 MB)
  short* XP1  = XP0 + SZ;                           // (16 MB)
  short* dP   = XP1 + SZ;                           // d_phase bf16 (16 MB)
  short* dA   = dP + SZ;                            // d_amp bf16 (16 MB)

  // 1: fused forward fft2 + amp/phase -> bf16
  fwd_fft2_amp<<<dim3(1024), dim3(256), 0, stream>>>(feats, Pb, Pa);
  // operand conversion (tiny)
  conv_w<<<dim3(1024, 4), dim3(256), 0, stream>>>(w_t2f, w_t2f2, w_df, w_df2, Wall);
  conv_tok<<<dim3(128, 4), dim3(256), 0, stream>>>(lt1, lt2, layerp, Tok);
  // GEMM1 + instance-norm + softmax -> shifted bf16 aw  (M=8192, N=128, K=1024)
  gemm64_sm<<<dim3(128, 1, 2), dim3(256), 0, stream>>>(Pa, Pb, Tok, awb);
  // GEMM-vT: B2 = W_t2f @ Vtok^T + b_t2f (row bias)  (M=1024, N=128, K=1024)
  gemm64<<<dim3(16, 1, 2), dim3(256), 0, stream>>>(
      Wall, Wall + 1024 * 1024,
      Tok + 2 * 128 * 1024, Tok + 3 * 128 * 1024,
      b_t2f, b_t2f2,
      B2, B2 + 1024 * 128, 1024, 128, 1, 2);
  // GEMM2: XP = aw @ B2^T + P  (M=8192, N=1024, K=128), bf16 out
  gemm128<<<dim3(64, 8, 2), dim3(256), 0, stream>>>(
      awb, awb + 8192 * 128, B2, B2 + 1024 * 128,
      Pa, Pb, (const float*)nullptr, (const float*)nullptr,
      XP0, XP1, 128, 1024, 1, 0);
  // GEMM3: d = XP @ w_df^T + b_df  (M=8192, N=1024, K=1024), bf16 out
  gemm128<<<dim3(64, 8, 2), dim3(256), 0, stream>>>(
      XP0, XP1, Wall + 2 * 1024 * 1024, Wall + 3 * 1024 * 1024,
      (const short*)nullptr, (const short*)nullptr,
      b_df, b_df2, dP, dA, 1024, 1024, 1, 1);
  // fused inverse: polar -> ifft_b -> ifft_c -> residual
  inv_fft2_res<<<dim3(1024), dim3(256), 0, stream>>>(dP, dA, feats, scalep, out);
  // cls token passthrough
  copy_cls<<<dim3(32), dim3(256), 0, stream>>>(feats, out);
}

// Round 8
// 291.398 us; speedup vs baseline: 2.2923x; 1.1082x over previous
//
#include <hip/hip_runtime.h>
#include <cstddef>

// ---------------------------------------------------------------------------
// Reins layer on MI355X — round 8 (R7 + one-line fix).
// R7 structure kept:
//  * GEMM2 eliminated algebraically: d = aw@(v@w_df^T) + P@w_df^T + b.
//  * gemm32_sm: 32-row tiles -> 512 blocks (2/CU).
//  * conv_all single dispatch.
// R8 fix: gemm32_sm A-fragment read was As+(wm+m16)*32+fcol, but fcol already
// includes m16*32 -> OOB read into Bs -> inf/NaN softmax.  Now As+wm*32+fcol.
// ---------------------------------------------------------------------------

using bf16x8 = __attribute__((ext_vector_type(8))) short;   // 8 bf16 in 4 VGPRs
using f32x4  = __attribute__((ext_vector_type(4))) float;

__device__ inline short f2bf(float f) {
  union { float f; unsigned u; } v; v.f = f;
  unsigned r = v.u + 0x7FFFu + ((v.u >> 16) & 1u);  // round-to-nearest-even
  return (short)(r >> 16);
}
__device__ inline float bf2f(short s) {
  union { unsigned u; float f; } v; v.u = ((unsigned)(unsigned short)s) << 16;
  return v.f;
}
__device__ inline void async16(const void* g, void* l) {
  __builtin_amdgcn_global_load_lds(
      (const __attribute__((address_space(1))) void*)g,
      (__attribute__((address_space(3))) void*)l, 16, 0, 0);
}
__device__ inline float fast_atan2(float y, float x) {   // max err ~1.5e-4 rad
  float ax = fabsf(x), ay = fabsf(y);
  float mx = fmaxf(ax, ay), mn = fminf(ax, ay);
  float a = mn * __frcp_rn(mx);
  float s = a * a;
  float r = fmaf(fmaf(fmaf(-0.0464964749f, s, 0.15931422f), s, -0.327622764f),
                 s * a, a);
  if (ay > ax) r = 1.5707963267948966f - r;
  if (x < 0.f) r = 3.14159265358979f - r;
  return (y < 0.f) ? -r : r;
}

__device__ inline int PADi(int i) { return i + (i >> 5); }   // LDS anti-conflict
__device__ inline int rev4_8(int t) {                         // reverse 4 base-4 digits
  return ((t & 3) << 6) | (((t >> 2) & 3) << 4) | (((t >> 4) & 3) << 2) | ((t >> 6) & 3);
}

// 1024-pt in-place radix-4 DIF, 4 interleaved FFTs sharing barriers.
// SIGN=-1 fwd, +1 inv.  X[256*m+t] ends at pos = 4*rev4_8(t)+m.
template <int SIGN>
__device__ inline void fft1024x4(float2 (*zb)[1056], int t) {
#pragma unroll
  for (int s = 0; s < 5; ++s) {
    const int Q = 256 >> (2 * s);
    const int j = t & (Q - 1);
    const int i0 = ((t & ~(Q - 1)) << 2) + j;
    const float ang = (float)SIGN * 6.283185307179586f * (float)j / (float)(4 * Q);
    float s1, c1; __sincosf(ang, &s1, &c1);
    const float c2 = c1 * c1 - s1 * s1, s2 = 2.f * c1 * s1;
    const float c3 = c2 * c1 - s2 * s1, s3 = c2 * s1 + s2 * c1;
#pragma unroll
    for (int p = 0; p < 4; ++p) {
      float2* z = zb[p];
      float2 x0 = z[PADi(i0)];
      float2 x1 = z[PADi(i0 + Q)];
      float2 x2 = z[PADi(i0 + 2 * Q)];
      float2 x3 = z[PADi(i0 + 3 * Q)];
      float t0x = x0.x + x2.x, t0y = x0.y + x2.y;
      float t1x = x0.x - x2.x, t1y = x0.y - x2.y;
      float t2x = x1.x + x3.x, t2y = x1.y + x3.y;
      float t3x = x1.x - x3.x, t3y = x1.y - x3.y;
      float u0x = t0x + t2x, u0y = t0y + t2y;
      float u2x = t0x - t2x, u2y = t0y - t2y;
      float u1x, u1y, u3x, u3y;
      if (SIGN < 0) { u1x = t1x + t3y; u1y = t1y - t3x; u3x = t1x - t3y; u3y = t1y + t3x; }
      else          { u1x = t1x - t3y; u1y = t1y + t3x; u3x = t1x + t3y; u3y = t1y - t3x; }
      z[PADi(i0)]         = make_float2(u0x, u0y);
      z[PADi(i0 + Q)]     = make_float2(u1x * c1 - u1y * s1, u1x * s1 + u1y * c1);
      z[PADi(i0 + 2 * Q)] = make_float2(u2x * c2 - u2y * s2, u2x * s2 + u2y * c2);
      z[PADi(i0 + 3 * Q)] = make_float2(u3x * c3 - u3y * s3, u3x * s3 + u3y * c3);
    }
    __syncthreads();
  }
}

// ---- 1. fused fwd fft2 + amp/phase: one block per n ------------------------
__global__ __launch_bounds__(256) void fwd_fft2_amp(const float* __restrict__ feats,
                                                    short* __restrict__ ampb,
                                                    short* __restrict__ phaseb) {
  __shared__ float2 zb[4][1056];                    // 33.8 KB
  const int t = threadIdx.x;
  const int n = blockIdx.x;
  const float* base = feats + 8192 + (size_t)n * 8192;
#pragma unroll
  for (int p = 0; p < 4; ++p) {
    const float* x0 = base + (size_t)(2 * p) * 1024;
    const float* x1 = x0 + 1024;
#pragma unroll
    for (int m = 0; m < 4; ++m) {
      const int c = t + 256 * m;
      zb[p][PADi(c)] = make_float2(x0[c], x1[c]);
    }
  }
  __syncthreads();
  fft1024x4<-1>(zb, t);
  const int rt = rev4_8(t);
  const float cv[8] = {1.f, 0.70710678f, 0.f, -0.70710678f, -1.f, -0.70710678f, 0.f, 0.70710678f};
  const float sv[8] = {0.f, 0.70710678f, 1.f, 0.70710678f, 0.f, -0.70710678f, -1.f, -0.70710678f};
  short* ab = ampb + (size_t)n * 8192;
  short* pb = phaseb + (size_t)n * 8192;
#pragma unroll
  for (int m = 0; m < 4; ++m) {
    const int k = 256 * m + t;
    const int kk = (1024 - k) & 1023;
    const int pos  = 4 * rt + m;
    const int pos2 = 4 * rev4_8(kk & 255) + (kk >> 8);
    float xr[8], xi[8];
#pragma unroll
    for (int p = 0; p < 4; ++p) {
      float2 Z = zb[p][PADi(pos)];
      float2 W = zb[p][PADi(pos2)];
      xr[2 * p]     = 0.5f * (Z.x + W.x);
      xi[2 * p]     = 0.5f * (Z.y - W.y);
      xr[2 * p + 1] = 0.5f * (Z.y + W.y);
      xi[2 * p + 1] = 0.5f * (W.x - Z.x);
    }
#pragma unroll
    for (int kb = 0; kb < 8; ++kb) {
      float sr = 0.f, si = 0.f;
#pragma unroll
      for (int b = 0; b < 8; ++b) {
        const int p = (kb * b) & 7;                 // e^{-i pi p/4}
        sr += xr[b] * cv[p] + xi[b] * sv[p];
        si += xi[b] * cv[p] - xr[b] * sv[p];
      }
      float r2 = sr * sr + si * si;
      if (r2 < 1e-5f) r2 = 1e-5f;                   // _replace_denormals(re^2+im^2)
      float a = sqrtf(r2);
      float rr = (sr < 1e-5f && sr > -1e-5f) ? 1e-5f : sr;
      float ph = fast_atan2(si, rr);
      ab[kb * 1024 + k] = f2bf(a);
      pb[kb * 1024 + k] = f2bf(ph);
    }
  }
}

// ---- conv_all: weights + shifted/unshifted tokens + cls copy, one dispatch -
__global__ __launch_bounds__(256) void conv_all(
    const float* __restrict__ w1, const float* __restrict__ w2,
    const float* __restrict__ w3, const float* __restrict__ w4,
    const float* __restrict__ lt1, const float* __restrict__ lt2,
    const int* __restrict__ layerp, const float* __restrict__ feats,
    short* __restrict__ Wdst, short* __restrict__ Tdst,
    float* __restrict__ out) {
  const int id = blockIdx.x;
  const int t = threadIdx.x * 4;
  if (id < 4096) {                                  // weights: 4 x 1024 rows
    const int z = id >> 10, row = id & 1023;
    const float* W = (z == 0 ? w1 : z == 1 ? w2 : z == 2 ? w3 : w4)
                     + (size_t)row * 1024;
    short* D = Wdst + ((size_t)z * 1024 + row) * 1024;
    float4 v = *(const float4*)(W + t);
    D[t] = f2bf(v.x); D[t + 1] = f2bf(v.y); D[t + 2] = f2bf(v.z); D[t + 3] = f2bf(v.w);
  } else if (id < 4608) {                           // tokens: 4 x 128 rows
    const int i2 = id - 4096;
    const int zz = i2 >> 7, row = i2 & 127;
    const int z = zz & 1, shift = zz >> 1;
    short* D = Tdst + ((size_t)zz * 128 + row) * 1024;
    if (row + shift < 100) {
      const float* S = (z ? lt2 : lt1) + (size_t)layerp[0] * 102400
                       + (size_t)(row + shift) * 1024;
      float4 v = *(const float4*)(S + t);
      D[t] = f2bf(v.x); D[t + 1] = f2bf(v.y); D[t + 2] = f2bf(v.z); D[t + 3] = f2bf(v.w);
    } else {
      D[t] = 0; D[t + 1] = 0; D[t + 2] = 0; D[t + 3] = 0;
    }
  } else {                                          // cls: 32 blocks x 256
    const int i = (id - 4608) * 256 + threadIdx.x;
    out[i] = feats[i];
  }
}

// ------------- m97-style bf16 GEMM:  C = A(MxK) @ B(NxK)^T ------------------
// 128x128 tile.  biasMode: 0=none, 1=per-col, 2=per-row.
__global__ __launch_bounds__(256) void gemm128(
    const short* A0, const short* A1,       // M x K bf16
    const short* B0, const short* B1,       // N x K bf16
    const short* Add0, const short* Add1,   // optional bf16 addend at C index
    const float* bias0, const float* bias1, // optional fp32 bias
    void* C0v, void* C1v,
    int K, int ldc, int outBf16, int biasMode) {
  const int z = blockIdx.z;
  const short* A   = z ? A1 : A0;
  const short* B   = z ? B1 : B0;
  const short* Add = z ? Add1 : Add0;
  const float* bias = z ? bias1 : bias0;
  void* Cv = z ? C1v : C0v;

  __shared__ __align__(16) short As[128 * 32];
  __shared__ __align__(16) short Bs[128 * 32];

  const int tid = threadIdx.x;
  const int wave = tid >> 6, lane = tid & 63;
  const int m16 = lane & 15, quad = lane >> 4;
  const int wm = (wave & 1) * 64, wn = (wave >> 1) * 64;

  f32x4 acc[4][4];
#pragma unroll
  for (int i = 0; i < 4; ++i)
#pragma unroll
    for (int j = 0; j < 4; ++j) acc[i][j] = (f32x4){0.f, 0.f, 0.f, 0.f};

  const int r0 = tid >> 2;                              // 0..63
  const int csw = (((tid & 3) ^ ((r0 >> 1) & 3)) * 8);  // elems
  const short* aSrc0 = A + (size_t)(blockIdx.x * 128 + r0) * K + csw;
  const short* aSrc1 = aSrc0 + (size_t)64 * K;
  const short* bSrc0 = B + (size_t)(blockIdx.y * 128 + r0) * K + csw;
  const short* bSrc1 = bSrc0 + (size_t)64 * K;
  short* aDst0 = As + tid * 8;
  short* aDst1 = As + 2048 + tid * 8;
  short* bDst0 = Bs + tid * 8;
  short* bDst1 = Bs + 2048 + tid * 8;

  const int fcol = ((quad ^ ((m16 >> 1) & 3)) * 8) + m16 * 32;

  for (int k0 = 0; k0 < K; k0 += 32) {
    async16(aSrc0 + k0, aDst0);
    async16(aSrc1 + k0, aDst1);
    async16(bSrc0 + k0, bDst0);
    async16(bSrc1 + k0, bDst1);
    __syncthreads();
    bf16x8 af[4], bg[4];
#pragma unroll
    for (int ib = 0; ib < 4; ++ib)
      af[ib] = *(const bf16x8*)(As + (wm + ib * 16) * 32 + fcol);
#pragma unroll
    for (int jb = 0; jb < 4; ++jb)
      bg[jb] = *(const bf16x8*)(Bs + (wn + jb * 16) * 32 + fcol);
#pragma unroll
    for (int ib = 0; ib < 4; ++ib)
#pragma unroll
      for (int jb = 0; jb < 4; ++jb)
        acc[ib][jb] = __builtin_amdgcn_mfma_f32_16x16x32_bf16(af[ib], bg[jb], acc[ib][jb], 0, 0, 0);
    __syncthreads();
  }

#pragma unroll
  for (int ib = 0; ib < 4; ++ib) {
    const int rowb = blockIdx.x * 128 + wm + ib * 16 + quad * 4;
#pragma unroll
    for (int jb = 0; jb < 4; ++jb) {
      const int col = blockIdx.y * 128 + wn + jb * 16 + m16;
      const float bcv = (biasMode == 1) ? bias[col] : 0.f;
#pragma unroll
      for (int r = 0; r < 4; ++r) {
        const size_t idx = (size_t)(rowb + r) * (size_t)ldc + col;
        float v = acc[ib][jb][r] + bcv;
        if (biasMode == 2) v += bias[rowb + r];
        if (Add) v += bf2f(Add[idx]);
        if (outBf16) ((short*)Cv)[idx] = f2bf(v);
        else         ((float*)Cv)[idx] = v;
      }
    }
  }
}

// ---- dual-K fused GEMM: C = A1@B1^T (K1) + A2@B2^T (K2) + bias_col, bf16 ---
__global__ __launch_bounds__(256) void gemm128_dual(
    const short* A1_0, const short* A1_1,   // M x K1
    const short* B1_0, const short* B1_1,   // N x K1
    const short* A2_0, const short* A2_1,   // M x K2
    const short* B2_0, const short* B2_1,   // N x K2
    const float* bias0, const float* bias1,
    short* C0, short* C1, int K1, int K2, int ldc) {
  const int z = blockIdx.z;
  const short* A1 = z ? A1_1 : A1_0;
  const short* B1 = z ? B1_1 : B1_0;
  const short* A2 = z ? A2_1 : A2_0;
  const short* B2 = z ? B2_1 : B2_0;
  const float* bias = z ? bias1 : bias0;
  short* C = z ? C1 : C0;

  __shared__ __align__(16) short As[128 * 32];
  __shared__ __align__(16) short Bs[128 * 32];

  const int tid = threadIdx.x;
  const int wave = tid >> 6, lane = tid & 63;
  const int m16 = lane & 15, quad = lane >> 4;
  const int wm = (wave & 1) * 64, wn = (wave >> 1) * 64;

  f32x4 acc[4][4];
#pragma unroll
  for (int i = 0; i < 4; ++i)
#pragma unroll
    for (int j = 0; j < 4; ++j) acc[i][j] = (f32x4){0.f, 0.f, 0.f, 0.f};

  const int r0 = tid >> 2;
  const int csw = (((tid & 3) ^ ((r0 >> 1) & 3)) * 8);
  short* aDst0 = As + tid * 8;
  short* aDst1 = As + 2048 + tid * 8;
  short* bDst0 = Bs + tid * 8;
  short* bDst1 = Bs + 2048 + tid * 8;
  const int fcol = ((quad ^ ((m16 >> 1) & 3)) * 8) + m16 * 32;

#pragma unroll 1
  for (int phase = 0; phase < 2; ++phase) {
    const short* A = phase ? A2 : A1;
    const short* B = phase ? B2 : B1;
    const int K = phase ? K2 : K1;
    const short* aSrc0 = A + (size_t)(blockIdx.x * 128 + r0) * K + csw;
    const short* aSrc1 = aSrc0 + (size_t)64 * K;
    const short* bSrc0 = B + (size_t)(blockIdx.y * 128 + r0) * K + csw;
    const short* bSrc1 = bSrc0 + (size_t)64 * K;
    for (int k0 = 0; k0 < K; k0 += 32) {
      async16(aSrc0 + k0, aDst0);
      async16(aSrc1 + k0, aDst1);
      async16(bSrc0 + k0, bDst0);
      async16(bSrc1 + k0, bDst1);
      __syncthreads();
      bf16x8 af[4], bg[4];
#pragma unroll
      for (int ib = 0; ib < 4; ++ib)
        af[ib] = *(const bf16x8*)(As + (wm + ib * 16) * 32 + fcol);
#pragma unroll
      for (int jb = 0; jb < 4; ++jb)
        bg[jb] = *(const bf16x8*)(Bs + (wn + jb * 16) * 32 + fcol);
#pragma unroll
      for (int ib = 0; ib < 4; ++ib)
#pragma unroll
        for (int jb = 0; jb < 4; ++jb)
          acc[ib][jb] = __builtin_amdgcn_mfma_f32_16x16x32_bf16(af[ib], bg[jb], acc[ib][jb], 0, 0, 0);
      __syncthreads();
    }
  }

#pragma unroll
  for (int ib = 0; ib < 4; ++ib) {
    const int rowb = blockIdx.x * 128 + wm + ib * 16 + quad * 4;
#pragma unroll
    for (int jb = 0; jb < 4; ++jb) {
      const int col = blockIdx.y * 128 + wn + jb * 16 + m16;
      const float bcv = bias[col];
#pragma unroll
      for (int r = 0; r < 4; ++r) {
        const size_t idx = (size_t)(rowb + r) * (size_t)ldc + col;
        C[idx] = f2bf(acc[ib][jb][r] + bcv);
      }
    }
  }
}

// ------------- 64x128-tile variant (V2T GEMM) -------------------------------
__global__ __launch_bounds__(256) void gemm64(
    const short* A0, const short* A1,       // M x K bf16
    const short* B0, const short* B1,       // 128 x K bf16
    const float* bias0, const float* bias1, // optional fp32 bias
    void* C0v, void* C1v,
    int K, int ldc, int outBf16, int biasMode) {
  const int z = blockIdx.z;
  const short* A   = z ? A1 : A0;
  const short* B   = z ? B1 : B0;
  const float* bias = z ? bias1 : bias0;
  void* Cv = z ? C1v : C0v;

  __shared__ __align__(16) short As[64 * 32];
  __shared__ __align__(16) short Bs[128 * 32];

  const int tid = threadIdx.x;
  const int wave = tid >> 6, lane = tid & 63;
  const int m16 = lane & 15, quad = lane >> 4;
  const int wm = (wave & 1) * 32, wn = (wave >> 1) * 64;

  f32x4 acc[2][4];
#pragma unroll
  for (int i = 0; i < 2; ++i)
#pragma unroll
    for (int j = 0; j < 4; ++j) acc[i][j] = (f32x4){0.f, 0.f, 0.f, 0.f};

  const int r0 = tid >> 2;                              // 0..63
  const int csw = (((tid & 3) ^ ((r0 >> 1) & 3)) * 8);
  const short* aSrc  = A + (size_t)(blockIdx.x * 64 + r0) * K + csw;
  const short* bSrc0 = B + (size_t)r0 * K + csw;
  const short* bSrc1 = bSrc0 + (size_t)64 * K;
  short* aDst  = As + tid * 8;
  short* bDst0 = Bs + tid * 8;
  short* bDst1 = Bs + 2048 + tid * 8;

  const int fcol = ((quad ^ ((m16 >> 1) & 3)) * 8) + m16 * 32;

  for (int k0 = 0; k0 < K; k0 += 32) {
    async16(aSrc + k0, aDst);
    async16(bSrc0 + k0, bDst0);
    async16(bSrc1 + k0, bDst1);
    __syncthreads();
    bf16x8 af[2], bg[4];
#pragma unroll
    for (int ib = 0; ib < 2; ++ib)
      af[ib] = *(const bf16x8*)(As + (wm + ib * 16) * 32 + fcol);
#pragma unroll
    for (int jb = 0; jb < 4; ++jb)
      bg[jb] = *(const bf16x8*)(Bs + (wn + jb * 16) * 32 + fcol);
#pragma unroll
    for (int ib = 0; ib < 2; ++ib)
#pragma unroll
      for (int jb = 0; jb < 4; ++jb)
        acc[ib][jb] = __builtin_amdgcn_mfma_f32_16x16x32_bf16(af[ib], bg[jb], acc[ib][jb], 0, 0, 0);
    __syncthreads();
  }

#pragma unroll
  for (int ib = 0; ib < 2; ++ib) {
    const int rowb = blockIdx.x * 64 + wm + ib * 16 + quad * 4;
#pragma unroll
    for (int jb = 0; jb < 4; ++jb) {
      const int col = wn + jb * 16 + m16;
      const float bcv = (biasMode == 1) ? bias[col] : 0.f;
#pragma unroll
      for (int r = 0; r < 4; ++r) {
        const size_t idx = (size_t)(rowb + r) * (size_t)ldc + col;
        float v = acc[ib][jb][r] + bcv;
        if (biasMode == 2) v += bias[rowb + r];
        if (outBf16) ((short*)Cv)[idx] = f2bf(v);
        else         ((float*)Cv)[idx] = v;
      }
    }
  }
}

// ---- GEMM1 + fused instance-norm(z=1) + softmax -> shifted bf16 aw ---------
// 32x128 tile (512 blocks = 2/CU), N=128 = full logits row per block.
__global__ __launch_bounds__(256) void gemm32_sm(
    const short* A0, const short* A1,       // 8192 x 1024 bf16 (phase, amp)
    const short* Tok,                       // 2 x 128 x 1024 bf16 tokens
    short* __restrict__ awb) {              // 2 x 8192 x 128 bf16 out
  const int z = blockIdx.z;
  const short* A = z ? A1 : A0;
  const short* B = Tok + (size_t)z * 128 * 1024;
  const int K = 1024;

  __shared__ __align__(16) short As[32 * 32];
  __shared__ __align__(16) short Bs[128 * 32];
  __shared__ float ltile[32][129];
  __shared__ float red1[32][8], red2[32][8];

  const int tid = threadIdx.x;
  const int wave = tid >> 6, lane = tid & 63;
  const int m16 = lane & 15, quad = lane >> 4;
  const int wm = (wave & 1) * 16, wn = (wave >> 1) * 64;

  f32x4 acc[4];
#pragma unroll
  for (int j = 0; j < 4; ++j) acc[j] = (f32x4){0.f, 0.f, 0.f, 0.f};

  const int r0 = tid >> 2;                              // 0..63
  const int csw = (((tid & 3) ^ ((r0 >> 1) & 3)) * 8);
  const short* aSrc  = A + (size_t)(blockIdx.x * 32 + r0) * K + csw;  // tid<128
  const short* bSrc0 = B + (size_t)r0 * K + csw;
  const short* bSrc1 = bSrc0 + (size_t)64 * K;
  short* aDst  = As + tid * 8;
  short* bDst0 = Bs + tid * 8;
  short* bDst1 = Bs + 2048 + tid * 8;
  const int fcol = ((quad ^ ((m16 >> 1) & 3)) * 8) + m16 * 32;

  for (int k0 = 0; k0 < K; k0 += 32) {
    if (tid < 128) async16(aSrc + k0, aDst);
    async16(bSrc0 + k0, bDst0);
    async16(bSrc1 + k0, bDst1);
    __syncthreads();
    bf16x8 af = *(const bf16x8*)(As + wm * 32 + fcol);  // FIX: fcol has m16*32
    bf16x8 bg[4];
#pragma unroll
    for (int jb = 0; jb < 4; ++jb)
      bg[jb] = *(const bf16x8*)(Bs + (wn + jb * 16) * 32 + fcol);
#pragma unroll
    for (int jb = 0; jb < 4; ++jb)
      acc[jb] = __builtin_amdgcn_mfma_f32_16x16x32_bf16(af, bg[jb], acc[jb], 0, 0, 0);
    __syncthreads();
  }

  // stage logits tile to LDS (rows 0..31 x cols 0..127)
#pragma unroll
  for (int jb = 0; jb < 4; ++jb)
#pragma unroll
    for (int r = 0; r < 4; ++r)
      ltile[wm + quad * 4 + r][wn + jb * 16 + m16] = acc[jb][r];
  __syncthreads();

  // fused instance-norm + softmax: 8 threads per row
  const int row = tid >> 3, l8 = tid & 7;
  float s = 0.f, q = 0.f;
  for (int c = l8; c < 100; c += 8) { float x = ltile[row][c]; s += x; q += x * x; }
  red1[row][l8] = s; red2[row][l8] = q;
  __syncthreads();
  float ssum = 0.f, qsum = 0.f;
#pragma unroll
  for (int i = 0; i < 8; ++i) { ssum += red1[row][i]; qsum += red2[row][i]; }
  __syncthreads();
  const float mu = ssum * 0.01f;
  const float rinv = rsqrtf(fmaxf(qsum * 0.01f - mu * mu, 0.f) + 1e-5f);
  float mx = -3.4e38f;
  for (int c = l8; c < 100; c += 8) {
    float x = ltile[row][c];
    if (z == 1) x = (x - mu) * rinv;                // instance-norm (amp path)
    x *= 0.03125f;                                  // * C^{-1/2}
    ltile[row][c] = x;
    mx = fmaxf(mx, x);
  }
  red1[row][l8] = mx;
  __syncthreads();
#pragma unroll
  for (int i = 0; i < 8; ++i) mx = fmaxf(mx, red1[row][i]);
  __syncthreads();
  float es = 0.f;
  for (int c = l8; c < 100; c += 8) {
    float e = __expf(ltile[row][c] - mx);
    ltile[row][c] = e; es += e;
  }
  red1[row][l8] = es;
  __syncthreads();
  float tot = 0.f;
#pragma unroll
  for (int i = 0; i < 8; ++i) tot += red1[row][i];
  const float inv = 1.f / tot;
  short* Aout = awb + ((size_t)z * 8192 + (size_t)blockIdx.x * 32 + row) * 128;
  for (int c = l8; c < 100; c += 8)
    if (c >= 1) Aout[c - 1] = f2bf(ltile[row][c] * inv);  // aw[k]=attn[k+1]
  for (int k = l8; k < 128; k += 8)
    if (k >= 99) Aout[k] = 0;                             // zero pad 99..127
}

// ---- fused inverse: polar->z, 8-pt ifft (regs, + Hermitian mirror write), --
// ---- packed 1024-pt ifft, residual.  One block per n. ----------------------
__global__ __launch_bounds__(256) void inv_fft2_res(const short* __restrict__ dPb,
                                                    const short* __restrict__ dAb,
                                                    const float* __restrict__ feats,
                                                    const float* __restrict__ scalep,
                                                    float* __restrict__ out) {
  __shared__ float2 zb[4][1056];                    // 33.8 KB only
  const int t = threadIdx.x;
  const int n = blockIdx.x;
  const short* pp = dPb + (size_t)n * 8192;
  const short* ap = dAb + (size_t)n * 8192;
  const float cv[8] = {1.f, 0.70710678f, 0.f, -0.70710678f, -1.f, -0.70710678f, 0.f, 0.70710678f};
  const float sv[8] = {0.f, 0.70710678f, 1.f, 0.70710678f, 0.f, -0.70710678f, -1.f, -0.70710678f};
  const float invs = 0.022097086912079608f;         // 1/sqrt(2048)
  const float inv8 = 0.35355339059327373f;          // 1/sqrt(8) (ortho)
  for (int k = t; k < 513; k += 256) {
    float zr[8], zi[8];
#pragma unroll
    for (int b = 0; b < 8; ++b) {
      float p = bf2f(pp[b * 1024 + k]);
      float a = bf2f(ap[b * 1024 + k]) * invs;
      float s, c; __sincosf(p, &s, &c);
      zr[b] = c * a; zi[b] = s * a;
    }
#pragma unroll
    for (int p4 = 0; p4 < 4; ++p4) {
      float2 a2, b2;                                // Z[2p], Z[2p+1] after ifft_b
#pragma unroll
      for (int h = 0; h < 2; ++h) {
        const int bp = 2 * p4 + h;
        float sr = 0.f, si = 0.f;
#pragma unroll
        for (int b = 0; b < 8; ++b) {
          const int p = (bp * b) & 7;               // e^{+i pi p/4}
          sr += zr[b] * cv[p] - zi[b] * sv[p];
          si += zi[b] * cv[p] + zr[b] * sv[p];
        }
        if (h == 0) a2 = make_float2(sr * inv8, si * inv8);
        else        b2 = make_float2(sr * inv8, si * inv8);
      }
      // Y = Za + i*Zb at k; Hermitian mirror at 1024-k
      zb[p4][PADi(k)] = make_float2(a2.x - b2.y, a2.y + b2.x);
      if (k >= 1 && k <= 511)
        zb[p4][PADi(1024 - k)] = make_float2(a2.x + b2.y, b2.x - a2.y);
    }
  }
  __syncthreads();
  fft1024x4<1>(zb, t);
  const int rt = rev4_8(t);
  const float s = scalep[0] * 0.03125f;             // scale * 1/sqrt(1024)
#pragma unroll
  for (int p = 0; p < 4; ++p) {
    const size_t ob0 = 8192 + ((size_t)n * 8 + 2 * p) * 1024;
    const size_t ob1 = ob0 + 1024;
#pragma unroll
    for (int m = 0; m < 4; ++m) {
      const int nn = 256 * m + t;
      float2 y = zb[p][PADi(4 * rt + m)];
      out[ob0 + nn] = feats[ob0 + nn] + y.x * s;
      out[ob1 + nn] = feats[ob1 + nn] + y.y * s;
    }
  }
}

// ---------------------------------------------------------------------------
extern "C" void kernel_launch(void* const* d_in, const int* in_sizes, int n_in,
                              void* d_out, int out_size, void* d_ws, size_t ws_size,
                              hipStream_t stream) {
  const float* feats  = (const float*)d_in[0];
  const float* lt1    = (const float*)d_in[1];
  const float* lt2    = (const float*)d_in[2];
  const float* w_t2f  = (const float*)d_in[3];
  const float* b_t2f  = (const float*)d_in[4];
  const float* w_df   = (const float*)d_in[5];
  const float* b_df   = (const float*)d_in[6];
  const float* w_t2f2 = (const float*)d_in[7];
  const float* b_t2f2 = (const float*)d_in[8];
  const float* w_df2  = (const float*)d_in[9];
  const float* b_df2  = (const float*)d_in[10];
  const float* scalep = (const float*)d_in[11];
  const int*   layerp = (const int*)d_in[12];
  float* out = (float*)d_out;
  (void)in_sizes; (void)n_in; (void)out_size; (void)ws_size;

  const size_t SZ = 8192ull * 1024ull;              // 8,388,608 elements
  short* Pa   = (short*)d_ws;                       // phase bf16 (16 MB)
  short* Pb   = Pa + SZ;                            // amp   bf16 (16 MB)
  short* awb  = Pb + SZ;                            // aw bf16, 2x8192x128 (4 MB)
  short* Tok  = awb + 2ull * 8192 * 128;            // tokens bf16, 4x128x1024 (1 MB)
  short* Wall = Tok + 4ull * 128 * 1024;            // weights bf16, 4x1024x1024 (8 MB)
  short* vrow = Wall + 4ull * 1024 * 1024;          // v row-major, 2x128x1024 (0.5 MB)
  short* V2T  = vrow + 2ull * 128 * 1024;           // w_df@v^T, 2x1024x128 (0.5 MB)
  short* dP   = V2T + 2ull * 1024 * 128;            // d_phase bf16 (16 MB)
  short* dA   = dP + SZ;                            // d_amp bf16 (16 MB)

  // 1: fused forward fft2 + amp/phase -> bf16
  fwd_fft2_amp<<<dim3(1024), dim3(256), 0, stream>>>(feats, Pb, Pa);
  // 2: weights/tokens bf16 + cls copy, one dispatch
  conv_all<<<dim3(4640), dim3(256), 0, stream>>>(
      w_t2f, w_t2f2, w_df, w_df2, lt1, lt2, layerp, feats, Wall, Tok, out);
  // 3: GEMM1 + instance-norm + softmax -> shifted bf16 aw (M=8192,N=128,K=1024)
  gemm32_sm<<<dim3(256, 1, 2), dim3(256), 0, stream>>>(Pa, Pb, Tok, awb);
  // 4: v = Tok_sh @ w_t2f^T + b_t2f  (M=128, N=1024, K=1024), bf16 row-major
  gemm128<<<dim3(1, 8, 2), dim3(256), 0, stream>>>(
      Tok + 2 * 128 * 1024, Tok + 3 * 128 * 1024, Wall, Wall + 1024 * 1024,
      (const short*)nullptr, (const short*)nullptr,
      b_t2f, b_t2f2, vrow, vrow + 128 * 1024, 1024, 1024, 1, 1);
  // 5: V2T = w_df @ v^T  (M=1024, N=128, K=1024), bf16, ldc=128
  gemm64<<<dim3(16, 1, 2), dim3(256), 0, stream>>>(
      Wall + 2 * 1024 * 1024, Wall + 3 * 1024 * 1024,
      vrow, vrow + 128 * 1024,
      (const float*)nullptr, (const float*)nullptr,
      V2T, V2T + 1024 * 128, 1024, 128, 1, 0);
  // 6: d = aw @ V2T^T + P @ w_df^T + b_df  (M=8192, N=1024, K=128+1024), bf16
  gemm128_dual<<<dim3(64, 8, 2), dim3(256), 0, stream>>>(
      awb, awb + 8192 * 128, V2T, V2T + 1024 * 128,
      Pa, Pb, Wall + 2 * 1024 * 1024, Wall + 3 * 1024 * 1024,
      b_df, b_df2, dP, dA, 128, 1024, 1024);
  // 7: fused inverse: polar -> ifft_b -> ifft_c -> residual (+cls done in 2)
  inv_fft2_res<<<dim3(1024), dim3(256), 0, stream>>>(dP, dA, feats, scalep, out);
}

// Round 9
// 270.414 us; speedup vs baseline: 2.4702x; 1.0776x over previous
//
#include <hip/hip_runtime.h>
#include <cstddef>

// ---------------------------------------------------------------------------
// Reins layer on MI355X — round 9.
// R8 kept. R9:
//  * conv_all grid-fused into fwd dispatch; v-GEMM grid-fused into gemm_sm
//    dispatch (heterogeneous grid, union LDS).  Two dispatches gone.
//  * 8-pt DFTs replaced with radix-2 FFT8 butterfly nets (~4.5x fewer VALU).
//  * inv_fft2_res split into 2 blocks per n (17 KB LDS -> 8 blocks/CU).
//  * gemm128_dual untouched (control, ~63 us).
// ---------------------------------------------------------------------------

using bf16x8 = __attribute__((ext_vector_type(8))) short;   // 8 bf16 in 4 VGPRs
using f32x4  = __attribute__((ext_vector_type(4))) float;

__device__ inline short f2bf(float f) {
  union { float f; unsigned u; } v; v.f = f;
  unsigned r = v.u + 0x7FFFu + ((v.u >> 16) & 1u);  // round-to-nearest-even
  return (short)(r >> 16);
}
__device__ inline float bf2f(short s) {
  union { unsigned u; float f; } v; v.u = ((unsigned)(unsigned short)s) << 16;
  return v.f;
}
__device__ inline void async16(const void* g, void* l) {
  __builtin_amdgcn_global_load_lds(
      (const __attribute__((address_space(1))) void*)g,
      (__attribute__((address_space(3))) void*)l, 16, 0, 0);
}
__device__ inline float fast_atan2(float y, float x) {   // max err ~1.5e-4 rad
  float ax = fabsf(x), ay = fabsf(y);
  float mx = fmaxf(ax, ay), mn = fminf(ax, ay);
  float a = mn * __frcp_rn(mx);
  float s = a * a;
  float r = fmaf(fmaf(fmaf(-0.0464964749f, s, 0.15931422f), s, -0.327622764f),
                 s * a, a);
  if (ay > ax) r = 1.5707963267948966f - r;
  if (x < 0.f) r = 3.14159265358979f - r;
  return (y < 0.f) ? -r : r;
}

__device__ inline int PADi(int i) { return i + (i >> 5); }   // LDS anti-conflict
__device__ inline int rev4_8(int t) {                         // reverse 4 base-4 digits
  return ((t & 3) << 6) | (((t >> 2) & 3) << 4) | (((t >> 4) & 3) << 2) | ((t >> 6) & 3);
}

// ---- radix-2 DIF FFT8, natural-order in & out.  Verified vs e^{±2πik/8}. ---
__device__ inline void fft8_fwd(float* xr, float* xi) {      // X[k]=Σx e^{-2πikb/8}
  const float r = 0.70710678118654752f;
  float ar[4], ai[4], br[4], bi[4], tr, ti;
  ar[0]=xr[0]+xr[4]; ai[0]=xi[0]+xi[4]; br[0]=xr[0]-xr[4]; bi[0]=xi[0]-xi[4];
  ar[1]=xr[1]+xr[5]; ai[1]=xi[1]+xi[5];
  tr=xr[1]-xr[5]; ti=xi[1]-xi[5]; br[1]=(tr+ti)*r; bi[1]=(ti-tr)*r;   // *(1-i)r
  ar[2]=xr[2]+xr[6]; ai[2]=xi[2]+xi[6];
  tr=xr[2]-xr[6]; ti=xi[2]-xi[6]; br[2]=ti; bi[2]=-tr;                // *(-i)
  ar[3]=xr[3]+xr[7]; ai[3]=xi[3]+xi[7];
  tr=xr[3]-xr[7]; ti=xi[3]-xi[7]; br[3]=(ti-tr)*r; bi[3]=-(tr+ti)*r;  // *-(1+i)r
  float u0r=ar[0]+ar[2], u0i=ai[0]+ai[2], u1r=ar[1]+ar[3], u1i=ai[1]+ai[3];
  float v0r=ar[0]-ar[2], v0i=ai[0]-ai[2];
  tr=ar[1]-ar[3]; ti=ai[1]-ai[3];
  float v1r=ti, v1i=-tr;                                              // *(-i)
  xr[0]=u0r+u1r; xi[0]=u0i+u1i; xr[4]=u0r-u1r; xi[4]=u0i-u1i;
  xr[2]=v0r+v1r; xi[2]=v0i+v1i; xr[6]=v0r-v1r; xi[6]=v0i-v1i;
  u0r=br[0]+br[2]; u0i=bi[0]+bi[2]; u1r=br[1]+br[3]; u1i=bi[1]+bi[3];
  v0r=br[0]-br[2]; v0i=bi[0]-bi[2];
  tr=br[1]-br[3]; ti=bi[1]-bi[3];
  v1r=ti; v1i=-tr;
  xr[1]=u0r+u1r; xi[1]=u0i+u1i; xr[5]=u0r-u1r; xi[5]=u0i-u1i;
  xr[3]=v0r+v1r; xi[3]=v0i+v1i; xr[7]=v0r-v1r; xi[7]=v0i-v1i;
}
__device__ inline void fft8_inv(float* xr, float* xi) {      // X[k]=Σx e^{+2πikb/8}
  const float r = 0.70710678118654752f;
  float ar[4], ai[4], br[4], bi[4], tr, ti;
  ar[0]=xr[0]+xr[4]; ai[0]=xi[0]+xi[4]; br[0]=xr[0]-xr[4]; bi[0]=xi[0]-xi[4];
  ar[1]=xr[1]+xr[5]; ai[1]=xi[1]+xi[5];
  tr=xr[1]-xr[5]; ti=xi[1]-xi[5]; br[1]=(tr-ti)*r; bi[1]=(tr+ti)*r;   // *(1+i)r
  ar[2]=xr[2]+xr[6]; ai[2]=xi[2]+xi[6];
  tr=xr[2]-xr[6]; ti=xi[2]-xi[6]; br[2]=-ti; bi[2]=tr;                // *(+i)
  ar[3]=xr[3]+xr[7]; ai[3]=xi[3]+xi[7];
  tr=xr[3]-xr[7]; ti=xi[3]-xi[7]; br[3]=-(tr+ti)*r; bi[3]=(tr-ti)*r;  // *(-1+i)r
  float u0r=ar[0]+ar[2], u0i=ai[0]+ai[2], u1r=ar[1]+ar[3], u1i=ai[1]+ai[3];
  float v0r=ar[0]-ar[2], v0i=ai[0]-ai[2];
  tr=ar[1]-ar[3]; ti=ai[1]-ai[3];
  float v1r=-ti, v1i=tr;                                              // *(+i)
  xr[0]=u0r+u1r; xi[0]=u0i+u1i; xr[4]=u0r-u1r; xi[4]=u0i-u1i;
  xr[2]=v0r+v1r; xi[2]=v0i+v1i; xr[6]=v0r-v1r; xi[6]=v0i-v1i;
  u0r=br[0]+br[2]; u0i=bi[0]+bi[2]; u1r=br[1]+br[3]; u1i=bi[1]+bi[3];
  v0r=br[0]-br[2]; v0i=bi[0]-bi[2];
  tr=br[1]-br[3]; ti=bi[1]-bi[3];
  v1r=-ti; v1i=tr;
  xr[1]=u0r+u1r; xi[1]=u0i+u1i; xr[5]=u0r-u1r; xi[5]=u0i-u1i;
  xr[3]=v0r+v1r; xi[3]=v0i+v1i; xr[7]=v0r-v1r; xi[7]=v0i-v1i;
}

// 1024-pt in-place radix-4 DIF, NP interleaved FFTs sharing barriers.
// SIGN=-1 fwd, +1 inv.  X[256*m+t] ends at pos = 4*rev4_8(t)+m.
template <int SIGN, int NP>
__device__ inline void fft1024xN(float2 (*zb)[1056], int t) {
#pragma unroll
  for (int s = 0; s < 5; ++s) {
    const int Q = 256 >> (2 * s);
    const int j = t & (Q - 1);
    const int i0 = ((t & ~(Q - 1)) << 2) + j;
    const float ang = (float)SIGN * 6.283185307179586f * (float)j / (float)(4 * Q);
    float s1, c1; __sincosf(ang, &s1, &c1);
    const float c2 = c1 * c1 - s1 * s1, s2 = 2.f * c1 * s1;
    const float c3 = c2 * c1 - s2 * s1, s3 = c2 * s1 + s2 * c1;
#pragma unroll
    for (int p = 0; p < NP; ++p) {
      float2* z = zb[p];
      float2 x0 = z[PADi(i0)];
      float2 x1 = z[PADi(i0 + Q)];
      float2 x2 = z[PADi(i0 + 2 * Q)];
      float2 x3 = z[PADi(i0 + 3 * Q)];
      float t0x = x0.x + x2.x, t0y = x0.y + x2.y;
      float t1x = x0.x - x2.x, t1y = x0.y - x2.y;
      float t2x = x1.x + x3.x, t2y = x1.y + x3.y;
      float t3x = x1.x - x3.x, t3y = x1.y - x3.y;
      float u0x = t0x + t2x, u0y = t0y + t2y;
      float u2x = t0x - t2x, u2y = t0y - t2y;
      float u1x, u1y, u3x, u3y;
      if (SIGN < 0) { u1x = t1x + t3y; u1y = t1y - t3x; u3x = t1x - t3y; u3y = t1y + t3x; }
      else          { u1x = t1x - t3y; u1y = t1y + t3x; u3x = t1x + t3y; u3y = t1y - t3x; }
      z[PADi(i0)]         = make_float2(u0x, u0y);
      z[PADi(i0 + Q)]     = make_float2(u1x * c1 - u1y * s1, u1x * s1 + u1y * c1);
      z[PADi(i0 + 2 * Q)] = make_float2(u2x * c2 - u2y * s2, u2x * s2 + u2y * c2);
      z[PADi(i0 + 3 * Q)] = make_float2(u3x * c3 - u3y * s3, u3x * s3 + u3y * c3);
    }
    __syncthreads();
  }
}

// ---- 1. fused fwd fft2 + amp/phase + (conv weights/tokens/cls as extra -----
// ---- blocks).  Blocks [0,1024): FFT per n.  [1024, 5664): conv work. -------
__global__ __launch_bounds__(256) void fwd_fft2_amp_conv(
    const float* __restrict__ feats,
    short* __restrict__ ampb, short* __restrict__ phaseb,
    const float* __restrict__ w1, const float* __restrict__ w2,
    const float* __restrict__ w3, const float* __restrict__ w4,
    const float* __restrict__ lt1, const float* __restrict__ lt2,
    const int* __restrict__ layerp,
    short* __restrict__ Wdst, short* __restrict__ Tdst,
    float* __restrict__ out) {
  if (blockIdx.x >= 1024) {                         // ---- conv part ----
    const int id = blockIdx.x - 1024;
    const int t4 = threadIdx.x * 4;
    if (id < 4096) {                                // weights: 4 x 1024 rows
      const int z = id >> 10, row = id & 1023;
      const float* W = (z == 0 ? w1 : z == 1 ? w2 : z == 2 ? w3 : w4)
                       + (size_t)row * 1024;
      short* D = Wdst + ((size_t)z * 1024 + row) * 1024;
      float4 v = *(const float4*)(W + t4);
      D[t4] = f2bf(v.x); D[t4 + 1] = f2bf(v.y); D[t4 + 2] = f2bf(v.z); D[t4 + 3] = f2bf(v.w);
    } else if (id < 4608) {                         // tokens: 4 x 128 rows
      const int i2 = id - 4096;
      const int zz = i2 >> 7, row = i2 & 127;
      const int z = zz & 1, shift = zz >> 1;
      short* D = Tdst + ((size_t)zz * 128 + row) * 1024;
      if (row + shift < 100) {
        const float* S = (z ? lt2 : lt1) + (size_t)layerp[0] * 102400
                         + (size_t)(row + shift) * 1024;
        float4 v = *(const float4*)(S + t4);
        D[t4] = f2bf(v.x); D[t4 + 1] = f2bf(v.y); D[t4 + 2] = f2bf(v.z); D[t4 + 3] = f2bf(v.w);
      } else {
        D[t4] = 0; D[t4 + 1] = 0; D[t4 + 2] = 0; D[t4 + 3] = 0;
      }
    } else {                                        // cls: 32 blocks x 256
      const int i = (id - 4608) * 256 + threadIdx.x;
      out[i] = feats[i];
    }
    return;
  }
  // ---- FFT part ----
  __shared__ float2 zb[4][1056];                    // 33.8 KB
  const int t = threadIdx.x;
  const int n = blockIdx.x;
  const float* base = feats + 8192 + (size_t)n * 8192;
#pragma unroll
  for (int p = 0; p < 4; ++p) {
    const float* x0 = base + (size_t)(2 * p) * 1024;
    const float* x1 = x0 + 1024;
#pragma unroll
    for (int m = 0; m < 4; ++m) {
      const int c = t + 256 * m;
      zb[p][PADi(c)] = make_float2(x0[c], x1[c]);
    }
  }
  __syncthreads();
  fft1024xN<-1, 4>(zb, t);
  const int rt = rev4_8(t);
  short* ab = ampb + (size_t)n * 8192;
  short* pb = phaseb + (size_t)n * 8192;
#pragma unroll
  for (int m = 0; m < 4; ++m) {
    const int k = 256 * m + t;
    const int kk = (1024 - k) & 1023;
    const int pos  = 4 * rt + m;
    const int pos2 = 4 * rev4_8(kk & 255) + (kk >> 8);
    float xr[8], xi[8];
#pragma unroll
    for (int p = 0; p < 4; ++p) {
      float2 Z = zb[p][PADi(pos)];
      float2 W = zb[p][PADi(pos2)];
      xr[2 * p]     = 0.5f * (Z.x + W.x);
      xi[2 * p]     = 0.5f * (Z.y - W.y);
      xr[2 * p + 1] = 0.5f * (Z.y + W.y);
      xi[2 * p + 1] = 0.5f * (W.x - Z.x);
    }
    fft8_fwd(xr, xi);                               // X[kb] along batch dim
#pragma unroll
    for (int kb = 0; kb < 8; ++kb) {
      float sr = xr[kb], si = xi[kb];
      float r2 = sr * sr + si * si;
      if (r2 < 1e-5f) r2 = 1e-5f;                   // _replace_denormals(re^2+im^2)
      float a = sqrtf(r2);
      float rr = (sr < 1e-5f && sr > -1e-5f) ? 1e-5f : sr;
      float ph = fast_atan2(si, rr);
      ab[kb * 1024 + k] = f2bf(a);
      pb[kb * 1024 + k] = f2bf(ph);
    }
  }
}

// ---- 2. GEMM1+softmax (blocks x<256) and v-GEMM (blocks x>=256), one grid --
// sm: 32x128 tile, full logits row per block.  v: 128x128 tile, M=128.
__global__ __launch_bounds__(256) void gemm_sm_v(
    const short* A0, const short* A1,       // 8192 x 1024 bf16 (phase, amp)
    const short* Tok,                       // 4 x 128 x 1024 bf16 tokens
    const short* Wall,                      // 4 x 1024 x 1024 bf16 weights
    const float* bt1, const float* bt2,     // b_t2f, b_t2f2
    short* __restrict__ awb,                // 2 x 8192 x 128 bf16
    short* __restrict__ vrow) {             // 2 x 128 x 1024 bf16
  __shared__ __align__(16) char smem[28800];
  const int z = blockIdx.z;
  const int tid = threadIdx.x;
  const int wave = tid >> 6, lane = tid & 63;
  const int m16 = lane & 15, quad = lane >> 4;
  const int fcol = ((quad ^ ((m16 >> 1) & 3)) * 8) + m16 * 32;
  const int r0 = tid >> 2;
  const int csw = (((tid & 3) ^ ((r0 >> 1) & 3)) * 8);

  if (blockIdx.x >= 256) {                          // ---- v-GEMM part ----
    const int jb = blockIdx.x - 256;                // column block 0..7
    const short* A = Tok + (size_t)(2 + z) * 128 * 1024;   // shifted tokens
    const short* B = Wall + (size_t)z * 1024 * 1024;       // w_t2f / w_t2f2
    const float* bias = z ? bt2 : bt1;
    short* C = vrow + (size_t)z * 128 * 1024;
    const int K = 1024;
    short* As = (short*)smem;                       // 128 x 32
    short* Bs = (short*)(smem + 8192);              // 128 x 32
    const int wm = (wave & 1) * 64, wn = (wave >> 1) * 64;
    f32x4 acc[4][4];
#pragma unroll
    for (int i = 0; i < 4; ++i)
#pragma unroll
      for (int j = 0; j < 4; ++j) acc[i][j] = (f32x4){0.f, 0.f, 0.f, 0.f};
    const short* aSrc0 = A + (size_t)r0 * K + csw;
    const short* aSrc1 = aSrc0 + (size_t)64 * K;
    const short* bSrc0 = B + (size_t)(jb * 128 + r0) * K + csw;
    const short* bSrc1 = bSrc0 + (size_t)64 * K;
    short* aDst0 = As + tid * 8;
    short* aDst1 = As + 2048 + tid * 8;
    short* bDst0 = Bs + tid * 8;
    short* bDst1 = Bs + 2048 + tid * 8;
    for (int k0 = 0; k0 < K; k0 += 32) {
      async16(aSrc0 + k0, aDst0);
      async16(aSrc1 + k0, aDst1);
      async16(bSrc0 + k0, bDst0);
      async16(bSrc1 + k0, bDst1);
      __syncthreads();
      bf16x8 af[4], bg[4];
#pragma unroll
      for (int ib = 0; ib < 4; ++ib)
        af[ib] = *(const bf16x8*)(As + (wm + ib * 16) * 32 + fcol);
#pragma unroll
      for (int jb2 = 0; jb2 < 4; ++jb2)
        bg[jb2] = *(const bf16x8*)(Bs + (wn + jb2 * 16) * 32 + fcol);
#pragma unroll
      for (int ib = 0; ib < 4; ++ib)
#pragma unroll
        for (int jb2 = 0; jb2 < 4; ++jb2)
          acc[ib][jb2] = __builtin_amdgcn_mfma_f32_16x16x32_bf16(af[ib], bg[jb2], acc[ib][jb2], 0, 0, 0);
      __syncthreads();
    }
#pragma unroll
    for (int ib = 0; ib < 4; ++ib) {
      const int rowb = wm + ib * 16 + quad * 4;
#pragma unroll
      for (int jb2 = 0; jb2 < 4; ++jb2) {
        const int col = jb * 128 + wn + jb2 * 16 + m16;
        const float bcv = bias[col];
#pragma unroll
        for (int r = 0; r < 4; ++r)
          C[(size_t)(rowb + r) * 1024 + col] = f2bf(acc[ib][jb2][r] + bcv);
      }
    }
    return;
  }

  // ---- softmax-GEMM part (identical logic to R8 gemm32_sm) ----
  const short* A = z ? A1 : A0;
  const short* B = Tok + (size_t)z * 128 * 1024;
  const int K = 1024;
  short* As = (short*)smem;                         // 32 x 32 (2 KB)
  short* Bs = (short*)(smem + 2048);                // 128 x 32 (8 KB)
  float (*ltile)[129] = (float(*)[129])(smem + 10240);   // 16.5 KB
  float (*red1)[8] = (float(*)[8])(smem + 26752);
  float (*red2)[8] = (float(*)[8])(smem + 27776);
  const int wm = (wave & 1) * 16, wn = (wave >> 1) * 64;
  f32x4 acc[4];
#pragma unroll
  for (int j = 0; j < 4; ++j) acc[j] = (f32x4){0.f, 0.f, 0.f, 0.f};
  const short* aSrc  = A + (size_t)(blockIdx.x * 32 + r0) * K + csw;  // tid<128
  const short* bSrc0 = B + (size_t)r0 * K + csw;
  const short* bSrc1 = bSrc0 + (size_t)64 * K;
  short* aDst  = As + tid * 8;
  short* bDst0 = Bs + tid * 8;
  short* bDst1 = Bs + 2048 + tid * 8;
  for (int k0 = 0; k0 < K; k0 += 32) {
    if (tid < 128) async16(aSrc + k0, aDst);
    async16(bSrc0 + k0, bDst0);
    async16(bSrc1 + k0, bDst1);
    __syncthreads();
    bf16x8 af = *(const bf16x8*)(As + wm * 32 + fcol);
    bf16x8 bg[4];
#pragma unroll
    for (int jb = 0; jb < 4; ++jb)
      bg[jb] = *(const bf16x8*)(Bs + (wn + jb * 16) * 32 + fcol);
#pragma unroll
    for (int jb = 0; jb < 4; ++jb)
      acc[jb] = __builtin_amdgcn_mfma_f32_16x16x32_bf16(af, bg[jb], acc[jb], 0, 0, 0);
    __syncthreads();
  }
#pragma unroll
  for (int jb = 0; jb < 4; ++jb)
#pragma unroll
    for (int r = 0; r < 4; ++r)
      ltile[wm + quad * 4 + r][wn + jb * 16 + m16] = acc[jb][r];
  __syncthreads();
  const int row = tid >> 3, l8 = tid & 7;
  float s = 0.f, q = 0.f;
  for (int c = l8; c < 100; c += 8) { float x = ltile[row][c]; s += x; q += x * x; }
  red1[row][l8] = s; red2[row][l8] = q;
  __syncthreads();
  float ssum = 0.f, qsum = 0.f;
#pragma unroll
  for (int i = 0; i < 8; ++i) { ssum += red1[row][i]; qsum += red2[row][i]; }
  __syncthreads();
  const float mu = ssum * 0.01f;
  const float rinv = rsqrtf(fmaxf(qsum * 0.01f - mu * mu, 0.f) + 1e-5f);
  float mx = -3.4e38f;
  for (int c = l8; c < 100; c += 8) {
    float x = ltile[row][c];
    if (z == 1) x = (x - mu) * rinv;                // instance-norm (amp path)
    x *= 0.03125f;                                  // * C^{-1/2}
    ltile[row][c] = x;
    mx = fmaxf(mx, x);
  }
  red1[row][l8] = mx;
  __syncthreads();
#pragma unroll
  for (int i = 0; i < 8; ++i) mx = fmaxf(mx, red1[row][i]);
  __syncthreads();
  float es = 0.f;
  for (int c = l8; c < 100; c += 8) {
    float e = __expf(ltile[row][c] - mx);
    ltile[row][c] = e; es += e;
  }
  red1[row][l8] = es;
  __syncthreads();
  float tot = 0.f;
#pragma unroll
  for (int i = 0; i < 8; ++i) tot += red1[row][i];
  const float inv = 1.f / tot;
  short* Aout = awb + ((size_t)z * 8192 + (size_t)blockIdx.x * 32 + row) * 128;
  for (int c = l8; c < 100; c += 8)
    if (c >= 1) Aout[c - 1] = f2bf(ltile[row][c] * inv);  // aw[k]=attn[k+1]
  for (int k = l8; k < 128; k += 8)
    if (k >= 99) Aout[k] = 0;                             // zero pad 99..127
}

// ------------- 64x128-tile GEMM (V2T) ---------------------------------------
__global__ __launch_bounds__(256) void gemm64(
    const short* A0, const short* A1,       // M x K bf16
    const short* B0, const short* B1,       // 128 x K bf16
    void* C0v, void* C1v, int K, int ldc) {
  const int z = blockIdx.z;
  const short* A = z ? A1 : A0;
  const short* B = z ? B1 : B0;
  void* Cv = z ? C1v : C0v;
  __shared__ __align__(16) short As[64 * 32];
  __shared__ __align__(16) short Bs[128 * 32];
  const int tid = threadIdx.x;
  const int wave = tid >> 6, lane = tid & 63;
  const int m16 = lane & 15, quad = lane >> 4;
  const int wm = (wave & 1) * 32, wn = (wave >> 1) * 64;
  f32x4 acc[2][4];
#pragma unroll
  for (int i = 0; i < 2; ++i)
#pragma unroll
    for (int j = 0; j < 4; ++j) acc[i][j] = (f32x4){0.f, 0.f, 0.f, 0.f};
  const int r0 = tid >> 2;
  const int csw = (((tid & 3) ^ ((r0 >> 1) & 3)) * 8);
  const short* aSrc  = A + (size_t)(blockIdx.x * 64 + r0) * K + csw;
  const short* bSrc0 = B + (size_t)r0 * K + csw;
  const short* bSrc1 = bSrc0 + (size_t)64 * K;
  short* aDst  = As + tid * 8;
  short* bDst0 = Bs + tid * 8;
  short* bDst1 = Bs + 2048 + tid * 8;
  const int fcol = ((quad ^ ((m16 >> 1) & 3)) * 8) + m16 * 32;
  for (int k0 = 0; k0 < K; k0 += 32) {
    async16(aSrc + k0, aDst);
    async16(bSrc0 + k0, bDst0);
    async16(bSrc1 + k0, bDst1);
    __syncthreads();
    bf16x8 af[2], bg[4];
#pragma unroll
    for (int ib = 0; ib < 2; ++ib)
      af[ib] = *(const bf16x8*)(As + (wm + ib * 16) * 32 + fcol);
#pragma unroll
    for (int jb = 0; jb < 4; ++jb)
      bg[jb] = *(const bf16x8*)(Bs + (wn + jb * 16) * 32 + fcol);
#pragma unroll
    for (int ib = 0; ib < 2; ++ib)
#pragma unroll
      for (int jb = 0; jb < 4; ++jb)
        acc[ib][jb] = __builtin_amdgcn_mfma_f32_16x16x32_bf16(af[ib], bg[jb], acc[ib][jb], 0, 0, 0);
    __syncthreads();
  }
#pragma unroll
  for (int ib = 0; ib < 2; ++ib) {
    const int rowb = blockIdx.x * 64 + wm + ib * 16 + quad * 4;
#pragma unroll
    for (int jb = 0; jb < 4; ++jb) {
      const int col = wn + jb * 16 + m16;
#pragma unroll
      for (int r = 0; r < 4; ++r)
        ((short*)Cv)[(size_t)(rowb + r) * ldc + col] = f2bf(acc[ib][jb][r]);
    }
  }
}

// ---- dual-K fused GEMM: C = A1@B1^T (K1) + A2@B2^T (K2) + bias_col, bf16 ---
__global__ __launch_bounds__(256) void gemm128_dual(
    const short* A1_0, const short* A1_1,   // M x K1
    const short* B1_0, const short* B1_1,   // N x K1
    const short* A2_0, const short* A2_1,   // M x K2
    const short* B2_0, const short* B2_1,   // N x K2
    const float* bias0, const float* bias1,
    short* C0, short* C1, int K1, int K2, int ldc) {
  const int z = blockIdx.z;
  const short* A1 = z ? A1_1 : A1_0;
  const short* B1 = z ? B1_1 : B1_0;
  const short* A2 = z ? A2_1 : A2_0;
  const short* B2 = z ? B2_1 : B2_0;
  const float* bias = z ? bias1 : bias0;
  short* C = z ? C1 : C0;
  __shared__ __align__(16) short As[128 * 32];
  __shared__ __align__(16) short Bs[128 * 32];
  const int tid = threadIdx.x;
  const int wave = tid >> 6, lane = tid & 63;
  const int m16 = lane & 15, quad = lane >> 4;
  const int wm = (wave & 1) * 64, wn = (wave >> 1) * 64;
  f32x4 acc[4][4];
#pragma unroll
  for (int i = 0; i < 4; ++i)
#pragma unroll
    for (int j = 0; j < 4; ++j) acc[i][j] = (f32x4){0.f, 0.f, 0.f, 0.f};
  const int r0 = tid >> 2;
  const int csw = (((tid & 3) ^ ((r0 >> 1) & 3)) * 8);
  short* aDst0 = As + tid * 8;
  short* aDst1 = As + 2048 + tid * 8;
  short* bDst0 = Bs + tid * 8;
  short* bDst1 = Bs + 2048 + tid * 8;
  const int fcol = ((quad ^ ((m16 >> 1) & 3)) * 8) + m16 * 32;
#pragma unroll 1
  for (int phase = 0; phase < 2; ++phase) {
    const short* A = phase ? A2 : A1;
    const short* B = phase ? B2 : B1;
    const int K = phase ? K2 : K1;
    const short* aSrc0 = A + (size_t)(blockIdx.x * 128 + r0) * K + csw;
    const short* aSrc1 = aSrc0 + (size_t)64 * K;
    const short* bSrc0 = B + (size_t)(blockIdx.y * 128 + r0) * K + csw;
    const short* bSrc1 = bSrc0 + (size_t)64 * K;
    for (int k0 = 0; k0 < K; k0 += 32) {
      async16(aSrc0 + k0, aDst0);
      async16(aSrc1 + k0, aDst1);
      async16(bSrc0 + k0, bDst0);
      async16(bSrc1 + k0, bDst1);
      __syncthreads();
      bf16x8 af[4], bg[4];
#pragma unroll
      for (int ib = 0; ib < 4; ++ib)
        af[ib] = *(const bf16x8*)(As + (wm + ib * 16) * 32 + fcol);
#pragma unroll
      for (int jb = 0; jb < 4; ++jb)
        bg[jb] = *(const bf16x8*)(Bs + (wn + jb * 16) * 32 + fcol);
#pragma unroll
      for (int ib = 0; ib < 4; ++ib)
#pragma unroll
        for (int jb = 0; jb < 4; ++jb)
          acc[ib][jb] = __builtin_amdgcn_mfma_f32_16x16x32_bf16(af[ib], bg[jb], acc[ib][jb], 0, 0, 0);
      __syncthreads();
    }
  }
#pragma unroll
  for (int ib = 0; ib < 4; ++ib) {
    const int rowb = blockIdx.x * 128 + wm + ib * 16 + quad * 4;
#pragma unroll
    for (int jb = 0; jb < 4; ++jb) {
      const int col = blockIdx.y * 128 + wn + jb * 16 + m16;
      const float bcv = bias[col];
#pragma unroll
      for (int r = 0; r < 4; ++r) {
        const size_t idx = (size_t)(rowb + r) * (size_t)ldc + col;
        C[idx] = f2bf(acc[ib][jb][r] + bcv);
      }
    }
  }
}

// ---- fused inverse: polar->z, FFT8 inv (regs), Hermitian-packed 1024-pt ----
// ---- ifft, + residual.  TWO blocks per n (each owns 2 packed FFTs). --------
__global__ __launch_bounds__(256) void inv_fft2_res(const short* __restrict__ dPb,
                                                    const short* __restrict__ dAb,
                                                    const float* __restrict__ feats,
                                                    const float* __restrict__ scalep,
                                                    float* __restrict__ out) {
  __shared__ float2 zb[2][1056];                    // 16.9 KB -> 8 blocks/CU
  const int t = threadIdx.x;
  const int n = blockIdx.x >> 1, q = blockIdx.x & 1;  // q: which half (p4 = 2q+l)
  const short* pp = dPb + (size_t)n * 8192;
  const short* ap = dAb + (size_t)n * 8192;
  const float invs = 0.022097086912079608f;         // 1/sqrt(2048)
  const float inv8 = 0.35355339059327373f;          // 1/sqrt(8) (ortho)
  for (int k = t; k < 513; k += 256) {
    float zr[8], zi[8];
#pragma unroll
    for (int b = 0; b < 8; ++b) {
      float p = bf2f(pp[b * 1024 + k]);
      float a = bf2f(ap[b * 1024 + k]) * invs;
      float s, c; __sincosf(p, &s, &c);
      zr[b] = c * a; zi[b] = s * a;
    }
    fft8_inv(zr, zi);                               // Z[bp] = ifft along batch
#pragma unroll
    for (int l = 0; l < 2; ++l) {
      const int bp = 4 * q + 2 * l;                 // pair (bp, bp+1)
      float ax = zr[bp] * inv8,     ay = zi[bp] * inv8;
      float bx = zr[bp + 1] * inv8, by = zi[bp + 1] * inv8;
      zb[l][PADi(k)] = make_float2(ax - by, ay + bx);   // Y = Za + i*Zb
      if (k >= 1 && k <= 511)
        zb[l][PADi(1024 - k)] = make_float2(ax + by, bx - ay);
    }
  }
  __syncthreads();
  fft1024xN<1, 2>(zb, t);
  const int rt = rev4_8(t);
  const float s = scalep[0] * 0.03125f;             // scale * 1/sqrt(1024)
#pragma unroll
  for (int l = 0; l < 2; ++l) {
    const int p4 = 2 * q + l;
    const size_t ob0 = 8192 + ((size_t)n * 8 + 2 * p4) * 1024;
    const size_t ob1 = ob0 + 1024;
#pragma unroll
    for (int m = 0; m < 4; ++m) {
      const int nn = 256 * m + t;
      float2 y = zb[l][PADi(4 * rt + m)];
      out[ob0 + nn] = feats[ob0 + nn] + y.x * s;
      out[ob1 + nn] = feats[ob1 + nn] + y.y * s;
    }
  }
}

// ---------------------------------------------------------------------------
extern "C" void kernel_launch(void* const* d_in, const int* in_sizes, int n_in,
                              void* d_out, int out_size, void* d_ws, size_t ws_size,
                              hipStream_t stream) {
  const float* feats  = (const float*)d_in[0];
  const float* lt1    = (const float*)d_in[1];
  const float* lt2    = (const float*)d_in[2];
  const float* w_t2f  = (const float*)d_in[3];
  const float* b_t2f  = (const float*)d_in[4];
  const float* w_df   = (const float*)d_in[5];
  const float* b_df   = (const float*)d_in[6];
  const float* w_t2f2 = (const float*)d_in[7];
  const float* b_t2f2 = (const float*)d_in[8];
  const float* w_df2  = (const float*)d_in[9];
  const float* b_df2  = (const float*)d_in[10];
  const float* scalep = (const float*)d_in[11];
  const int*   layerp = (const int*)d_in[12];
  float* out = (float*)d_out;
  (void)in_sizes; (void)n_in; (void)out_size; (void)ws_size;

  const size_t SZ = 8192ull * 1024ull;              // 8,388,608 elements
  short* Pa   = (short*)d_ws;                       // phase bf16 (16 MB)
  short* Pb   = Pa + SZ;                            // amp   bf16 (16 MB)
  short* awb  = Pb + SZ;                            // aw bf16, 2x8192x128 (4 MB)
  short* Tok  = awb + 2ull * 8192 * 128;            // tokens bf16, 4x128x1024 (1 MB)
  short* Wall = Tok + 4ull * 128 * 1024;            // weights bf16, 4x1024x1024 (8 MB)
  short* vrow = Wall + 4ull * 1024 * 1024;          // v row-major, 2x128x1024 (0.5 MB)
  short* V2T  = vrow + 2ull * 128 * 1024;           // w_df@v^T, 2x1024x128 (0.5 MB)
  short* dP   = V2T + 2ull * 1024 * 128;            // d_phase bf16 (16 MB)
  short* dA   = dP + SZ;                            // d_amp bf16 (16 MB)

  // 1: fwd fft2 + amp/phase (blocks 0..1023) + weight/token convert + cls copy
  fwd_fft2_amp_conv<<<dim3(5664), dim3(256), 0, stream>>>(
      feats, Pb, Pa, w_t2f, w_t2f2, w_df, w_df2, lt1, lt2, layerp,
      Wall, Tok, out);
  // 2: GEMM1+in+softmax (x<256) and v = Tok_sh@w_t2f^T + b (x>=256), one grid
  gemm_sm_v<<<dim3(264, 1, 2), dim3(256), 0, stream>>>(
      Pa, Pb, Tok, Wall, b_t2f, b_t2f2, awb, vrow);
  // 3: V2T = w_df @ v^T  (M=1024, N=128, K=1024), bf16, ldc=128
  gemm64<<<dim3(16, 1, 2), dim3(256), 0, stream>>>(
      Wall + 2 * 1024 * 1024, Wall + 3 * 1024 * 1024,
      vrow, vrow + 128 * 1024,
      V2T, V2T + 1024 * 128, 1024, 128);
  // 4: d = aw @ V2T^T + P @ w_df^T + b_df  (M=8192, N=1024, K=128+1024), bf16
  gemm128_dual<<<dim3(64, 8, 2), dim3(256), 0, stream>>>(
      awb, awb + 8192 * 128, V2T, V2T + 1024 * 128,
      Pa, Pb, Wall + 2 * 1024 * 1024, Wall + 3 * 1024 * 1024,
      b_df, b_df2, dP, dA, 128, 1024, 1024);
  // 5: fused inverse: polar -> ifft8 -> ifft_c -> residual (2 blocks/n)
  inv_fft2_res<<<dim3(2048), dim3(256), 0, stream>>>(dP, dA, feats, scalep, out);
}

// Round 10
// 252.879 us; speedup vs baseline: 2.6415x; 1.0693x over previous
//
#include <hip/hip_runtime.h>
#include <cstddef>

// ---------------------------------------------------------------------------
// Reins layer on MI355X — round 10.
// R9 kept. R10: BK=64 (two BK=32 sub-buffers per barrier) in gemm128_dual and
// gemm_sm_v's softmax part — halves the per-K-step vmcnt(0)+s_barrier drain
// count, which the R9 arithmetic showed dominates (MFMA only ~4.7 us of the
// 62 us dispatch).  Everything else unchanged (controls).
// ---------------------------------------------------------------------------

using bf16x8 = __attribute__((ext_vector_type(8))) short;   // 8 bf16 in 4 VGPRs
using f32x4  = __attribute__((ext_vector_type(4))) float;

__device__ inline short f2bf(float f) {
  union { float f; unsigned u; } v; v.f = f;
  unsigned r = v.u + 0x7FFFu + ((v.u >> 16) & 1u);  // round-to-nearest-even
  return (short)(r >> 16);
}
__device__ inline float bf2f(short s) {
  union { unsigned u; float f; } v; v.u = ((unsigned)(unsigned short)s) << 16;
  return v.f;
}
__device__ inline void async16(const void* g, void* l) {
  __builtin_amdgcn_global_load_lds(
      (const __attribute__((address_space(1))) void*)g,
      (__attribute__((address_space(3))) void*)l, 16, 0, 0);
}
__device__ inline float fast_atan2(float y, float x) {   // max err ~1.5e-4 rad
  float ax = fabsf(x), ay = fabsf(y);
  float mx = fmaxf(ax, ay), mn = fminf(ax, ay);
  float a = mn * __frcp_rn(mx);
  float s = a * a;
  float r = fmaf(fmaf(fmaf(-0.0464964749f, s, 0.15931422f), s, -0.327622764f),
                 s * a, a);
  if (ay > ax) r = 1.5707963267948966f - r;
  if (x < 0.f) r = 3.14159265358979f - r;
  return (y < 0.f) ? -r : r;
}

__device__ inline int PADi(int i) { return i + (i >> 5); }   // LDS anti-conflict
__device__ inline int rev4_8(int t) {                         // reverse 4 base-4 digits
  return ((t & 3) << 6) | (((t >> 2) & 3) << 4) | (((t >> 4) & 3) << 2) | ((t >> 6) & 3);
}

// ---- radix-2 DIF FFT8, natural-order in & out ------------------------------
__device__ inline void fft8_fwd(float* xr, float* xi) {      // X[k]=Σx e^{-2πikb/8}
  const float r = 0.70710678118654752f;
  float ar[4], ai[4], br[4], bi[4], tr, ti;
  ar[0]=xr[0]+xr[4]; ai[0]=xi[0]+xi[4]; br[0]=xr[0]-xr[4]; bi[0]=xi[0]-xi[4];
  ar[1]=xr[1]+xr[5]; ai[1]=xi[1]+xi[5];
  tr=xr[1]-xr[5]; ti=xi[1]-xi[5]; br[1]=(tr+ti)*r; bi[1]=(ti-tr)*r;   // *(1-i)r
  ar[2]=xr[2]+xr[6]; ai[2]=xi[2]+xi[6];
  tr=xr[2]-xr[6]; ti=xi[2]-xi[6]; br[2]=ti; bi[2]=-tr;                // *(-i)
  ar[3]=xr[3]+xr[7]; ai[3]=xi[3]+xi[7];
  tr=xr[3]-xr[7]; ti=xi[3]-xi[7]; br[3]=(ti-tr)*r; bi[3]=-(tr+ti)*r;  // *-(1+i)r
  float u0r=ar[0]+ar[2], u0i=ai[0]+ai[2], u1r=ar[1]+ar[3], u1i=ai[1]+ai[3];
  float v0r=ar[0]-ar[2], v0i=ai[0]-ai[2];
  tr=ar[1]-ar[3]; ti=ai[1]-ai[3];
  float v1r=ti, v1i=-tr;                                              // *(-i)
  xr[0]=u0r+u1r; xi[0]=u0i+u1i; xr[4]=u0r-u1r; xi[4]=u0i-u1i;
  xr[2]=v0r+v1r; xi[2]=v0i+v1i; xr[6]=v0r-v1r; xi[6]=v0i-v1i;
  u0r=br[0]+br[2]; u0i=bi[0]+bi[2]; u1r=br[1]+br[3]; u1i=bi[1]+bi[3];
  v0r=br[0]-br[2]; v0i=bi[0]-bi[2];
  tr=br[1]-br[3]; ti=bi[1]-bi[3];
  v1r=ti; v1i=-tr;
  xr[1]=u0r+u1r; xi[1]=u0i+u1i; xr[5]=u0r-u1r; xi[5]=u0i-u1i;
  xr[3]=v0r+v1r; xi[3]=v0i+v1i; xr[7]=v0r-v1r; xi[7]=v0i-v1i;
}
__device__ inline void fft8_inv(float* xr, float* xi) {      // X[k]=Σx e^{+2πikb/8}
  const float r = 0.70710678118654752f;
  float ar[4], ai[4], br[4], bi[4], tr, ti;
  ar[0]=xr[0]+xr[4]; ai[0]=xi[0]+xi[4]; br[0]=xr[0]-xr[4]; bi[0]=xi[0]-xi[4];
  ar[1]=xr[1]+xr[5]; ai[1]=xi[1]+xi[5];
  tr=xr[1]-xr[5]; ti=xi[1]-xi[5]; br[1]=(tr-ti)*r; bi[1]=(tr+ti)*r;   // *(1+i)r
  ar[2]=xr[2]+xr[6]; ai[2]=xi[2]+xi[6];
  tr=xr[2]-xr[6]; ti=xi[2]-xi[6]; br[2]=-ti; bi[2]=tr;                // *(+i)
  ar[3]=xr[3]+xr[7]; ai[3]=xi[3]+xi[7];
  tr=xr[3]-xr[7]; ti=xi[3]-xi[7]; br[3]=-(tr+ti)*r; bi[3]=(tr-ti)*r;  // *(-1+i)r
  float u0r=ar[0]+ar[2], u0i=ai[0]+ai[2], u1r=ar[1]+ar[3], u1i=ai[1]+ai[3];
  float v0r=ar[0]-ar[2], v0i=ai[0]-ai[2];
  tr=ar[1]-ar[3]; ti=ai[1]-ai[3];
  float v1r=-ti, v1i=tr;                                              // *(+i)
  xr[0]=u0r+u1r; xi[0]=u0i+u1i; xr[4]=u0r-u1r; xi[4]=u0i-u1i;
  xr[2]=v0r+v1r; xi[2]=v0i+v1i; xr[6]=v0r-v1r; xi[6]=v0i-v1i;
  u0r=br[0]+br[2]; u0i=bi[0]+bi[2]; u1r=br[1]+br[3]; u1i=bi[1]+bi[3];
  v0r=br[0]-br[2]; v0i=bi[0]-bi[2];
  tr=br[1]-br[3]; ti=bi[1]-bi[3];
  v1r=-ti; v1i=tr;
  xr[1]=u0r+u1r; xi[1]=u0i+u1i; xr[5]=u0r-u1r; xi[5]=u0i-u1i;
  xr[3]=v0r+v1r; xi[3]=v0i+v1i; xr[7]=v0r-v1r; xi[7]=v0i-v1i;
}

// 1024-pt in-place radix-4 DIF, NP interleaved FFTs sharing barriers.
template <int SIGN, int NP>
__device__ inline void fft1024xN(float2 (*zb)[1056], int t) {
#pragma unroll
  for (int s = 0; s < 5; ++s) {
    const int Q = 256 >> (2 * s);
    const int j = t & (Q - 1);
    const int i0 = ((t & ~(Q - 1)) << 2) + j;
    const float ang = (float)SIGN * 6.283185307179586f * (float)j / (float)(4 * Q);
    float s1, c1; __sincosf(ang, &s1, &c1);
    const float c2 = c1 * c1 - s1 * s1, s2 = 2.f * c1 * s1;
    const float c3 = c2 * c1 - s2 * s1, s3 = c2 * s1 + s2 * c1;
#pragma unroll
    for (int p = 0; p < NP; ++p) {
      float2* z = zb[p];
      float2 x0 = z[PADi(i0)];
      float2 x1 = z[PADi(i0 + Q)];
      float2 x2 = z[PADi(i0 + 2 * Q)];
      float2 x3 = z[PADi(i0 + 3 * Q)];
      float t0x = x0.x + x2.x, t0y = x0.y + x2.y;
      float t1x = x0.x - x2.x, t1y = x0.y - x2.y;
      float t2x = x1.x + x3.x, t2y = x1.y + x3.y;
      float t3x = x1.x - x3.x, t3y = x1.y - x3.y;
      float u0x = t0x + t2x, u0y = t0y + t2y;
      float u2x = t0x - t2x, u2y = t0y - t2y;
      float u1x, u1y, u3x, u3y;
      if (SIGN < 0) { u1x = t1x + t3y; u1y = t1y - t3x; u3x = t1x - t3y; u3y = t1y + t3x; }
      else          { u1x = t1x - t3y; u1y = t1y + t3x; u3x = t1x + t3y; u3y = t1y - t3x; }
      z[PADi(i0)]         = make_float2(u0x, u0y);
      z[PADi(i0 + Q)]     = make_float2(u1x * c1 - u1y * s1, u1x * s1 + u1y * c1);
      z[PADi(i0 + 2 * Q)] = make_float2(u2x * c2 - u2y * s2, u2x * s2 + u2y * c2);
      z[PADi(i0 + 3 * Q)] = make_float2(u3x * c3 - u3y * s3, u3x * s3 + u3y * c3);
    }
    __syncthreads();
  }
}

// ---- 1. fused fwd fft2 + amp/phase + conv work as extra blocks -------------
__global__ __launch_bounds__(256) void fwd_fft2_amp_conv(
    const float* __restrict__ feats,
    short* __restrict__ ampb, short* __restrict__ phaseb,
    const float* __restrict__ w1, const float* __restrict__ w2,
    const float* __restrict__ w3, const float* __restrict__ w4,
    const float* __restrict__ lt1, const float* __restrict__ lt2,
    const int* __restrict__ layerp,
    short* __restrict__ Wdst, short* __restrict__ Tdst,
    float* __restrict__ out) {
  if (blockIdx.x >= 1024) {                         // ---- conv part ----
    const int id = blockIdx.x - 1024;
    const int t4 = threadIdx.x * 4;
    if (id < 4096) {                                // weights: 4 x 1024 rows
      const int z = id >> 10, row = id & 1023;
      const float* W = (z == 0 ? w1 : z == 1 ? w2 : z == 2 ? w3 : w4)
                       + (size_t)row * 1024;
      short* D = Wdst + ((size_t)z * 1024 + row) * 1024;
      float4 v = *(const float4*)(W + t4);
      D[t4] = f2bf(v.x); D[t4 + 1] = f2bf(v.y); D[t4 + 2] = f2bf(v.z); D[t4 + 3] = f2bf(v.w);
    } else if (id < 4608) {                         // tokens: 4 x 128 rows
      const int i2 = id - 4096;
      const int zz = i2 >> 7, row = i2 & 127;
      const int z = zz & 1, shift = zz >> 1;
      short* D = Tdst + ((size_t)zz * 128 + row) * 1024;
      if (row + shift < 100) {
        const float* S = (z ? lt2 : lt1) + (size_t)layerp[0] * 102400
                         + (size_t)(row + shift) * 1024;
        float4 v = *(const float4*)(S + t4);
        D[t4] = f2bf(v.x); D[t4 + 1] = f2bf(v.y); D[t4 + 2] = f2bf(v.z); D[t4 + 3] = f2bf(v.w);
      } else {
        D[t4] = 0; D[t4 + 1] = 0; D[t4 + 2] = 0; D[t4 + 3] = 0;
      }
    } else {                                        // cls: 32 blocks x 256
      const int i = (id - 4608) * 256 + threadIdx.x;
      out[i] = feats[i];
    }
    return;
  }
  // ---- FFT part ----
  __shared__ float2 zb[4][1056];                    // 33.8 KB
  const int t = threadIdx.x;
  const int n = blockIdx.x;
  const float* base = feats + 8192 + (size_t)n * 8192;
#pragma unroll
  for (int p = 0; p < 4; ++p) {
    const float* x0 = base + (size_t)(2 * p) * 1024;
    const float* x1 = x0 + 1024;
#pragma unroll
    for (int m = 0; m < 4; ++m) {
      const int c = t + 256 * m;
      zb[p][PADi(c)] = make_float2(x0[c], x1[c]);
    }
  }
  __syncthreads();
  fft1024xN<-1, 4>(zb, t);
  const int rt = rev4_8(t);
  short* ab = ampb + (size_t)n * 8192;
  short* pb = phaseb + (size_t)n * 8192;
#pragma unroll
  for (int m = 0; m < 4; ++m) {
    const int k = 256 * m + t;
    const int kk = (1024 - k) & 1023;
    const int pos  = 4 * rt + m;
    const int pos2 = 4 * rev4_8(kk & 255) + (kk >> 8);
    float xr[8], xi[8];
#pragma unroll
    for (int p = 0; p < 4; ++p) {
      float2 Z = zb[p][PADi(pos)];
      float2 W = zb[p][PADi(pos2)];
      xr[2 * p]     = 0.5f * (Z.x + W.x);
      xi[2 * p]     = 0.5f * (Z.y - W.y);
      xr[2 * p + 1] = 0.5f * (Z.y + W.y);
      xi[2 * p + 1] = 0.5f * (W.x - Z.x);
    }
    fft8_fwd(xr, xi);                               // X[kb] along batch dim
#pragma unroll
    for (int kb = 0; kb < 8; ++kb) {
      float sr = xr[kb], si = xi[kb];
      float r2 = sr * sr + si * si;
      if (r2 < 1e-5f) r2 = 1e-5f;                   // _replace_denormals(re^2+im^2)
      float a = sqrtf(r2);
      float rr = (sr < 1e-5f && sr > -1e-5f) ? 1e-5f : sr;
      float ph = fast_atan2(si, rr);
      ab[kb * 1024 + k] = f2bf(a);
      pb[kb * 1024 + k] = f2bf(ph);
    }
  }
}

// ---- 2. GEMM1+softmax (x<256, BK=64) and v-GEMM (x>=256, BK=32), one grid --
__global__ __launch_bounds__(256) void gemm_sm_v(
    const short* A0, const short* A1,       // 8192 x 1024 bf16 (phase, amp)
    const short* Tok,                       // 4 x 128 x 1024 bf16 tokens
    const short* Wall,                      // 4 x 1024 x 1024 bf16 weights
    const float* bt1, const float* bt2,     // b_t2f, b_t2f2
    short* __restrict__ awb,                // 2 x 8192 x 128 bf16
    short* __restrict__ vrow) {             // 2 x 128 x 1024 bf16
  __shared__ __align__(16) char smem[39040];
  const int z = blockIdx.z;
  const int tid = threadIdx.x;
  const int wave = tid >> 6, lane = tid & 63;
  const int m16 = lane & 15, quad = lane >> 4;
  const int fcol = ((quad ^ ((m16 >> 1) & 3)) * 8) + m16 * 32;
  const int r0 = tid >> 2;
  const int csw = (((tid & 3) ^ ((r0 >> 1) & 3)) * 8);

  if (blockIdx.x >= 256) {                          // ---- v-GEMM part (BK=32) --
    const int jb = blockIdx.x - 256;                // column block 0..7
    const short* A = Tok + (size_t)(2 + z) * 128 * 1024;   // shifted tokens
    const short* B = Wall + (size_t)z * 1024 * 1024;       // w_t2f / w_t2f2
    const float* bias = z ? bt2 : bt1;
    short* C = vrow + (size_t)z * 128 * 1024;
    const int K = 1024;
    short* As = (short*)smem;                       // 128 x 32
    short* Bs = (short*)(smem + 8192);              // 128 x 32
    const int wm = (wave & 1) * 64, wn = (wave >> 1) * 64;
    f32x4 acc[4][4];
#pragma unroll
    for (int i = 0; i < 4; ++i)
#pragma unroll
      for (int j = 0; j < 4; ++j) acc[i][j] = (f32x4){0.f, 0.f, 0.f, 0.f};
    const short* aSrc0 = A + (size_t)r0 * K + csw;
    const short* aSrc1 = aSrc0 + (size_t)64 * K;
    const short* bSrc0 = B + (size_t)(jb * 128 + r0) * K + csw;
    const short* bSrc1 = bSrc0 + (size_t)64 * K;
    short* aDst0 = As + tid * 8;
    short* aDst1 = As + 2048 + tid * 8;
    short* bDst0 = Bs + tid * 8;
    short* bDst1 = Bs + 2048 + tid * 8;
    for (int k0 = 0; k0 < K; k0 += 32) {
      async16(aSrc0 + k0, aDst0);
      async16(aSrc1 + k0, aDst1);
      async16(bSrc0 + k0, bDst0);
      async16(bSrc1 + k0, bDst1);
      __syncthreads();
      bf16x8 af[4], bg[4];
#pragma unroll
      for (int ib = 0; ib < 4; ++ib)
        af[ib] = *(const bf16x8*)(As + (wm + ib * 16) * 32 + fcol);
#pragma unroll
      for (int jb2 = 0; jb2 < 4; ++jb2)
        bg[jb2] = *(const bf16x8*)(Bs + (wn + jb2 * 16) * 32 + fcol);
#pragma unroll
      for (int ib = 0; ib < 4; ++ib)
#pragma unroll
        for (int jb2 = 0; jb2 < 4; ++jb2)
          acc[ib][jb2] = __builtin_amdgcn_mfma_f32_16x16x32_bf16(af[ib], bg[jb2], acc[ib][jb2], 0, 0, 0);
      __syncthreads();
    }
#pragma unroll
    for (int ib = 0; ib < 4; ++ib) {
      const int rowb = wm + ib * 16 + quad * 4;
#pragma unroll
      for (int jb2 = 0; jb2 < 4; ++jb2) {
        const int col = jb * 128 + wn + jb2 * 16 + m16;
        const float bcv = bias[col];
#pragma unroll
        for (int r = 0; r < 4; ++r)
          C[(size_t)(rowb + r) * 1024 + col] = f2bf(acc[ib][jb2][r] + bcv);
      }
    }
    return;
  }

  // ---- softmax-GEMM part, BK=64 (two BK=32 sub-buffers per barrier) ----
  const short* A = z ? A1 : A0;
  const short* B = Tok + (size_t)z * 128 * 1024;
  const int K = 1024;
  short* As = (short*)smem;                         // [2][32*32]  (4 KB)
  short* Bs = (short*)(smem + 4096);                // [2][128*32] (16 KB)
  float (*ltile)[129] = (float(*)[129])(smem + 20480);   // 16.5 KB
  float (*red1)[8] = (float(*)[8])(smem + 36992);
  float (*red2)[8] = (float(*)[8])(smem + 38016);
  const int wm = (wave & 1) * 16, wn = (wave >> 1) * 64;
  f32x4 acc[4];
#pragma unroll
  for (int j = 0; j < 4; ++j) acc[j] = (f32x4){0.f, 0.f, 0.f, 0.f};
  // A staging: all 256 threads; sub = tid>=128, idx = tid&127
  const int asub = tid >> 7, aidx = tid & 127;
  const int ar0 = aidx >> 2;
  const int acsw = (((aidx & 3) ^ ((ar0 >> 1) & 3)) * 8);
  const short* aSrc = A + (size_t)(blockIdx.x * 32 + ar0) * K + acsw + asub * 32;
  short* aDst = As + asub * 1024 + aidx * 8;
  const short* bSrc0 = B + (size_t)r0 * K + csw;
  const short* bSrc1 = bSrc0 + (size_t)64 * K;
  short* bDst00 = Bs + tid * 8;                     // sub0 rows 0-63
  short* bDst01 = Bs + 2048 + tid * 8;              // sub0 rows 64-127
  short* bDst10 = Bs + 4096 + tid * 8;              // sub1 rows 0-63
  short* bDst11 = Bs + 4096 + 2048 + tid * 8;       // sub1 rows 64-127
  for (int k0 = 0; k0 < K; k0 += 64) {
    async16(aSrc + k0, aDst);
    async16(bSrc0 + k0, bDst00);
    async16(bSrc1 + k0, bDst01);
    async16(bSrc0 + k0 + 32, bDst10);
    async16(bSrc1 + k0 + 32, bDst11);
    __syncthreads();
#pragma unroll
    for (int sub = 0; sub < 2; ++sub) {
      bf16x8 af = *(const bf16x8*)(As + sub * 1024 + wm * 32 + fcol);
      bf16x8 bg[4];
#pragma unroll
      for (int jb = 0; jb < 4; ++jb)
        bg[jb] = *(const bf16x8*)(Bs + sub * 4096 + (wn + jb * 16) * 32 + fcol);
#pragma unroll
      for (int jb = 0; jb < 4; ++jb)
        acc[jb] = __builtin_amdgcn_mfma_f32_16x16x32_bf16(af, bg[jb], acc[jb], 0, 0, 0);
    }
    __syncthreads();
  }
#pragma unroll
  for (int jb = 0; jb < 4; ++jb)
#pragma unroll
    for (int r = 0; r < 4; ++r)
      ltile[wm + quad * 4 + r][wn + jb * 16 + m16] = acc[jb][r];
  __syncthreads();
  const int row = tid >> 3, l8 = tid & 7;
  float s = 0.f, q = 0.f;
  for (int c = l8; c < 100; c += 8) { float x = ltile[row][c]; s += x; q += x * x; }
  red1[row][l8] = s; red2[row][l8] = q;
  __syncthreads();
  float ssum = 0.f, qsum = 0.f;
#pragma unroll
  for (int i = 0; i < 8; ++i) { ssum += red1[row][i]; qsum += red2[row][i]; }
  __syncthreads();
  const float mu = ssum * 0.01f;
  const float rinv = rsqrtf(fmaxf(qsum * 0.01f - mu * mu, 0.f) + 1e-5f);
  float mx = -3.4e38f;
  for (int c = l8; c < 100; c += 8) {
    float x = ltile[row][c];
    if (z == 1) x = (x - mu) * rinv;                // instance-norm (amp path)
    x *= 0.03125f;                                  // * C^{-1/2}
    ltile[row][c] = x;
    mx = fmaxf(mx, x);
  }
  red1[row][l8] = mx;
  __syncthreads();
#pragma unroll
  for (int i = 0; i < 8; ++i) mx = fmaxf(mx, red1[row][i]);
  __syncthreads();
  float es = 0.f;
  for (int c = l8; c < 100; c += 8) {
    float e = __expf(ltile[row][c] - mx);
    ltile[row][c] = e; es += e;
  }
  red1[row][l8] = es;
  __syncthreads();
  float tot = 0.f;
#pragma unroll
  for (int i = 0; i < 8; ++i) tot += red1[row][i];
  const float inv = 1.f / tot;
  short* Aout = awb + ((size_t)z * 8192 + (size_t)blockIdx.x * 32 + row) * 128;
  for (int c = l8; c < 100; c += 8)
    if (c >= 1) Aout[c - 1] = f2bf(ltile[row][c] * inv);  // aw[k]=attn[k+1]
  for (int k = l8; k < 128; k += 8)
    if (k >= 99) Aout[k] = 0;                             // zero pad 99..127
}

// ------------- 64x128-tile GEMM (V2T) ---------------------------------------
__global__ __launch_bounds__(256) void gemm64(
    const short* A0, const short* A1,       // M x K bf16
    const short* B0, const short* B1,       // 128 x K bf16
    void* C0v, void* C1v, int K, int ldc) {
  const int z = blockIdx.z;
  const short* A = z ? A1 : A0;
  const short* B = z ? B1 : B0;
  void* Cv = z ? C1v : C0v;
  __shared__ __align__(16) short As[64 * 32];
  __shared__ __align__(16) short Bs[128 * 32];
  const int tid = threadIdx.x;
  const int wave = tid >> 6, lane = tid & 63;
  const int m16 = lane & 15, quad = lane >> 4;
  const int wm = (wave & 1) * 32, wn = (wave >> 1) * 64;
  f32x4 acc[2][4];
#pragma unroll
  for (int i = 0; i < 2; ++i)
#pragma unroll
    for (int j = 0; j < 4; ++j) acc[i][j] = (f32x4){0.f, 0.f, 0.f, 0.f};
  const int r0 = tid >> 2;
  const int csw = (((tid & 3) ^ ((r0 >> 1) & 3)) * 8);
  const short* aSrc  = A + (size_t)(blockIdx.x * 64 + r0) * K + csw;
  const short* bSrc0 = B + (size_t)r0 * K + csw;
  const short* bSrc1 = bSrc0 + (size_t)64 * K;
  short* aDst  = As + tid * 8;
  short* bDst0 = Bs + tid * 8;
  short* bDst1 = Bs + 2048 + tid * 8;
  const int fcol = ((quad ^ ((m16 >> 1) & 3)) * 8) + m16 * 32;
  for (int k0 = 0; k0 < K; k0 += 32) {
    async16(aSrc + k0, aDst);
    async16(bSrc0 + k0, bDst0);
    async16(bSrc1 + k0, bDst1);
    __syncthreads();
    bf16x8 af[2], bg[4];
#pragma unroll
    for (int ib = 0; ib < 2; ++ib)
      af[ib] = *(const bf16x8*)(As + (wm + ib * 16) * 32 + fcol);
#pragma unroll
    for (int jb = 0; jb < 4; ++jb)
      bg[jb] = *(const bf16x8*)(Bs + (wn + jb * 16) * 32 + fcol);
#pragma unroll
    for (int ib = 0; ib < 2; ++ib)
#pragma unroll
      for (int jb = 0; jb < 4; ++jb)
        acc[ib][jb] = __builtin_amdgcn_mfma_f32_16x16x32_bf16(af[ib], bg[jb], acc[ib][jb], 0, 0, 0);
    __syncthreads();
  }
#pragma unroll
  for (int ib = 0; ib < 2; ++ib) {
    const int rowb = blockIdx.x * 64 + wm + ib * 16 + quad * 4;
#pragma unroll
    for (int jb = 0; jb < 4; ++jb) {
      const int col = wn + jb * 16 + m16;
#pragma unroll
      for (int r = 0; r < 4; ++r)
        ((short*)Cv)[(size_t)(rowb + r) * ldc + col] = f2bf(acc[ib][jb][r]);
    }
  }
}

// ---- dual-K fused GEMM, BK=64: C = A1@B1^T + A2@B2^T + bias_col, bf16 ------
__global__ __launch_bounds__(256) void gemm128_dual(
    const short* A1_0, const short* A1_1,   // M x K1
    const short* B1_0, const short* B1_1,   // N x K1
    const short* A2_0, const short* A2_1,   // M x K2
    const short* B2_0, const short* B2_1,   // N x K2
    const float* bias0, const float* bias1,
    short* C0, short* C1, int K1, int K2, int ldc) {
  const int z = blockIdx.z;
  const short* A1 = z ? A1_1 : A1_0;
  const short* B1 = z ? B1_1 : B1_0;
  const short* A2 = z ? A2_1 : A2_0;
  const short* B2 = z ? B2_1 : B2_0;
  const float* bias = z ? bias1 : bias0;
  short* C = z ? C1 : C0;
  __shared__ __align__(16) short As[2][128 * 32];   // 16 KB
  __shared__ __align__(16) short Bs[2][128 * 32];   // 16 KB
  const int tid = threadIdx.x;
  const int wave = tid >> 6, lane = tid & 63;
  const int m16 = lane & 15, quad = lane >> 4;
  const int wm = (wave & 1) * 64, wn = (wave >> 1) * 64;
  f32x4 acc[4][4];
#pragma unroll
  for (int i = 0; i < 4; ++i)
#pragma unroll
    for (int j = 0; j < 4; ++j) acc[i][j] = (f32x4){0.f, 0.f, 0.f, 0.f};
  const int r0 = tid >> 2;
  const int csw = (((tid & 3) ^ ((r0 >> 1) & 3)) * 8);
  const int fcol = ((quad ^ ((m16 >> 1) & 3)) * 8) + m16 * 32;
#pragma unroll 1
  for (int phase = 0; phase < 2; ++phase) {
    const short* A = phase ? A2 : A1;
    const short* B = phase ? B2 : B1;
    const int K = phase ? K2 : K1;
    const short* aSrc0 = A + (size_t)(blockIdx.x * 128 + r0) * K + csw;
    const short* aSrc1 = aSrc0 + (size_t)64 * K;
    const short* bSrc0 = B + (size_t)(blockIdx.y * 128 + r0) * K + csw;
    const short* bSrc1 = bSrc0 + (size_t)64 * K;
    for (int k0 = 0; k0 < K; k0 += 64) {            // BK=64: 2 sub-steps/barrier
      async16(aSrc0 + k0,      As[0] + tid * 8);
      async16(aSrc1 + k0,      As[0] + 2048 + tid * 8);
      async16(aSrc0 + k0 + 32, As[1] + tid * 8);
      async16(aSrc1 + k0 + 32, As[1] + 2048 + tid * 8);
      async16(bSrc0 + k0,      Bs[0] + tid * 8);
      async16(bSrc1 + k0,      Bs[0] + 2048 + tid * 8);
      async16(bSrc0 + k0 + 32, Bs[1] + tid * 8);
      async16(bSrc1 + k0 + 32, Bs[1] + 2048 + tid * 8);
      __syncthreads();
#pragma unroll
      for (int sub = 0; sub < 2; ++sub) {
        bf16x8 af[4], bg[4];
#pragma unroll
        for (int ib = 0; ib < 4; ++ib)
          af[ib] = *(const bf16x8*)(As[sub] + (wm + ib * 16) * 32 + fcol);
#pragma unroll
        for (int jb = 0; jb < 4; ++jb)
          bg[jb] = *(const bf16x8*)(Bs[sub] + (wn + jb * 16) * 32 + fcol);
#pragma unroll
        for (int ib = 0; ib < 4; ++ib)
#pragma unroll
          for (int jb = 0; jb < 4; ++jb)
            acc[ib][jb] = __builtin_amdgcn_mfma_f32_16x16x32_bf16(af[ib], bg[jb], acc[ib][jb], 0, 0, 0);
      }
      __syncthreads();
    }
  }
#pragma unroll
  for (int ib = 0; ib < 4; ++ib) {
    const int rowb = blockIdx.x * 128 + wm + ib * 16 + quad * 4;
#pragma unroll
    for (int jb = 0; jb < 4; ++jb) {
      const int col = blockIdx.y * 128 + wn + jb * 16 + m16;
      const float bcv = bias[col];
#pragma unroll
      for (int r = 0; r < 4; ++r) {
        const size_t idx = (size_t)(rowb + r) * (size_t)ldc + col;
        C[idx] = f2bf(acc[ib][jb][r] + bcv);
      }
    }
  }
}

// ---- fused inverse: polar->z, FFT8 inv, Hermitian-packed ifft, residual ----
__global__ __launch_bounds__(256) void inv_fft2_res(const short* __restrict__ dPb,
                                                    const short* __restrict__ dAb,
                                                    const float* __restrict__ feats,
                                                    const float* __restrict__ scalep,
                                                    float* __restrict__ out) {
  __shared__ float2 zb[2][1056];                    // 16.9 KB -> 8 blocks/CU
  const int t = threadIdx.x;
  const int n = blockIdx.x >> 1, q = blockIdx.x & 1;
  const short* pp = dPb + (size_t)n * 8192;
  const short* ap = dAb + (size_t)n * 8192;
  const float invs = 0.022097086912079608f;         // 1/sqrt(2048)
  const float inv8 = 0.35355339059327373f;          // 1/sqrt(8) (ortho)
  for (int k = t; k < 513; k += 256) {
    float zr[8], zi[8];
#pragma unroll
    for (int b = 0; b < 8; ++b) {
      float p = bf2f(pp[b * 1024 + k]);
      float a = bf2f(ap[b * 1024 + k]) * invs;
      float s, c; __sincosf(p, &s, &c);
      zr[b] = c * a; zi[b] = s * a;
    }
    fft8_inv(zr, zi);                               // Z[bp] = ifft along batch
#pragma unroll
    for (int l = 0; l < 2; ++l) {
      const int bp = 4 * q + 2 * l;                 // pair (bp, bp+1)
      float ax = zr[bp] * inv8,     ay = zi[bp] * inv8;
      float bx = zr[bp + 1] * inv8, by = zi[bp + 1] * inv8;
      zb[l][PADi(k)] = make_float2(ax - by, ay + bx);   // Y = Za + i*Zb
      if (k >= 1 && k <= 511)
        zb[l][PADi(1024 - k)] = make_float2(ax + by, bx - ay);
    }
  }
  __syncthreads();
  fft1024xN<1, 2>(zb, t);
  const int rt = rev4_8(t);
  const float s = scalep[0] * 0.03125f;             // scale * 1/sqrt(1024)
#pragma unroll
  for (int l = 0; l < 2; ++l) {
    const int p4 = 2 * q + l;
    const size_t ob0 = 8192 + ((size_t)n * 8 + 2 * p4) * 1024;
    const size_t ob1 = ob0 + 1024;
#pragma unroll
    for (int m = 0; m < 4; ++m) {
      const int nn = 256 * m + t;
      float2 y = zb[l][PADi(4 * rt + m)];
      out[ob0 + nn] = feats[ob0 + nn] + y.x * s;
      out[ob1 + nn] = feats[ob1 + nn] + y.y * s;
    }
  }
}

// ---------------------------------------------------------------------------
extern "C" void kernel_launch(void* const* d_in, const int* in_sizes, int n_in,
                              void* d_out, int out_size, void* d_ws, size_t ws_size,
                              hipStream_t stream) {
  const float* feats  = (const float*)d_in[0];
  const float* lt1    = (const float*)d_in[1];
  const float* lt2    = (const float*)d_in[2];
  const float* w_t2f  = (const float*)d_in[3];
  const float* b_t2f  = (const float*)d_in[4];
  const float* w_df   = (const float*)d_in[5];
  const float* b_df   = (const float*)d_in[6];
  const float* w_t2f2 = (const float*)d_in[7];
  const float* b_t2f2 = (const float*)d_in[8];
  const float* w_df2  = (const float*)d_in[9];
  const float* b_df2  = (const float*)d_in[10];
  const float* scalep = (const float*)d_in[11];
  const int*   layerp = (const int*)d_in[12];
  float* out = (float*)d_out;
  (void)in_sizes; (void)n_in; (void)out_size; (void)ws_size;

  const size_t SZ = 8192ull * 1024ull;              // 8,388,608 elements
  short* Pa   = (short*)d_ws;                       // phase bf16 (16 MB)
  short* Pb   = Pa + SZ;                            // amp   bf16 (16 MB)
  short* awb  = Pb + SZ;                            // aw bf16, 2x8192x128 (4 MB)
  short* Tok  = awb + 2ull * 8192 * 128;            // tokens bf16, 4x128x1024 (1 MB)
  short* Wall = Tok + 4ull * 128 * 1024;            // weights bf16, 4x1024x1024 (8 MB)
  short* vrow = Wall + 4ull * 1024 * 1024;          // v row-major, 2x128x1024 (0.5 MB)
  short* V2T  = vrow + 2ull * 128 * 1024;           // w_df@v^T, 2x1024x128 (0.5 MB)
  short* dP   = V2T + 2ull * 1024 * 128;            // d_phase bf16 (16 MB)
  short* dA   = dP + SZ;                            // d_amp bf16 (16 MB)

  // 1: fwd fft2 + amp/phase (blocks 0..1023) + weight/token convert + cls copy
  fwd_fft2_amp_conv<<<dim3(5664), dim3(256), 0, stream>>>(
      feats, Pb, Pa, w_t2f, w_t2f2, w_df, w_df2, lt1, lt2, layerp,
      Wall, Tok, out);
  // 2: GEMM1+in+softmax (x<256) and v = Tok_sh@w_t2f^T + b (x>=256), one grid
  gemm_sm_v<<<dim3(264, 1, 2), dim3(256), 0, stream>>>(
      Pa, Pb, Tok, Wall, b_t2f, b_t2f2, awb, vrow);
  // 3: V2T = w_df @ v^T  (M=1024, N=128, K=1024), bf16, ldc=128
  gemm64<<<dim3(16, 1, 2), dim3(256), 0, stream>>>(
      Wall + 2 * 1024 * 1024, Wall + 3 * 1024 * 1024,
      vrow, vrow + 128 * 1024,
      V2T, V2T + 1024 * 128, 1024, 128);
  // 4: d = aw @ V2T^T + P @ w_df^T + b_df  (M=8192, N=1024, K=128+1024), bf16
  gemm128_dual<<<dim3(64, 8, 2), dim3(256), 0, stream>>>(
      awb, awb + 8192 * 128, V2T, V2T + 1024 * 128,
      Pa, Pb, Wall + 2 * 1024 * 1024, Wall + 3 * 1024 * 1024,
      b_df, b_df2, dP, dA, 128, 1024, 1024);
  // 5: fused inverse: polar -> ifft8 -> ifft_c -> residual (2 blocks/n)
  inv_fft2_res<<<dim3(2048), dim3(256), 0, stream>>>(dP, dA, feats, scalep, out);
}